// Round 3
// baseline (2533.957 us; speedup 1.0000x reference)
//
#include <hip/hip_runtime.h>
#include <hip/hip_bf16.h>
#include <math.h>

// Problem dims
#define N_NODES 20000
#define S_NE    16
#define E_EDGES 160000
#define NMP     2
#define H_HEADS 4
#define O_DIM   64
#define D_FEAT  64
#define E_DIMC  32
#define PREP    128
#define NCLS    8
#define B_TR    4096
#define D1      256           // H*O

typedef __hip_bfloat16 bf16;

// Generic float load/store: T selects the raw dtype of the global buffer.
template <typename T>
__device__ __forceinline__ float ldv(const void* p, size_t i) {
    if constexpr (sizeof(T) == 4) return ((const float*)p)[i];
    else return __bfloat162float(((const bf16*)p)[i]);
}
template <typename T>
__device__ __forceinline__ void stv(void* p, size_t i, float v) {
    if constexpr (sizeof(T) == 4) ((float*)p)[i] = v;
    else ((bf16*)p)[i] = __float2bfloat16(v);
}
template <typename T>
__device__ __forceinline__ bool active(const int* flag) {
    return *flag == (sizeof(T) == 4 ? 1 : 0);
}

__device__ __forceinline__ float wave_sum(float v) {
    #pragma unroll
    for (int off = 32; off > 0; off >>= 1) v += __shfl_xor(v, off, 64);
    return v;
}

// ---------------------------------------------------------------------------
// Dtype detector: low 16 bits of each 32-bit word, viewed as bf16. For fp32
// data that's random mantissa bits -> huge/NaN ~half the time. For packed
// bf16 data it's a genuine N(0,1) sample -> always |v| < 64.
__global__ void k_detect(const unsigned* __restrict__ w, int* __restrict__ flag) {
    int t = threadIdx.x;  // 64
    int bad = 0;
    for (int i = t; i < 512; i += 64) {
        float v = __uint_as_float((w[i] & 0xffffu) << 16);
        if (!(fabsf(v) < 64.f)) bad++;   // counts NaN/Inf/huge
    }
    #pragma unroll
    for (int off = 32; off > 0; off >>= 1) bad += __shfl_xor(bad, off, 64);
    if (t == 0) *flag = (bad > 32) ? 1 : 0;   // 1 => buffers are fp32
}

// ---------------------------------------------------------------------------
// all_feats0[n,p] = sum_d feats[n,d] * W_prep1[d,p]
template <typename T>
__global__ void k_prep_nodes(const void* __restrict__ feats,
                             const void* __restrict__ W,
                             float* __restrict__ out,
                             const int* __restrict__ flag) {
    if (!active<T>(flag)) return;
    int g = blockIdx.x * blockDim.x + threadIdx.x;
    if (g >= N_NODES * PREP) return;
    int n = g >> 7, p = g & 127;
    float acc = 0.f;
    #pragma unroll
    for (int d = 0; d < D_FEAT; ++d)
        acc += ldv<T>(feats, (size_t)n * D_FEAT + d) * ldv<T>(W, d * PREP + p);
    out[g] = acc;
}

// ---------------------------------------------------------------------------
// Fused per-(mp, train-node) kernel: edge-prep -> L0 edge attn -> L0 node attn
// -> L1 node attn. 256 threads: wave = head h, lane = output dim o.
template <typename T>
__global__ __launch_bounds__(256) void k_fused(
        const void* __restrict__ feats,
        const void* __restrict__ edge_emb_mp,   // [E, 32]
        const void* __restrict__ W_prep0,       // [64, 128]
        const void* __restrict__ epw_mp,        // [32, 128]
        const void* __restrict__ ewq,           // [H,128,64]
        const void* __restrict__ ewk,
        const void* __restrict__ nwq0,          // [H,128,64]
        const void* __restrict__ nwk0,
        const void* __restrict__ nwq1,          // [H,256,64]
        const void* __restrict__ nwk1,
        const int*  __restrict__ n2e_mp,        // [N,16]
        const int*  __restrict__ adj_mp,        // [E,2]
        const int*  __restrict__ tid,           // [B]
        const float* __restrict__ all_feats0,   // [N,128]
        float* __restrict__ xcat_mp,            // [B,512]
        const int* __restrict__ flag) {
    if (!active<T>(flag)) return;
    int b = blockIdx.x;
    int t = threadIdx.x;
    int h = t >> 6, o = t & 63;

    __shared__ int   s_eid[S_NE];
    __shared__ int   s_nrow[2 * S_NE];
    __shared__ float s_emb[S_NE * E_DIMC];     // 512
    __shared__ float s_f[D_FEAT];              // 64
    __shared__ float s_q0[PREP];               // 128
    __shared__ float s_eprep[S_NE * PREP];     // 2048
    __shared__ float s_xn[2 * S_NE * PREP];    // 4096
    __shared__ float s_nedge[S_NE * D1];       // 4096
    __shared__ float s_out0[D1];               // 256

    int tid_b = tid[b];
    if (t < S_NE) s_eid[t] = n2e_mp[(size_t)tid_b * S_NE + t];
    if (t < D_FEAT) s_f[t] = ldv<T>(feats, (size_t)tid_b * D_FEAT + t);
    __syncthreads();  // s_eid, s_f ready

    if (t < 2 * S_NE) s_nrow[t] = adj_mp[(size_t)s_eid[t >> 1] * 2 + (t & 1)];
    {
        int j = t;          // 512 total = 2 per thread
        int s = j >> 5, d = j & 31;
        s_emb[j] = ldv<T>(edge_emb_mp, (size_t)s_eid[s] * E_DIMC + d);
        j = t + 256; s = j >> 5; d = j & 31;
        s_emb[j] = ldv<T>(edge_emb_mp, (size_t)s_eid[s] * E_DIMC + d);
    }
    if (t < PREP) {         // dummy row: feats[tid_b] @ W_prep0
        float a = 0.f;
        #pragma unroll
        for (int d = 0; d < D_FEAT; ++d) a += s_f[d] * ldv<T>(W_prep0, d * PREP + t);
        s_q0[t] = a;
    }
    __syncthreads();  // s_nrow, s_emb, s_q0 ready

    // endpoint node prep rows (gather from all_feats0)
    for (int j = t; j < 2 * S_NE * PREP; j += 256) {
        int r = j >> 7, d = j & 127;
        s_xn[j] = all_feats0[(size_t)s_nrow[r] * PREP + d];
    }
    // eprep[s][p] = emb[s] @ edge_prep_w
    for (int j = t; j < S_NE * PREP; j += 256) {
        int s = j >> 7, p = j & 127;
        float a = 0.f;
        #pragma unroll
        for (int d = 0; d < E_DIMC; ++d) a += s_emb[s * E_DIMC + d] * ldv<T>(epw_mp, d * PREP + p);
        s_eprep[j] = a;
    }
    __syncthreads();  // s_xn, s_eprep ready

    // ---- Phase B: layer-0 edge attention for all 16 slots ----
    {
        float qe[S_NE], kA[S_NE], kB[S_NE];
        #pragma unroll
        for (int s = 0; s < S_NE; ++s) { qe[s] = 0.f; kA[s] = 0.f; kB[s] = 0.f; }
        size_t woff = (size_t)h * PREP * O_DIM + o;
        #pragma unroll 4
        for (int d = 0; d < PREP; ++d) {
            float wqv = ldv<T>(ewq, woff + d * O_DIM);
            float wkv = ldv<T>(ewk, woff + d * O_DIM);
            #pragma unroll
            for (int s = 0; s < S_NE; ++s) {
                qe[s] += s_eprep[s * PREP + d] * wqv;
                kA[s] += s_xn[(2 * s) * PREP + d] * wkv;
                kB[s] += s_xn[(2 * s + 1) * PREP + d] * wkv;
            }
        }
        #pragma unroll
        for (int s = 0; s < S_NE; ++s) {
            float lA = wave_sum(qe[s] * kA[s]) * 0.125f;
            float lB = wave_sum(qe[s] * kB[s]) * 0.125f;
            float m = fmaxf(lA, lB);
            float eA = expf(lA - m), eB = expf(lB - m);
            float inv = 1.f / (eA + eB);
            float v = qe[s] + (eA * kA[s] + eB * kB[s]) * inv;
            v = v > 0.f ? v : expf(v) - 1.f;  // ELU
            s_nedge[s * D1 + t] = v;
        }
    }

    // ---- Phase C: layer-0 node attention (q = dummy row, k = eprep slots) ----
    {
        float qn = 0.f, kn[S_NE];
        #pragma unroll
        for (int s = 0; s < S_NE; ++s) kn[s] = 0.f;
        size_t woff = (size_t)h * PREP * O_DIM + o;
        #pragma unroll 4
        for (int d = 0; d < PREP; ++d) {
            float wqv = ldv<T>(nwq0, woff + d * O_DIM);
            float wkv = ldv<T>(nwk0, woff + d * O_DIM);
            qn += s_q0[d] * wqv;
            #pragma unroll
            for (int s = 0; s < S_NE; ++s) kn[s] += s_eprep[s * PREP + d] * wkv;
        }
        float lg[S_NE];
        #pragma unroll
        for (int s = 0; s < S_NE; ++s) lg[s] = wave_sum(qn * kn[s]) * 0.125f;
        float mx = lg[0];
        #pragma unroll
        for (int s = 1; s < S_NE; ++s) mx = fmaxf(mx, lg[s]);
        float sum = 0.f;
        #pragma unroll
        for (int s = 0; s < S_NE; ++s) { lg[s] = expf(lg[s] - mx); sum += lg[s]; }
        float inv = 1.f / sum;
        float agg = 0.f;
        #pragma unroll
        for (int s = 0; s < S_NE; ++s) agg += lg[s] * kn[s];
        float v = qn + agg * inv;
        v = v > 0.f ? v : expf(v) - 1.f;
        s_out0[t] = v;
        xcat_mp[(size_t)b * (2 * D1) + t] = v;
    }
    __syncthreads();  // s_nedge, s_out0 ready

    // ---- Phase D: layer-1 node attention (q = out0, k = nedge slots) ----
    {
        float qn = 0.f, kn[S_NE];
        #pragma unroll
        for (int s = 0; s < S_NE; ++s) kn[s] = 0.f;
        size_t woff = (size_t)h * D1 * O_DIM + o;
        #pragma unroll 4
        for (int d = 0; d < D1; ++d) {
            float wqv = ldv<T>(nwq1, woff + d * O_DIM);
            float wkv = ldv<T>(nwk1, woff + d * O_DIM);
            qn += s_out0[d] * wqv;
            #pragma unroll
            for (int s = 0; s < S_NE; ++s) kn[s] += s_nedge[s * D1 + d] * wkv;
        }
        float lg[S_NE];
        #pragma unroll
        for (int s = 0; s < S_NE; ++s) lg[s] = wave_sum(qn * kn[s]) * 0.125f;
        float mx = lg[0];
        #pragma unroll
        for (int s = 1; s < S_NE; ++s) mx = fmaxf(mx, lg[s]);
        float sum = 0.f;
        #pragma unroll
        for (int s = 0; s < S_NE; ++s) { lg[s] = expf(lg[s] - mx); sum += lg[s]; }
        float inv = 1.f / sum;
        float agg = 0.f;
        #pragma unroll
        for (int s = 0; s < S_NE; ++s) agg += lg[s] * kn[s];
        float v = qn + agg * inv;
        v = v > 0.f ? v : expf(v) - 1.f;
        xcat_mp[(size_t)b * (2 * D1) + D1 + t] = v;
    }
}

// ---------------------------------------------------------------------------
// gate_pre[m,b] = sum_e vg[e] * tanh( sum_d x[m,b,d] * Wg[d,e] )
template <typename T>
__global__ void k_gate(const float* __restrict__ xcat,
                       const void* __restrict__ Wg, const void* __restrict__ vg,
                       float* __restrict__ gate_pre,
                       const int* __restrict__ flag) {
    if (!active<T>(flag)) return;
    int mb = blockIdx.x;   // m*B + b
    int t = threadIdx.x;   // 128
    __shared__ float xr[2 * D1];
    for (int idx = t; idx < 2 * D1; idx += 128) xr[idx] = xcat[(size_t)mb * (2 * D1) + idx];
    __syncthreads();
    float acc = 0.f;
    for (int d = 0; d < 2 * D1; ++d) acc += xr[d] * ldv<T>(Wg, d * PREP + t);
    float gp = tanhf(acc) * ldv<T>(vg, t);
    __shared__ float red[128];
    red[t] = gp;
    __syncthreads();
    for (int s = 64; s > 0; s >>= 1) { if (t < s) red[t] += red[t + s]; __syncthreads(); }
    if (t == 0) gate_pre[mb] = red[0];
}

// softmax over mp, pool, FC -> logits; write logits then gate (same dtype as T)
template <typename T>
__global__ void k_final(const float* __restrict__ xcat,
                        const float* __restrict__ gate_pre,
                        const void* __restrict__ Wfc, const void* __restrict__ bfc,
                        void* __restrict__ out,
                        const int* __restrict__ flag) {
    if (!active<T>(flag)) return;
    int b = blockIdx.x;
    int t = threadIdx.x;  // 64
    float g0 = gate_pre[b], g1 = gate_pre[B_TR + b];
    float mx = fmaxf(g0, g1);
    float e0 = expf(g0 - mx), e1 = expf(g1 - mx);
    float inv = 1.f / (e0 + e1);
    float w0 = e0 * inv, w1 = e1 * inv;
    __shared__ float pooled[2 * D1];
    for (int d = t; d < 2 * D1; d += 64)
        pooled[d] = w0 * xcat[(size_t)b * (2 * D1) + d]
                  + w1 * xcat[(size_t)(B_TR + b) * (2 * D1) + d];
    __syncthreads();
    if (t < NCLS) {
        float acc = ldv<T>(bfc, t);
        for (int d = 0; d < 2 * D1; ++d) acc += pooled[d] * ldv<T>(Wfc, d * NCLS + t);
        stv<T>(out, (size_t)b * NCLS + t, acc);
    }
    if (t == 8) stv<T>(out, (size_t)B_TR * NCLS + b, w0);
    if (t == 9) stv<T>(out, (size_t)B_TR * NCLS + B_TR + b, w1);
}

// ---------------------------------------------------------------------------
extern "C" void kernel_launch(void* const* d_in, const int* in_sizes, int n_in,
                              void* d_out, int out_size, void* d_ws, size_t ws_size,
                              hipStream_t stream) {
    const void* feats       = d_in[0];
    const void* edge_emb    = d_in[1];
    const void* W_prep0     = d_in[2];
    // d_in[3]: W_prep1
    const void* edge_prep_w = d_in[4];
    const void* e_wq0       = d_in[5];
    const void* e_wk0       = d_in[6];
    // d_in[7], d_in[8]: edge_wq_l1 / edge_wk_l1 — dead (layer-1 edge update unused)
    const void* n_wq0       = d_in[9];
    const void* n_wk0       = d_in[10];
    const void* n_wq1       = d_in[11];
    const void* n_wk1       = d_in[12];
    const void* Wg          = d_in[13];
    const void* vg          = d_in[14];
    const void* Wfc         = d_in[15];
    const void* bfc         = d_in[16];
    const int*  n2e         = (const int*)d_in[17];
    const int*  adj         = (const int*)d_in[18];
    const int*  tid         = (const int*)d_in[19];

    // fp32 workspace layout (~27 MB total)
    float* ws         = (float*)d_ws;
    float* all_feats0 = ws;                                    // N*PREP      (10.24 MB)
    float* xcat       = all_feats0 + (size_t)N_NODES * PREP;   // NMP*B*512   (16.78 MB)
    float* gate_pre   = xcat + (size_t)NMP * B_TR * 2 * D1;    // NMP*B       (32 KB)
    int*   flag       = (int*)(gate_pre + NMP * B_TR);

    k_detect<<<1, 64, 0, stream>>>((const unsigned*)feats, flag);

    // Per-mp element strides (dtype-independent element offsets; byte scaling
    // differs per variant, so compute byte offsets per instantiation).
    #define LAUNCH_ALL(T)                                                          \
    do {                                                                           \
        const size_t esz = sizeof(T);                                              \
        k_prep_nodes<T><<<(N_NODES * PREP + 255) / 256, 256, 0, stream>>>(         \
            feats, d_in[3], all_feats0, flag);                                     \
        for (int mp = 0; mp < NMP; ++mp) {                                         \
            k_fused<T><<<B_TR, 256, 0, stream>>>(                                  \
                feats,                                                             \
                (const char*)edge_emb + esz * (size_t)mp * E_EDGES * E_DIMC,       \
                W_prep0,                                                           \
                (const char*)edge_prep_w + esz * (size_t)mp * E_DIMC * PREP,       \
                (const char*)e_wq0 + esz * (size_t)mp * H_HEADS * PREP * O_DIM,    \
                (const char*)e_wk0 + esz * (size_t)mp * H_HEADS * PREP * O_DIM,    \
                (const char*)n_wq0 + esz * (size_t)mp * H_HEADS * PREP * O_DIM,    \
                (const char*)n_wk0 + esz * (size_t)mp * H_HEADS * PREP * O_DIM,    \
                (const char*)n_wq1 + esz * (size_t)mp * H_HEADS * D1 * O_DIM,      \
                (const char*)n_wk1 + esz * (size_t)mp * H_HEADS * D1 * O_DIM,      \
                n2e + (size_t)mp * N_NODES * S_NE,                                 \
                adj + (size_t)mp * E_EDGES * 2,                                    \
                tid, all_feats0,                                                   \
                xcat + (size_t)mp * B_TR * 2 * D1, flag);                          \
        }                                                                          \
        k_gate<T><<<NMP * B_TR, 128, 0, stream>>>(xcat, Wg, vg, gate_pre, flag);   \
        k_final<T><<<B_TR, 64, 0, stream>>>(xcat, gate_pre, Wfc, bfc, d_out, flag);\
    } while (0)

    LAUNCH_ALL(float);
    LAUNCH_ALL(bf16);
    #undef LAUNCH_ALL
}

// Round 4
// 1442.750 us; speedup vs baseline: 1.7563x; 1.7563x over previous
//
#include <hip/hip_runtime.h>
#include <hip/hip_bf16.h>
#include <math.h>

// Problem dims
#define N_NODES 20000
#define S_NE    16
#define E_EDGES 160000
#define NMP     2
#define H_HEADS 4
#define O_DIM   64
#define D_FEAT  64
#define E_DIMC  32
#define PREP    128
#define NCLS    8
#define B_TR    4096
#define D1      256           // H*O

// LDS row pads (keep 16B alignment, break power-of-2 bank strides)
#define LDA0    132           // PREP + 4
#define LDA1    260           // D1 + 4

typedef __hip_bfloat16 bf16;

// Generic float load/store: T selects the raw dtype of the global buffer.
template <typename T>
__device__ __forceinline__ float ldv(const void* p, size_t i) {
    if constexpr (sizeof(T) == 4) return ((const float*)p)[i];
    else return __bfloat162float(((const bf16*)p)[i]);
}
template <typename T>
__device__ __forceinline__ float4 ld4(const void* p, size_t i) {
    if constexpr (sizeof(T) == 4) {
        return *(const float4*)((const float*)p + i);
    } else {
        float4 r;
        r.x = ldv<T>(p, i); r.y = ldv<T>(p, i + 1);
        r.z = ldv<T>(p, i + 2); r.w = ldv<T>(p, i + 3);
        return r;
    }
}
template <typename T>
__device__ __forceinline__ void stv(void* p, size_t i, float v) {
    if constexpr (sizeof(T) == 4) ((float*)p)[i] = v;
    else ((bf16*)p)[i] = __float2bfloat16(v);
}
template <typename T>
__device__ __forceinline__ bool active(const int* flag) {
    return *flag == (sizeof(T) == 4 ? 1 : 0);
}

__device__ __forceinline__ float wave_sum(float v) {
    #pragma unroll
    for (int off = 32; off > 0; off >>= 1) v += __shfl_xor(v, off, 64);
    return v;
}
// lane = og*4 + mg within a wave (mg = lane&3, og = lane>>2)
__device__ __forceinline__ float og_sum(float v) {
    v += __shfl_xor(v, 4, 64);  v += __shfl_xor(v, 8, 64);
    v += __shfl_xor(v, 16, 64); v += __shfl_xor(v, 32, 64);
    return v;
}
__device__ __forceinline__ float mg_sum(float v) {
    v += __shfl_xor(v, 1, 64); v += __shfl_xor(v, 2, 64); return v;
}
__device__ __forceinline__ float mg_max(float v) {
    v = fmaxf(v, __shfl_xor(v, 1, 64)); v = fmaxf(v, __shfl_xor(v, 2, 64)); return v;
}
__device__ __forceinline__ float eluf(float x) { return x > 0.f ? x : expf(x) - 1.f; }
__device__ __forceinline__ float4 elu4(float4 v) {
    v.x = eluf(v.x); v.y = eluf(v.y); v.z = eluf(v.z); v.w = eluf(v.w); return v;
}

#define FMA4C(acc, s, b) do { (acc).x += (s)*(b).x; (acc).y += (s)*(b).y; \
                              (acc).z += (s)*(b).z; (acc).w += (s)*(b).w; } while (0)
#define ZERO4(v) do { (v).x = 0.f; (v).y = 0.f; (v).z = 0.f; (v).w = 0.f; } while (0)

// ---------------------------------------------------------------------------
// Dtype detector (unchanged — R3-verified): flag=1 => fp32 buffers.
__global__ void k_detect(const unsigned* __restrict__ w, int* __restrict__ flag) {
    int t = threadIdx.x;  // 64
    int bad = 0;
    for (int i = t; i < 512; i += 64) {
        float v = __uint_as_float((w[i] & 0xffffu) << 16);
        if (!(fabsf(v) < 64.f)) bad++;
    }
    #pragma unroll
    for (int off = 32; off > 0; off >>= 1) bad += __shfl_xor(bad, off, 64);
    if (t == 0) *flag = (bad > 32) ? 1 : 0;
}

// ---------------------------------------------------------------------------
// all_feats0[n,p] = sum_d feats[n,d] * W_prep1[d,p]  — float4-blocked
template <typename T>
__global__ void k_prep_nodes(const void* __restrict__ feats,
                             const void* __restrict__ W,
                             float* __restrict__ out,
                             const int* __restrict__ flag) {
    if (!active<T>(flag)) return;
    int g = blockIdx.x * blockDim.x + threadIdx.x;
    if (g >= N_NODES * 32) return;
    int n = g >> 5, pg = g & 31;
    float4 acc; ZERO4(acc);
    #pragma unroll 8
    for (int d = 0; d < D_FEAT; ++d) {
        float f = ldv<T>(feats, (size_t)n * D_FEAT + d);
        float4 w4 = ld4<T>(W, (size_t)d * PREP + pg * 4);
        FMA4C(acc, f, w4);
    }
    *(float4*)(out + (size_t)n * PREP + pg * 4) = acc;
}

// ---------------------------------------------------------------------------
// Fused per-(mp, train-node) block. 4 waves = 4 heads; lane = og*4+mg.
// Each lane owns 4 output cols (og*4..+3) and 4 (or 8) interleaved rows (mg+4i).
template <typename T>
__global__ __launch_bounds__(256) void k_fused(
        const void* __restrict__ feats,
        const void* __restrict__ edge_emb_mp,   // [E, 32]
        const void* __restrict__ W_prep0,       // [64, 128]
        const void* __restrict__ epw_mp,        // [32, 128]
        const void* __restrict__ ewq,           // [H,128,64]
        const void* __restrict__ ewk,
        const void* __restrict__ nwq0,          // [H,128,64]
        const void* __restrict__ nwk0,
        const void* __restrict__ nwq1,          // [H,256,64]
        const void* __restrict__ nwk1,
        const int*  __restrict__ n2e_mp,        // [N,16]
        const int*  __restrict__ adj_mp,        // [E,2]
        const int*  __restrict__ tid,           // [B]
        const float* __restrict__ all_feats0,   // [N,128]
        float* __restrict__ xcat_mp,            // [B,512]
        const int* __restrict__ flag) {
    if (!active<T>(flag)) return;
    int b = blockIdx.x;
    int t = threadIdx.x;
    int h = t >> 6;
    int lane = t & 63;
    int mg = lane & 3, og = lane >> 2;

    __shared__ int   s_eid[S_NE];
    __shared__ int   s_nrow[2 * S_NE];
    __shared__ __align__(16) float s_emb[S_NE * E_DIMC];     // 2 KB
    __shared__ __align__(16) float s_f[D_FEAT];
    __shared__ __align__(16) float s_q0[PREP];
    __shared__ __align__(16) float s_eprep[S_NE * LDA0];     // 8.25 KB
    __shared__ __align__(16) float s_xn_pool[2 * S_NE * LDA0]; // 16.5 KB (xn, then nedge)
    __shared__ __align__(16) float s_out0[D1];
    float* s_nedge = s_xn_pool;   // overlay: 16*260=4160 <= 32*132=4224

    // ---- Preamble ----
    int tid_b = tid[b];
    if (t < S_NE)   s_eid[t] = n2e_mp[(size_t)tid_b * S_NE + t];
    if (t < D_FEAT) s_f[t] = ldv<T>(feats, (size_t)tid_b * D_FEAT + t);
    __syncthreads();

    if (t < 2 * S_NE) s_nrow[t] = adj_mp[(size_t)s_eid[t >> 1] * 2 + (t & 1)];
    {   // edge embeddings (512 floats, 2/thread)
        int j = t, s = j >> 5, d = j & 31;
        s_emb[j] = ldv<T>(edge_emb_mp, (size_t)s_eid[s] * E_DIMC + d);
        j = t + 256; s = j >> 5; d = j & 31;
        s_emb[j] = ldv<T>(edge_emb_mp, (size_t)s_eid[s] * E_DIMC + d);
    }
    if (t < PREP) {  // dummy row: feats[tid_b] @ W_prep0
        float a = 0.f;
        #pragma unroll
        for (int d = 0; d < D_FEAT; ++d) a += s_f[d] * ldv<T>(W_prep0, d * PREP + t);
        s_q0[t] = a;
    }
    __syncthreads();   // s_nrow, s_emb ready

    // xn gather: 32 rows x 128 floats as float4 (4 per thread)
    #pragma unroll
    for (int k = 0; k < 4; ++k) {
        int j = t + 256 * k;          // 0..1023
        int r = j >> 5, dc = j & 31;
        float4 v = *(const float4*)(all_feats0 + (size_t)s_nrow[r] * PREP + dc * 4);
        *(float4*)&s_xn_pool[r * LDA0 + dc * 4] = v;
    }
    // eprep: thread (s = t>>4, pg = t&15) computes eprep[s][pg*8..+7]
    {
        int s = t >> 4, pg = t & 15;
        float4 a0, a1; ZERO4(a0); ZERO4(a1);
        #pragma unroll
        for (int d = 0; d < E_DIMC; ++d) {
            float e = s_emb[s * E_DIMC + d];
            float4 w0 = ld4<T>(epw_mp, (size_t)d * PREP + pg * 8);
            float4 w1 = ld4<T>(epw_mp, (size_t)d * PREP + pg * 8 + 4);
            FMA4C(a0, e, w0); FMA4C(a1, e, w1);
        }
        *(float4*)&s_eprep[s * LDA0 + pg * 8]     = a0;
        *(float4*)&s_eprep[s * LDA0 + pg * 8 + 4] = a1;
    }
    __syncthreads();   // s_xn, s_eprep, s_q0 ready

    // ---- Phase B: L0 edge attention. Q=eprep@ewq[h] (16x64), K=xn@ewk[h] (32x64)
    float4 aq[4], ak[8];
    #pragma unroll
    for (int i = 0; i < 4; ++i) ZERO4(aq[i]);
    #pragma unroll
    for (int i = 0; i < 8; ++i) ZERO4(ak[i]);
    {
        size_t wb = (size_t)h * PREP * O_DIM + og * 4;
        for (int kk = 0; kk < PREP; kk += 4) {
            float4 bq[4], bk[4];
            #pragma unroll
            for (int j = 0; j < 4; ++j) {
                bq[j] = ld4<T>(ewq, wb + (size_t)(kk + j) * O_DIM);
                bk[j] = ld4<T>(ewk, wb + (size_t)(kk + j) * O_DIM);
            }
            #pragma unroll
            for (int i = 0; i < 4; ++i) {   // Q rows s = mg+4i
                float4 a = *(const float4*)&s_eprep[(mg + 4 * i) * LDA0 + kk];
                FMA4C(aq[i], a.x, bq[0]); FMA4C(aq[i], a.y, bq[1]);
                FMA4C(aq[i], a.z, bq[2]); FMA4C(aq[i], a.w, bq[3]);
            }
            #pragma unroll
            for (int i = 0; i < 8; ++i) {   // K rows r = 2mg+(i&1)+8(i>>1)
                int r = 2 * mg + (i & 1) + 8 * (i >> 1);
                float4 a = *(const float4*)&s_xn_pool[r * LDA0 + kk];
                FMA4C(ak[i], a.x, bk[0]); FMA4C(ak[i], a.y, bk[1]);
                FMA4C(ak[i], a.z, bk[2]); FMA4C(ak[i], a.w, bk[3]);
            }
        }
    }
    __syncthreads();   // all waves done reading s_xn (nedge overlays it)

    // B-post: per lane, slots s = mg+4j; neighbors kA=ak[2j], kB=ak[2j+1]
    #pragma unroll
    for (int j = 0; j < 4; ++j) {
        int s = mg + 4 * j;
        float4 q = aq[j], kA = ak[2 * j], kB = ak[2 * j + 1];
        float lA = og_sum(q.x * kA.x + q.y * kA.y + q.z * kA.z + q.w * kA.w) * 0.125f;
        float lB = og_sum(q.x * kB.x + q.y * kB.y + q.z * kB.z + q.w * kB.w) * 0.125f;
        float m = fmaxf(lA, lB);
        float eA = expf(lA - m), eB = expf(lB - m);
        float inv = 1.f / (eA + eB);
        float4 v;
        v.x = q.x + (eA * kA.x + eB * kB.x) * inv;
        v.y = q.y + (eA * kA.y + eB * kB.y) * inv;
        v.z = q.z + (eA * kA.z + eB * kB.z) * inv;
        v.w = q.w + (eA * kA.w + eB * kB.w) * inv;
        *(float4*)&s_nedge[s * LDA1 + h * O_DIM + og * 4] = elu4(v);
    }

    // ---- Phase C: L0 node attention. q = q0@nwq0[h], K = eprep@nwk0[h]
    float4 zq; ZERO4(zq);
    float4 zk[4];
    #pragma unroll
    for (int i = 0; i < 4; ++i) ZERO4(zk[i]);
    {
        size_t wb = (size_t)h * PREP * O_DIM + og * 4;
        for (int kk = 0; kk < PREP; kk += 4) {
            float4 q4 = *(const float4*)&s_q0[kk];
            float4 bq[4], bk[4];
            #pragma unroll
            for (int j = 0; j < 4; ++j) {
                bq[j] = ld4<T>(nwq0, wb + (size_t)(kk + j) * O_DIM);
                bk[j] = ld4<T>(nwk0, wb + (size_t)(kk + j) * O_DIM);
            }
            FMA4C(zq, q4.x, bq[0]); FMA4C(zq, q4.y, bq[1]);
            FMA4C(zq, q4.z, bq[2]); FMA4C(zq, q4.w, bq[3]);
            #pragma unroll
            for (int i = 0; i < 4; ++i) {
                float4 a = *(const float4*)&s_eprep[(mg + 4 * i) * LDA0 + kk];
                FMA4C(zk[i], a.x, bk[0]); FMA4C(zk[i], a.y, bk[1]);
                FMA4C(zk[i], a.z, bk[2]); FMA4C(zk[i], a.w, bk[3]);
            }
        }
    }
    {   // C-post: softmax over 16 slots, combine, ELU -> s_out0 + xcat[:,0:256]
        float lg[4];
        #pragma unroll
        for (int j = 0; j < 4; ++j)
            lg[j] = og_sum(zq.x * zk[j].x + zq.y * zk[j].y +
                           zq.z * zk[j].z + zq.w * zk[j].w) * 0.125f;
        float mx = fmaxf(fmaxf(lg[0], lg[1]), fmaxf(lg[2], lg[3]));
        mx = mg_max(mx);
        float ea[4], ssum = 0.f;
        #pragma unroll
        for (int j = 0; j < 4; ++j) { ea[j] = expf(lg[j] - mx); ssum += ea[j]; }
        ssum = mg_sum(ssum);
        float inv = 1.f / ssum;
        float4 part; ZERO4(part);
        #pragma unroll
        for (int j = 0; j < 4; ++j) FMA4C(part, ea[j], zk[j]);
        part.x = mg_sum(part.x); part.y = mg_sum(part.y);
        part.z = mg_sum(part.z); part.w = mg_sum(part.w);
        float4 v;
        v.x = zq.x + part.x * inv; v.y = zq.y + part.y * inv;
        v.z = zq.z + part.z * inv; v.w = zq.w + part.w * inv;
        v = elu4(v);
        if (mg == 0) {
            *(float4*)&s_out0[h * O_DIM + og * 4] = v;
            *(float4*)(xcat_mp + (size_t)b * (2 * D1) + h * O_DIM + og * 4) = v;
        }
    }
    __syncthreads();   // s_out0 complete (all heads), nedge complete

    // ---- Phase D: L1 node attention. q = out0@nwq1[h], K = nedge@nwk1[h], K-dim=256
    ZERO4(zq);
    #pragma unroll
    for (int i = 0; i < 4; ++i) ZERO4(zk[i]);
    {
        size_t wb = (size_t)h * D1 * O_DIM + og * 4;
        for (int kk = 0; kk < D1; kk += 4) {
            float4 q4 = *(const float4*)&s_out0[kk];
            float4 bq[4], bk[4];
            #pragma unroll
            for (int j = 0; j < 4; ++j) {
                bq[j] = ld4<T>(nwq1, wb + (size_t)(kk + j) * O_DIM);
                bk[j] = ld4<T>(nwk1, wb + (size_t)(kk + j) * O_DIM);
            }
            FMA4C(zq, q4.x, bq[0]); FMA4C(zq, q4.y, bq[1]);
            FMA4C(zq, q4.z, bq[2]); FMA4C(zq, q4.w, bq[3]);
            #pragma unroll
            for (int i = 0; i < 4; ++i) {
                float4 a = *(const float4*)&s_nedge[(mg + 4 * i) * LDA1 + kk];
                FMA4C(zk[i], a.x, bk[0]); FMA4C(zk[i], a.y, bk[1]);
                FMA4C(zk[i], a.z, bk[2]); FMA4C(zk[i], a.w, bk[3]);
            }
        }
    }
    {   // D-post -> xcat[:,256:512]
        float lg[4];
        #pragma unroll
        for (int j = 0; j < 4; ++j)
            lg[j] = og_sum(zq.x * zk[j].x + zq.y * zk[j].y +
                           zq.z * zk[j].z + zq.w * zk[j].w) * 0.125f;
        float mx = fmaxf(fmaxf(lg[0], lg[1]), fmaxf(lg[2], lg[3]));
        mx = mg_max(mx);
        float ea[4], ssum = 0.f;
        #pragma unroll
        for (int j = 0; j < 4; ++j) { ea[j] = expf(lg[j] - mx); ssum += ea[j]; }
        ssum = mg_sum(ssum);
        float inv = 1.f / ssum;
        float4 part; ZERO4(part);
        #pragma unroll
        for (int j = 0; j < 4; ++j) FMA4C(part, ea[j], zk[j]);
        part.x = mg_sum(part.x); part.y = mg_sum(part.y);
        part.z = mg_sum(part.z); part.w = mg_sum(part.w);
        float4 v;
        v.x = zq.x + part.x * inv; v.y = zq.y + part.y * inv;
        v.z = zq.z + part.z * inv; v.w = zq.w + part.w * inv;
        v = elu4(v);
        if (mg == 0)
            *(float4*)(xcat_mp + (size_t)b * (2 * D1) + D1 + h * O_DIM + og * 4) = v;
    }
}

// ---------------------------------------------------------------------------
// gate_pre[m,b] = sum_e vg[e] * tanh( sum_d x[m,b,d] * Wg[d,e] )
template <typename T>
__global__ void k_gate(const float* __restrict__ xcat,
                       const void* __restrict__ Wg, const void* __restrict__ vg,
                       float* __restrict__ gate_pre,
                       const int* __restrict__ flag) {
    if (!active<T>(flag)) return;
    int mb = blockIdx.x;
    int t = threadIdx.x;   // 128
    __shared__ float xr[2 * D1];
    for (int idx = t; idx < 2 * D1; idx += 128) xr[idx] = xcat[(size_t)mb * (2 * D1) + idx];
    __syncthreads();
    float acc = 0.f;
    for (int d = 0; d < 2 * D1; ++d) acc += xr[d] * ldv<T>(Wg, d * PREP + t);
    float gp = tanhf(acc) * ldv<T>(vg, t);
    __shared__ float red[128];
    red[t] = gp;
    __syncthreads();
    for (int s = 64; s > 0; s >>= 1) { if (t < s) red[t] += red[t + s]; __syncthreads(); }
    if (t == 0) gate_pre[mb] = red[0];
}

// softmax over mp, pool, FC -> logits; write logits then gate
template <typename T>
__global__ void k_final(const float* __restrict__ xcat,
                        const float* __restrict__ gate_pre,
                        const void* __restrict__ Wfc, const void* __restrict__ bfc,
                        void* __restrict__ out,
                        const int* __restrict__ flag) {
    if (!active<T>(flag)) return;
    int b = blockIdx.x;
    int t = threadIdx.x;  // 64
    float g0 = gate_pre[b], g1 = gate_pre[B_TR + b];
    float mx = fmaxf(g0, g1);
    float e0 = expf(g0 - mx), e1 = expf(g1 - mx);
    float inv = 1.f / (e0 + e1);
    float w0 = e0 * inv, w1 = e1 * inv;
    __shared__ float pooled[2 * D1];
    for (int d = t; d < 2 * D1; d += 64)
        pooled[d] = w0 * xcat[(size_t)b * (2 * D1) + d]
                  + w1 * xcat[(size_t)(B_TR + b) * (2 * D1) + d];
    __syncthreads();
    if (t < NCLS) {
        float acc = ldv<T>(bfc, t);
        for (int d = 0; d < 2 * D1; ++d) acc += pooled[d] * ldv<T>(Wfc, d * NCLS + t);
        stv<T>(out, (size_t)b * NCLS + t, acc);
    }
    if (t == 8) stv<T>(out, (size_t)B_TR * NCLS + b, w0);
    if (t == 9) stv<T>(out, (size_t)B_TR * NCLS + B_TR + b, w1);
}

// ---------------------------------------------------------------------------
extern "C" void kernel_launch(void* const* d_in, const int* in_sizes, int n_in,
                              void* d_out, int out_size, void* d_ws, size_t ws_size,
                              hipStream_t stream) {
    const void* feats       = d_in[0];
    const void* edge_emb    = d_in[1];
    const void* W_prep0     = d_in[2];
    const void* edge_prep_w = d_in[4];
    const void* e_wq0       = d_in[5];
    const void* e_wk0       = d_in[6];
    // d_in[7], d_in[8]: edge_wq_l1 / edge_wk_l1 — dead (layer-1 edge update unused)
    const void* n_wq0       = d_in[9];
    const void* n_wk0       = d_in[10];
    const void* n_wq1       = d_in[11];
    const void* n_wk1       = d_in[12];
    const void* Wg          = d_in[13];
    const void* vg          = d_in[14];
    const void* Wfc         = d_in[15];
    const void* bfc         = d_in[16];
    const int*  n2e         = (const int*)d_in[17];
    const int*  adj         = (const int*)d_in[18];
    const int*  tid         = (const int*)d_in[19];

    float* ws         = (float*)d_ws;
    float* all_feats0 = ws;                                    // N*PREP      (10.24 MB)
    float* xcat       = all_feats0 + (size_t)N_NODES * PREP;   // NMP*B*512   (16.78 MB)
    float* gate_pre   = xcat + (size_t)NMP * B_TR * 2 * D1;    // NMP*B
    int*   flag       = (int*)(gate_pre + NMP * B_TR);

    k_detect<<<1, 64, 0, stream>>>((const unsigned*)feats, flag);

    #define LAUNCH_ALL(T)                                                          \
    do {                                                                           \
        const size_t esz = sizeof(T);                                              \
        k_prep_nodes<T><<<(N_NODES * 32 + 255) / 256, 256, 0, stream>>>(           \
            feats, d_in[3], all_feats0, flag);                                     \
        for (int mp = 0; mp < NMP; ++mp) {                                         \
            k_fused<T><<<B_TR, 256, 0, stream>>>(                                  \
                feats,                                                             \
                (const char*)edge_emb + esz * (size_t)mp * E_EDGES * E_DIMC,       \
                W_prep0,                                                           \
                (const char*)edge_prep_w + esz * (size_t)mp * E_DIMC * PREP,       \
                (const char*)e_wq0 + esz * (size_t)mp * H_HEADS * PREP * O_DIM,    \
                (const char*)e_wk0 + esz * (size_t)mp * H_HEADS * PREP * O_DIM,    \
                (const char*)n_wq0 + esz * (size_t)mp * H_HEADS * PREP * O_DIM,    \
                (const char*)n_wk0 + esz * (size_t)mp * H_HEADS * PREP * O_DIM,    \
                (const char*)n_wq1 + esz * (size_t)mp * H_HEADS * D1 * O_DIM,      \
                (const char*)n_wk1 + esz * (size_t)mp * H_HEADS * D1 * O_DIM,      \
                n2e + (size_t)mp * N_NODES * S_NE,                                 \
                adj + (size_t)mp * E_EDGES * 2,                                    \
                tid, all_feats0,                                                   \
                xcat + (size_t)mp * B_TR * 2 * D1, flag);                          \
        }                                                                          \
        k_gate<T><<<NMP * B_TR, 128, 0, stream>>>(xcat, Wg, vg, gate_pre, flag);   \
        k_final<T><<<B_TR, 64, 0, stream>>>(xcat, gate_pre, Wfc, bfc, d_out, flag);\
    } while (0)

    LAUNCH_ALL(float);
    LAUNCH_ALL(bf16);
    #undef LAUNCH_ALL
}

// Round 5
// 1430.862 us; speedup vs baseline: 1.7709x; 1.0083x over previous
//
#include <hip/hip_runtime.h>
#include <hip/hip_bf16.h>
#include <math.h>

// Problem dims
#define N_NODES 20000
#define S_NE    16
#define E_EDGES 160000
#define NMP     2
#define H_HEADS 4
#define O_DIM   64
#define D_FEAT  64
#define E_DIMC  32
#define PREP    128
#define NCLS    8
#define B_TR    4096
#define D1      256           // H*O
#define NSLOT   (B_TR * S_NE) // 65536

// LDS row pads for fused fallback
#define LDA0    132
#define LDA1    260

typedef __hip_bfloat16 bf16;

template <typename T>
__device__ __forceinline__ float ldv(const void* p, size_t i) {
    if constexpr (sizeof(T) == 4) return ((const float*)p)[i];
    else return __bfloat162float(((const bf16*)p)[i]);
}
template <typename T>
__device__ __forceinline__ float4 ld4(const void* p, size_t i) {
    if constexpr (sizeof(T) == 4) {
        return *(const float4*)((const float*)p + i);
    } else {
        float4 r;
        r.x = ldv<T>(p, i); r.y = ldv<T>(p, i + 1);
        r.z = ldv<T>(p, i + 2); r.w = ldv<T>(p, i + 3);
        return r;
    }
}
template <typename T>
__device__ __forceinline__ void stv(void* p, size_t i, float v) {
    if constexpr (sizeof(T) == 4) ((float*)p)[i] = v;
    else ((bf16*)p)[i] = __float2bfloat16(v);
}
template <typename T>
__device__ __forceinline__ bool active(const int* flag) {
    return *flag == (sizeof(T) == 4 ? 1 : 0);
}

__device__ __forceinline__ float wave_sum(float v) {
    #pragma unroll
    for (int off = 32; off > 0; off >>= 1) v += __shfl_xor(v, off, 64);
    return v;
}
__device__ __forceinline__ float og_sum(float v) {
    v += __shfl_xor(v, 4, 64);  v += __shfl_xor(v, 8, 64);
    v += __shfl_xor(v, 16, 64); v += __shfl_xor(v, 32, 64);
    return v;
}
__device__ __forceinline__ float mg_sum(float v) {
    v += __shfl_xor(v, 1, 64); v += __shfl_xor(v, 2, 64); return v;
}
__device__ __forceinline__ float mg_max(float v) {
    v = fmaxf(v, __shfl_xor(v, 1, 64)); v = fmaxf(v, __shfl_xor(v, 2, 64)); return v;
}
__device__ __forceinline__ float eluf(float x) { return x > 0.f ? x : expf(x) - 1.f; }
__device__ __forceinline__ float4 elu4(float4 v) {
    v.x = eluf(v.x); v.y = eluf(v.y); v.z = eluf(v.z); v.w = eluf(v.w); return v;
}

#define FMA4C(acc, s, b) do { (acc).x += (s)*(b).x; (acc).y += (s)*(b).y; \
                              (acc).z += (s)*(b).z; (acc).w += (s)*(b).w; } while (0)
#define ZERO4(v) do { (v).x = 0.f; (v).y = 0.f; (v).z = 0.f; (v).w = 0.f; } while (0)

// ---------------------------------------------------------------------------
// Dtype detector (R3-verified): flag=1 => fp32 buffers.
__global__ void k_detect(const unsigned* __restrict__ w, int* __restrict__ flag) {
    int t = threadIdx.x;
    int bad = 0;
    for (int i = t; i < 512; i += 64) {
        float v = __uint_as_float((w[i] & 0xffffu) << 16);
        if (!(fabsf(v) < 64.f)) bad++;
    }
    #pragma unroll
    for (int off = 32; off > 0; off >>= 1) bad += __shfl_xor(bad, off, 64);
    if (t == 0) *flag = (bad > 32) ? 1 : 0;
}

// ---------------------------------------------------------------------------
// all_feats0[n,p] = feats @ W_prep1
template <typename T>
__global__ void k_prep_nodes(const void* __restrict__ feats,
                             const void* __restrict__ W,
                             float* __restrict__ out,
                             const int* __restrict__ flag) {
    if (!active<T>(flag)) return;
    int g = blockIdx.x * blockDim.x + threadIdx.x;
    if (g >= N_NODES * 32) return;
    int n = g >> 5, pg = g & 31;
    float4 acc; ZERO4(acc);
    #pragma unroll 8
    for (int d = 0; d < D_FEAT; ++d) {
        float f = ldv<T>(feats, (size_t)n * D_FEAT + d);
        float4 w4 = ld4<T>(W, (size_t)d * PREP + pg * 4);
        FMA4C(acc, f, w4);
    }
    *(float4*)(out + (size_t)n * PREP + pg * 4) = acc;
}

// dummy[b,:] = feats[tid[b]] @ W_prep0
template <typename T>
__global__ void k_prep_dummy(const void* __restrict__ feats,
                             const void* __restrict__ W,
                             const int* __restrict__ tid,
                             float* __restrict__ out,
                             const int* __restrict__ flag) {
    if (!active<T>(flag)) return;
    int g = blockIdx.x * blockDim.x + threadIdx.x;
    if (g >= B_TR * 32) return;
    int b = g >> 5, pg = g & 31;
    int n = tid[b];
    float4 acc; ZERO4(acc);
    #pragma unroll 8
    for (int d = 0; d < D_FEAT; ++d) {
        float f = ldv<T>(feats, (size_t)n * D_FEAT + d);
        float4 w4 = ld4<T>(W, (size_t)d * PREP + pg * 4);
        FMA4C(acc, f, w4);
    }
    *(float4*)(out + (size_t)b * PREP + pg * 4) = acc;
}

// slot tables: eid[i], adjA[i], adjB[i] for i = b*16+s
template <typename T>
__global__ void k_slot_setup(const int* __restrict__ n2e_mp,
                             const int* __restrict__ adj_mp,
                             const int* __restrict__ tid,
                             int* __restrict__ eid,
                             int* __restrict__ adjA,
                             int* __restrict__ adjB,
                             const int* __restrict__ flag) {
    if (!active<T>(flag)) return;
    int i = blockIdx.x * blockDim.x + threadIdx.x;
    if (i >= NSLOT) return;
    int b = i >> 4, s = i & 15;
    int e = n2e_mp[(size_t)tid[b] * S_NE + s];
    eid[i] = e;
    adjA[i] = adj_mp[(size_t)e * 2 + 0];
    adjB[i] = adj_mp[(size_t)e * 2 + 1];
}

// ---------------------------------------------------------------------------
// Dense register-tiled GEMM: C[m, h*64 + n] = sum_k A[m,k] * B[h*sH + k*sD + n]
// BM=64, BN=64 (one h per blockIdx.y), BK=32. 256 thr, 4x4 acc/thread.
// A rows optionally gathered via Aidx. A dtype TA, B dtype T, C fp32.
template <typename TA, typename T>
__global__ __launch_bounds__(256) void k_gemm(
        const void* __restrict__ A, const int* __restrict__ Aidx, int strideA,
        const void* __restrict__ B, int sH, int sD,
        float* __restrict__ C, int ldC, int M, int K,
        const int* __restrict__ flag) {
    if (!active<T>(flag)) return;
    int bm = blockIdx.x * 64;
    int h  = blockIdx.y;
    int t  = threadIdx.x;
    int tx = t & 15, ty = t >> 4;

    __shared__ float As[32][68];   // [k][m]
    __shared__ float Bs[32][68];   // [k][n]

    float acc[4][4] = {{0.f}};
    int arow = t >> 3, kq = (t & 7) * 4;
    int brow = t >> 4, nq = (t & 15) * 4;

    for (int k0 = 0; k0 < K; k0 += 32) {
        #pragma unroll
        for (int c = 0; c < 2; ++c) {
            int rm = arow + 32 * c;
            int gr = bm + rm;
            gr = (gr < M) ? gr : 0;
            size_t row = Aidx ? (size_t)Aidx[gr] : (size_t)gr;
            float4 a = ld4<TA>(A, row * strideA + k0 + kq);
            As[kq + 0][rm] = a.x; As[kq + 1][rm] = a.y;
            As[kq + 2][rm] = a.z; As[kq + 3][rm] = a.w;
        }
        #pragma unroll
        for (int c = 0; c < 2; ++c) {
            int rk = brow + 16 * c;
            float4 b = ld4<T>(B, (size_t)h * sH + (size_t)(k0 + rk) * sD + nq);
            *(float4*)&Bs[rk][nq] = b;
        }
        __syncthreads();
        #pragma unroll
        for (int kk = 0; kk < 32; ++kk) {
            float4 av = *(const float4*)&As[kk][ty * 4];
            float4 bv = *(const float4*)&Bs[kk][tx * 4];
            float am[4] = {av.x, av.y, av.z, av.w};
            #pragma unroll
            for (int i = 0; i < 4; ++i) {
                acc[i][0] += am[i] * bv.x; acc[i][1] += am[i] * bv.y;
                acc[i][2] += am[i] * bv.z; acc[i][3] += am[i] * bv.w;
            }
        }
        __syncthreads();
    }
    #pragma unroll
    for (int i = 0; i < 4; ++i) {
        int m = bm + ty * 4 + i;
        if (m < M) {
            float4 st; st.x = acc[i][0]; st.y = acc[i][1];
            st.z = acc[i][2]; st.w = acc[i][3];
            *(float4*)&C[(size_t)m * ldC + h * 64 + tx * 4] = st;
        }
    }
}

// ---------------------------------------------------------------------------
// Edge attention (L0 edge update) per slot: nedge = elu(q + softmax2-combo)
template <typename T>
__global__ void k_edge_attn(const float* __restrict__ Qe,
                            const float* __restrict__ Kn,
                            const int* __restrict__ adjA,
                            const int* __restrict__ adjB,
                            float* __restrict__ nedge,
                            const int* __restrict__ flag) {
    if (!active<T>(flag)) return;
    int slot = blockIdx.x * 4 + (threadIdx.x >> 6);
    int o = threadIdx.x & 63;
    size_t ra = (size_t)adjA[slot] * D1, rb = (size_t)adjB[slot] * D1;
    size_t qs = (size_t)slot * D1;
    #pragma unroll
    for (int h = 0; h < H_HEADS; ++h) {
        int c = h * O_DIM + o;
        float q  = Qe[qs + c];
        float kA = Kn[ra + c];
        float kB = Kn[rb + c];
        float lA = wave_sum(q * kA) * 0.125f;
        float lB = wave_sum(q * kB) * 0.125f;
        float m = fmaxf(lA, lB);
        float eA = expf(lA - m), eB = expf(lB - m);
        float inv = 1.f / (eA + eB);
        nedge[qs + c] = eluf(q + (eA * kA + eB * kB) * inv);
    }
}

// Node attention per train node: K rows are the node's 16 contiguous slots.
template <typename T>
__global__ void k_node_attn(const float* __restrict__ qbuf,   // [B,256]
                            const float* __restrict__ Kbuf,   // [NSLOT,256]
                            float* __restrict__ outA,         // [B,256] or null
                            float* __restrict__ xcat,         // [B,512]
                            int xoff,
                            const int* __restrict__ flag) {
    if (!active<T>(flag)) return;
    int b = blockIdx.x;
    int t = threadIdx.x;
    int h = t >> 6, o = t & 63;
    int c = h * O_DIM + o;
    float q = qbuf[(size_t)b * D1 + c];
    float k[S_NE], lg[S_NE];
    #pragma unroll
    for (int s = 0; s < S_NE; ++s) {
        k[s] = Kbuf[((size_t)b * S_NE + s) * D1 + c];
        lg[s] = wave_sum(q * k[s]) * 0.125f;
    }
    float mx = lg[0];
    #pragma unroll
    for (int s = 1; s < S_NE; ++s) mx = fmaxf(mx, lg[s]);
    float sum = 0.f;
    #pragma unroll
    for (int s = 0; s < S_NE; ++s) { lg[s] = expf(lg[s] - mx); sum += lg[s]; }
    float inv = 1.f / sum;
    float agg = 0.f;
    #pragma unroll
    for (int s = 0; s < S_NE; ++s) agg += lg[s] * k[s];
    float v = eluf(q + agg * inv);
    if (outA) outA[(size_t)b * D1 + c] = v;
    xcat[(size_t)b * (2 * D1) + xoff + c] = v;
}

// ---------------------------------------------------------------------------
// Fused fallback (R4 kernel, verbatim) — used when ws_size is too small.
template <typename T>
__global__ __launch_bounds__(256) void k_fused(
        const void* __restrict__ feats,
        const void* __restrict__ edge_emb_mp,
        const void* __restrict__ W_prep0,
        const void* __restrict__ epw_mp,
        const void* __restrict__ ewq,
        const void* __restrict__ ewk,
        const void* __restrict__ nwq0,
        const void* __restrict__ nwk0,
        const void* __restrict__ nwq1,
        const void* __restrict__ nwk1,
        const int*  __restrict__ n2e_mp,
        const int*  __restrict__ adj_mp,
        const int*  __restrict__ tid,
        const float* __restrict__ all_feats0,
        float* __restrict__ xcat_mp,
        const int* __restrict__ flag) {
    if (!active<T>(flag)) return;
    int b = blockIdx.x;
    int t = threadIdx.x;
    int h = t >> 6;
    int lane = t & 63;
    int mg = lane & 3, og = lane >> 2;

    __shared__ int   s_eid[S_NE];
    __shared__ int   s_nrow[2 * S_NE];
    __shared__ __align__(16) float s_emb[S_NE * E_DIMC];
    __shared__ __align__(16) float s_f[D_FEAT];
    __shared__ __align__(16) float s_q0[PREP];
    __shared__ __align__(16) float s_eprep[S_NE * LDA0];
    __shared__ __align__(16) float s_xn_pool[2 * S_NE * LDA0];
    __shared__ __align__(16) float s_out0[D1];
    float* s_nedge = s_xn_pool;

    int tid_b = tid[b];
    if (t < S_NE)   s_eid[t] = n2e_mp[(size_t)tid_b * S_NE + t];
    if (t < D_FEAT) s_f[t] = ldv<T>(feats, (size_t)tid_b * D_FEAT + t);
    __syncthreads();

    if (t < 2 * S_NE) s_nrow[t] = adj_mp[(size_t)s_eid[t >> 1] * 2 + (t & 1)];
    {
        int j = t, s = j >> 5, d = j & 31;
        s_emb[j] = ldv<T>(edge_emb_mp, (size_t)s_eid[s] * E_DIMC + d);
        j = t + 256; s = j >> 5; d = j & 31;
        s_emb[j] = ldv<T>(edge_emb_mp, (size_t)s_eid[s] * E_DIMC + d);
    }
    if (t < PREP) {
        float a = 0.f;
        #pragma unroll
        for (int d = 0; d < D_FEAT; ++d) a += s_f[d] * ldv<T>(W_prep0, d * PREP + t);
        s_q0[t] = a;
    }
    __syncthreads();

    #pragma unroll
    for (int k = 0; k < 4; ++k) {
        int j = t + 256 * k;
        int r = j >> 5, dc = j & 31;
        float4 v = *(const float4*)(all_feats0 + (size_t)s_nrow[r] * PREP + dc * 4);
        *(float4*)&s_xn_pool[r * LDA0 + dc * 4] = v;
    }
    {
        int s = t >> 4, pg = t & 15;
        float4 a0, a1; ZERO4(a0); ZERO4(a1);
        #pragma unroll
        for (int d = 0; d < E_DIMC; ++d) {
            float e = s_emb[s * E_DIMC + d];
            float4 w0 = ld4<T>(epw_mp, (size_t)d * PREP + pg * 8);
            float4 w1 = ld4<T>(epw_mp, (size_t)d * PREP + pg * 8 + 4);
            FMA4C(a0, e, w0); FMA4C(a1, e, w1);
        }
        *(float4*)&s_eprep[s * LDA0 + pg * 8]     = a0;
        *(float4*)&s_eprep[s * LDA0 + pg * 8 + 4] = a1;
    }
    __syncthreads();

    float4 aq[4], ak[8];
    #pragma unroll
    for (int i = 0; i < 4; ++i) ZERO4(aq[i]);
    #pragma unroll
    for (int i = 0; i < 8; ++i) ZERO4(ak[i]);
    {
        size_t wb = (size_t)h * PREP * O_DIM + og * 4;
        for (int kk = 0; kk < PREP; kk += 4) {
            float4 bq[4], bk[4];
            #pragma unroll
            for (int j = 0; j < 4; ++j) {
                bq[j] = ld4<T>(ewq, wb + (size_t)(kk + j) * O_DIM);
                bk[j] = ld4<T>(ewk, wb + (size_t)(kk + j) * O_DIM);
            }
            #pragma unroll
            for (int i = 0; i < 4; ++i) {
                float4 a = *(const float4*)&s_eprep[(mg + 4 * i) * LDA0 + kk];
                FMA4C(aq[i], a.x, bq[0]); FMA4C(aq[i], a.y, bq[1]);
                FMA4C(aq[i], a.z, bq[2]); FMA4C(aq[i], a.w, bq[3]);
            }
            #pragma unroll
            for (int i = 0; i < 8; ++i) {
                int r = 2 * mg + (i & 1) + 8 * (i >> 1);
                float4 a = *(const float4*)&s_xn_pool[r * LDA0 + kk];
                FMA4C(ak[i], a.x, bk[0]); FMA4C(ak[i], a.y, bk[1]);
                FMA4C(ak[i], a.z, bk[2]); FMA4C(ak[i], a.w, bk[3]);
            }
        }
    }
    __syncthreads();

    #pragma unroll
    for (int j = 0; j < 4; ++j) {
        int s = mg + 4 * j;
        float4 q = aq[j], kA = ak[2 * j], kB = ak[2 * j + 1];
        float lA = og_sum(q.x * kA.x + q.y * kA.y + q.z * kA.z + q.w * kA.w) * 0.125f;
        float lB = og_sum(q.x * kB.x + q.y * kB.y + q.z * kB.z + q.w * kB.w) * 0.125f;
        float m = fmaxf(lA, lB);
        float eA = expf(lA - m), eB = expf(lB - m);
        float inv = 1.f / (eA + eB);
        float4 v;
        v.x = q.x + (eA * kA.x + eB * kB.x) * inv;
        v.y = q.y + (eA * kA.y + eB * kB.y) * inv;
        v.z = q.z + (eA * kA.z + eB * kB.z) * inv;
        v.w = q.w + (eA * kA.w + eB * kB.w) * inv;
        *(float4*)&s_nedge[s * LDA1 + h * O_DIM + og * 4] = elu4(v);
    }

    float4 zq; ZERO4(zq);
    float4 zk[4];
    #pragma unroll
    for (int i = 0; i < 4; ++i) ZERO4(zk[i]);
    {
        size_t wb = (size_t)h * PREP * O_DIM + og * 4;
        for (int kk = 0; kk < PREP; kk += 4) {
            float4 q4 = *(const float4*)&s_q0[kk];
            float4 bq[4], bk[4];
            #pragma unroll
            for (int j = 0; j < 4; ++j) {
                bq[j] = ld4<T>(nwq0, wb + (size_t)(kk + j) * O_DIM);
                bk[j] = ld4<T>(nwk0, wb + (size_t)(kk + j) * O_DIM);
            }
            FMA4C(zq, q4.x, bq[0]); FMA4C(zq, q4.y, bq[1]);
            FMA4C(zq, q4.z, bq[2]); FMA4C(zq, q4.w, bq[3]);
            #pragma unroll
            for (int i = 0; i < 4; ++i) {
                float4 a = *(const float4*)&s_eprep[(mg + 4 * i) * LDA0 + kk];
                FMA4C(zk[i], a.x, bk[0]); FMA4C(zk[i], a.y, bk[1]);
                FMA4C(zk[i], a.z, bk[2]); FMA4C(zk[i], a.w, bk[3]);
            }
        }
    }
    {
        float lg[4];
        #pragma unroll
        for (int j = 0; j < 4; ++j)
            lg[j] = og_sum(zq.x * zk[j].x + zq.y * zk[j].y +
                           zq.z * zk[j].z + zq.w * zk[j].w) * 0.125f;
        float mx = fmaxf(fmaxf(lg[0], lg[1]), fmaxf(lg[2], lg[3]));
        mx = mg_max(mx);
        float ea[4], ssum = 0.f;
        #pragma unroll
        for (int j = 0; j < 4; ++j) { ea[j] = expf(lg[j] - mx); ssum += ea[j]; }
        ssum = mg_sum(ssum);
        float inv = 1.f / ssum;
        float4 part; ZERO4(part);
        #pragma unroll
        for (int j = 0; j < 4; ++j) FMA4C(part, ea[j], zk[j]);
        part.x = mg_sum(part.x); part.y = mg_sum(part.y);
        part.z = mg_sum(part.z); part.w = mg_sum(part.w);
        float4 v;
        v.x = zq.x + part.x * inv; v.y = zq.y + part.y * inv;
        v.z = zq.z + part.z * inv; v.w = zq.w + part.w * inv;
        v = elu4(v);
        if (mg == 0) {
            *(float4*)&s_out0[h * O_DIM + og * 4] = v;
            *(float4*)(xcat_mp + (size_t)b * (2 * D1) + h * O_DIM + og * 4) = v;
        }
    }
    __syncthreads();

    ZERO4(zq);
    #pragma unroll
    for (int i = 0; i < 4; ++i) ZERO4(zk[i]);
    {
        size_t wb = (size_t)h * D1 * O_DIM + og * 4;
        for (int kk = 0; kk < D1; kk += 4) {
            float4 q4 = *(const float4*)&s_out0[kk];
            float4 bq[4], bk[4];
            #pragma unroll
            for (int j = 0; j < 4; ++j) {
                bq[j] = ld4<T>(nwq1, wb + (size_t)(kk + j) * O_DIM);
                bk[j] = ld4<T>(nwk1, wb + (size_t)(kk + j) * O_DIM);
            }
            FMA4C(zq, q4.x, bq[0]); FMA4C(zq, q4.y, bq[1]);
            FMA4C(zq, q4.z, bq[2]); FMA4C(zq, q4.w, bq[3]);
            #pragma unroll
            for (int i = 0; i < 4; ++i) {
                float4 a = *(const float4*)&s_nedge[(mg + 4 * i) * LDA1 + kk];
                FMA4C(zk[i], a.x, bk[0]); FMA4C(zk[i], a.y, bk[1]);
                FMA4C(zk[i], a.z, bk[2]); FMA4C(zk[i], a.w, bk[3]);
            }
        }
    }
    {
        float lg[4];
        #pragma unroll
        for (int j = 0; j < 4; ++j)
            lg[j] = og_sum(zq.x * zk[j].x + zq.y * zk[j].y +
                           zq.z * zk[j].z + zq.w * zk[j].w) * 0.125f;
        float mx = fmaxf(fmaxf(lg[0], lg[1]), fmaxf(lg[2], lg[3]));
        mx = mg_max(mx);
        float ea[4], ssum = 0.f;
        #pragma unroll
        for (int j = 0; j < 4; ++j) { ea[j] = expf(lg[j] - mx); ssum += ea[j]; }
        ssum = mg_sum(ssum);
        float inv = 1.f / ssum;
        float4 part; ZERO4(part);
        #pragma unroll
        for (int j = 0; j < 4; ++j) FMA4C(part, ea[j], zk[j]);
        part.x = mg_sum(part.x); part.y = mg_sum(part.y);
        part.z = mg_sum(part.z); part.w = mg_sum(part.w);
        float4 v;
        v.x = zq.x + part.x * inv; v.y = zq.y + part.y * inv;
        v.z = zq.z + part.z * inv; v.w = zq.w + part.w * inv;
        v = elu4(v);
        if (mg == 0)
            *(float4*)(xcat_mp + (size_t)b * (2 * D1) + D1 + h * O_DIM + og * 4) = v;
    }
}

// ---------------------------------------------------------------------------
template <typename T>
__global__ void k_gate(const float* __restrict__ xcat,
                       const void* __restrict__ Wg, const void* __restrict__ vg,
                       float* __restrict__ gate_pre,
                       const int* __restrict__ flag) {
    if (!active<T>(flag)) return;
    int mb = blockIdx.x;
    int t = threadIdx.x;   // 128
    __shared__ float xr[2 * D1];
    for (int idx = t; idx < 2 * D1; idx += 128) xr[idx] = xcat[(size_t)mb * (2 * D1) + idx];
    __syncthreads();
    float acc = 0.f;
    for (int d = 0; d < 2 * D1; ++d) acc += xr[d] * ldv<T>(Wg, d * PREP + t);
    float gp = tanhf(acc) * ldv<T>(vg, t);
    __shared__ float red[128];
    red[t] = gp;
    __syncthreads();
    for (int s = 64; s > 0; s >>= 1) { if (t < s) red[t] += red[t + s]; __syncthreads(); }
    if (t == 0) gate_pre[mb] = red[0];
}

template <typename T>
__global__ void k_final(const float* __restrict__ xcat,
                        const float* __restrict__ gate_pre,
                        const void* __restrict__ Wfc, const void* __restrict__ bfc,
                        void* __restrict__ out,
                        const int* __restrict__ flag) {
    if (!active<T>(flag)) return;
    int b = blockIdx.x;
    int t = threadIdx.x;  // 64
    float g0 = gate_pre[b], g1 = gate_pre[B_TR + b];
    float mx = fmaxf(g0, g1);
    float e0 = expf(g0 - mx), e1 = expf(g1 - mx);
    float inv = 1.f / (e0 + e1);
    float w0 = e0 * inv, w1 = e1 * inv;
    __shared__ float pooled[2 * D1];
    for (int d = t; d < 2 * D1; d += 64)
        pooled[d] = w0 * xcat[(size_t)b * (2 * D1) + d]
                  + w1 * xcat[(size_t)(B_TR + b) * (2 * D1) + d];
    __syncthreads();
    if (t < NCLS) {
        float acc = ldv<T>(bfc, t);
        for (int d = 0; d < 2 * D1; ++d) acc += pooled[d] * ldv<T>(Wfc, d * NCLS + t);
        stv<T>(out, (size_t)b * NCLS + t, acc);
    }
    if (t == 8) stv<T>(out, (size_t)B_TR * NCLS + b, w0);
    if (t == 9) stv<T>(out, (size_t)B_TR * NCLS + B_TR + b, w1);
}

// ---------------------------------------------------------------------------
template <typename T>
static void launch_path(void* const* d_in, void* d_out, void* d_ws,
                        size_t ws_size, hipStream_t stream) {
    const size_t esz = sizeof(T);
    const void* feats       = d_in[0];
    const void* edge_emb    = d_in[1];
    const void* W_prep0     = d_in[2];
    const void* W_prep1     = d_in[3];
    const void* edge_prep_w = d_in[4];
    const void* e_wq0       = d_in[5];
    const void* e_wk0       = d_in[6];
    const void* n_wq0       = d_in[9];
    const void* n_wk0       = d_in[10];
    const void* n_wq1       = d_in[11];
    const void* n_wk1       = d_in[12];
    const void* Wg          = d_in[13];
    const void* vg          = d_in[14];
    const void* Wfc         = d_in[15];
    const void* bfc         = d_in[16];
    const int*  n2e         = (const int*)d_in[17];
    const int*  adj         = (const int*)d_in[18];
    const int*  tid         = (const int*)d_in[19];

    // Workspace layout (floats). First 4 entries shared with fallback path.
    float* ws = (float*)d_ws;
    size_t off = 0;
    auto alloc = [&](size_t n) { size_t o = off; off += (n + 3) & ~(size_t)3; return o; };
    size_t o_af0   = alloc((size_t)N_NODES * PREP);
    size_t o_xcat  = alloc((size_t)NMP * B_TR * 2 * D1);
    size_t o_gpre  = alloc(NMP * B_TR);
    size_t o_flag  = alloc(4);
    size_t o_dummy = alloc((size_t)B_TR * PREP);
    size_t o_eid   = alloc(NSLOT);
    size_t o_adjA  = alloc(NSLOT);
    size_t o_adjB  = alloc(NSLOT);
    size_t o_eprep = alloc((size_t)NSLOT * PREP);
    size_t o_Qe    = alloc((size_t)NSLOT * D1);
    size_t o_Kn    = alloc((size_t)N_NODES * D1);
    size_t o_K0    = alloc((size_t)NSLOT * D1);
    size_t o_ned   = alloc((size_t)NSLOT * D1);
    size_t o_K1    = alloc((size_t)NSLOT * D1);
    size_t o_q0    = alloc((size_t)B_TR * D1);
    size_t o_out0  = alloc((size_t)B_TR * D1);
    size_t o_Q1    = alloc((size_t)B_TR * D1);
    size_t need_bytes = off * 4;

    float* af0      = ws + o_af0;
    float* xcat     = ws + o_xcat;
    float* gate_pre = ws + o_gpre;
    int*   flag     = (int*)(ws + o_flag);

    k_prep_nodes<T><<<(N_NODES * 32 + 255) / 256, 256, 0, stream>>>(
        feats, W_prep1, af0, flag);

    if (ws_size >= need_bytes) {
        // ---------------- De-fused GEMM path ----------------
        float* dummy = ws + o_dummy;
        int*   eid   = (int*)(ws + o_eid);
        int*   adjA  = (int*)(ws + o_adjA);
        int*   adjB  = (int*)(ws + o_adjB);
        float* eprep = ws + o_eprep;
        float* Qe    = ws + o_Qe;
        float* Kn    = ws + o_Kn;
        float* K0    = ws + o_K0;
        float* ned   = ws + o_ned;
        float* K1    = ws + o_K1;
        float* q0    = ws + o_q0;
        float* out0  = ws + o_out0;
        float* Q1    = ws + o_Q1;

        k_prep_dummy<T><<<(B_TR * 32 + 255) / 256, 256, 0, stream>>>(
            feats, W_prep0, tid, dummy, flag);

        for (int mp = 0; mp < NMP; ++mp) {
            const char* emb = (const char*)edge_emb + esz * (size_t)mp * E_EDGES * E_DIMC;
            const char* epw = (const char*)edge_prep_w + esz * (size_t)mp * E_DIMC * PREP;
            const char* ewq = (const char*)e_wq0 + esz * (size_t)mp * H_HEADS * PREP * O_DIM;
            const char* ewk = (const char*)e_wk0 + esz * (size_t)mp * H_HEADS * PREP * O_DIM;
            const char* nq0 = (const char*)n_wq0 + esz * (size_t)mp * H_HEADS * PREP * O_DIM;
            const char* nk0 = (const char*)n_wk0 + esz * (size_t)mp * H_HEADS * PREP * O_DIM;
            const char* nq1 = (const char*)n_wq1 + esz * (size_t)mp * H_HEADS * D1 * O_DIM;
            const char* nk1 = (const char*)n_wk1 + esz * (size_t)mp * H_HEADS * D1 * O_DIM;

            k_slot_setup<T><<<(NSLOT + 255) / 256, 256, 0, stream>>>(
                n2e + (size_t)mp * N_NODES * S_NE,
                adj + (size_t)mp * E_EDGES * 2,
                tid, eid, adjA, adjB, flag);

            // G1: eprep = edge_emb[eid] @ epw   [NSLOT,128], K=32
            k_gemm<T, T><<<dim3(NSLOT / 64, 2), 256, 0, stream>>>(
                emb, eid, E_DIMC, epw, 64, PREP, eprep, PREP, NSLOT, E_DIMC, flag);
            // G2: Qe = eprep @ ewq   [NSLOT,256], K=128
            k_gemm<float, T><<<dim3(NSLOT / 64, 4), 256, 0, stream>>>(
                eprep, nullptr, PREP, ewq, PREP * O_DIM, O_DIM, Qe, D1, NSLOT, PREP, flag);
            // G5: K0 = eprep @ nwk0  [NSLOT,256], K=128
            k_gemm<float, T><<<dim3(NSLOT / 64, 4), 256, 0, stream>>>(
                eprep, nullptr, PREP, nk0, PREP * O_DIM, O_DIM, K0, D1, NSLOT, PREP, flag);
            // G3: Kn = af0 @ ewk     [N,256], K=128
            k_gemm<float, T><<<dim3((N_NODES + 63) / 64, 4), 256, 0, stream>>>(
                af0, nullptr, PREP, ewk, PREP * O_DIM, O_DIM, Kn, D1, N_NODES, PREP, flag);
            // edge attention -> nedge
            k_edge_attn<T><<<NSLOT / 4, 256, 0, stream>>>(Qe, Kn, adjA, adjB, ned, flag);
            // G9: K1 = nedge @ nwk1  [NSLOT,256], K=256
            k_gemm<float, T><<<dim3(NSLOT / 64, 4), 256, 0, stream>>>(
                ned, nullptr, D1, nk1, D1 * O_DIM, O_DIM, K1, D1, NSLOT, D1, flag);
            // G6: q0 = dummy @ nwq0  [B,256], K=128
            k_gemm<float, T><<<dim3(B_TR / 64, 4), 256, 0, stream>>>(
                dummy, nullptr, PREP, nq0, PREP * O_DIM, O_DIM, q0, D1, B_TR, PREP, flag);
            // node attn L0 -> out0 + xcat[:,0:256]
            k_node_attn<T><<<B_TR, 256, 0, stream>>>(
                q0, K0, out0, xcat + (size_t)mp * B_TR * 2 * D1, 0, flag);
            // G8: Q1 = out0 @ nwq1   [B,256], K=256
            k_gemm<float, T><<<dim3(B_TR / 64, 4), 256, 0, stream>>>(
                out0, nullptr, D1, nq1, D1 * O_DIM, O_DIM, Q1, D1, B_TR, D1, flag);
            // node attn L1 -> xcat[:,256:512]
            k_node_attn<T><<<B_TR, 256, 0, stream>>>(
                Q1, K1, nullptr, xcat + (size_t)mp * B_TR * 2 * D1, D1, flag);
        }
    } else {
        // ---------------- Fused fallback (R4) ----------------
        for (int mp = 0; mp < NMP; ++mp) {
            k_fused<T><<<B_TR, 256, 0, stream>>>(
                feats,
                (const char*)edge_emb + esz * (size_t)mp * E_EDGES * E_DIMC,
                W_prep0,
                (const char*)edge_prep_w + esz * (size_t)mp * E_DIMC * PREP,
                (const char*)e_wq0 + esz * (size_t)mp * H_HEADS * PREP * O_DIM,
                (const char*)e_wk0 + esz * (size_t)mp * H_HEADS * PREP * O_DIM,
                (const char*)n_wq0 + esz * (size_t)mp * H_HEADS * PREP * O_DIM,
                (const char*)n_wk0 + esz * (size_t)mp * H_HEADS * PREP * O_DIM,
                (const char*)n_wq1 + esz * (size_t)mp * H_HEADS * D1 * O_DIM,
                (const char*)n_wk1 + esz * (size_t)mp * H_HEADS * D1 * O_DIM,
                n2e + (size_t)mp * N_NODES * S_NE,
                adj + (size_t)mp * E_EDGES * 2,
                tid, af0,
                xcat + (size_t)mp * B_TR * 2 * D1, flag);
        }
    }

    k_gate<T><<<NMP * B_TR, 128, 0, stream>>>(xcat, Wg, vg, gate_pre, flag);
    k_final<T><<<B_TR, 64, 0, stream>>>(xcat, gate_pre, Wfc, bfc, d_out, flag);
}

// ---------------------------------------------------------------------------
extern "C" void kernel_launch(void* const* d_in, const int* in_sizes, int n_in,
                              void* d_out, int out_size, void* d_ws, size_t ws_size,
                              hipStream_t stream) {
    // flag offset must match launch_path's layout: af0 + xcat + gate_pre
    size_t o = (size_t)N_NODES * PREP;
    o += (size_t)NMP * B_TR * 2 * D1;
    o += (size_t)((NMP * B_TR + 3) & ~3);
    int* flag = (int*)((float*)d_ws + o);

    k_detect<<<1, 64, 0, stream>>>((const unsigned*)d_in[0], flag);

    launch_path<float>(d_in, d_out, d_ws, ws_size, stream);
    launch_path<bf16>(d_in, d_out, d_ws, ws_size, stream);
}

// Round 6
// 917.051 us; speedup vs baseline: 2.7632x; 1.5603x over previous
//
#include <hip/hip_runtime.h>
#include <hip/hip_bf16.h>
#include <math.h>

// Problem dims
#define N_NODES 20000
#define S_NE    16
#define E_EDGES 160000
#define NMP     2
#define H_HEADS 4
#define O_DIM   64
#define D_FEAT  64
#define E_DIMC  32
#define PREP    128
#define NCLS    8
#define B_TR    4096
#define D1      256           // H*O
#define NSLOT   (B_TR * S_NE) // 65536

// LDS row pads for fused fallback
#define LDA0    132
#define LDA1    260

typedef __hip_bfloat16 bf16;

template <typename T>
__device__ __forceinline__ float ldv(const void* p, size_t i) {
    if constexpr (sizeof(T) == 4) return ((const float*)p)[i];
    else return __bfloat162float(((const bf16*)p)[i]);
}
template <typename T>
__device__ __forceinline__ float4 ld4(const void* p, size_t i) {
    if constexpr (sizeof(T) == 4) {
        return *(const float4*)((const float*)p + i);
    } else {
        float4 r;
        r.x = ldv<T>(p, i); r.y = ldv<T>(p, i + 1);
        r.z = ldv<T>(p, i + 2); r.w = ldv<T>(p, i + 3);
        return r;
    }
}
template <typename T>
__device__ __forceinline__ void stv(void* p, size_t i, float v) {
    if constexpr (sizeof(T) == 4) ((float*)p)[i] = v;
    else ((bf16*)p)[i] = __float2bfloat16(v);
}
template <typename T>
__device__ __forceinline__ bool active(const int* flag) {
    return *flag == (sizeof(T) == 4 ? 1 : 0);
}

__device__ __forceinline__ float wave_sum(float v) {
    #pragma unroll
    for (int off = 32; off > 0; off >>= 1) v += __shfl_xor(v, off, 64);
    return v;
}
__device__ __forceinline__ float og_sum(float v) {
    v += __shfl_xor(v, 4, 64);  v += __shfl_xor(v, 8, 64);
    v += __shfl_xor(v, 16, 64); v += __shfl_xor(v, 32, 64);
    return v;
}
__device__ __forceinline__ float mg_sum(float v) {
    v += __shfl_xor(v, 1, 64); v += __shfl_xor(v, 2, 64); return v;
}
__device__ __forceinline__ float mg_max(float v) {
    v = fmaxf(v, __shfl_xor(v, 1, 64)); v = fmaxf(v, __shfl_xor(v, 2, 64)); return v;
}
__device__ __forceinline__ float eluf(float x) { return x > 0.f ? x : expf(x) - 1.f; }
__device__ __forceinline__ float4 elu4(float4 v) {
    v.x = eluf(v.x); v.y = eluf(v.y); v.z = eluf(v.z); v.w = eluf(v.w); return v;
}

#define FMA4C(acc, s, b) do { (acc).x += (s)*(b).x; (acc).y += (s)*(b).y; \
                              (acc).z += (s)*(b).z; (acc).w += (s)*(b).w; } while (0)
#define ZERO4(v) do { (v).x = 0.f; (v).y = 0.f; (v).z = 0.f; (v).w = 0.f; } while (0)

// ---------------------------------------------------------------------------
// Dtype detector (R3-verified): flag=1 => fp32 buffers. flag lives at ws[0].
__global__ void k_detect(const unsigned* __restrict__ w, int* __restrict__ flag) {
    int t = threadIdx.x;
    int bad = 0;
    for (int i = t; i < 512; i += 64) {
        float v = __uint_as_float((w[i] & 0xffffu) << 16);
        if (!(fabsf(v) < 64.f)) bad++;
    }
    #pragma unroll
    for (int off = 32; off > 0; off >>= 1) bad += __shfl_xor(bad, off, 64);
    if (t == 0) *flag = (bad > 32) ? 1 : 0;
}

// ---------------------------------------------------------------------------
// Precombined weights: 4 combos x 2 mp x 4 h blocks.
//  0: Wqe [mp][32][256]  = epw     @ ewq      1: Wk0 [mp][32][256] = epw     @ nwk0
//  2: Wkn [mp][64][256]  = W_prep1 @ ewk      3: Wq0 [mp][64][256] = W_prep0 @ nwq0
template <typename T>
__device__ void precomb_body(const void* epw, const void* ewq, const void* nwk0,
                             const void* Wp1, const void* ewk,
                             const void* Wp0, const void* nwq0,
                             float* wqe, float* wk0, float* wkn, float* wq0) {
    int bid = blockIdx.x;          // 32 blocks
    int combo = bid >> 3, mp = (bid >> 2) & 1, h = bid & 3;
    int t = threadIdx.x, o = t & 63, rg = t >> 6;
    const void* Aw; const void* Bw; float* outp; int R; size_t aoff;
    size_t boff = (size_t)mp * H_HEADS * PREP * O_DIM + (size_t)h * PREP * O_DIM;
    switch (combo) {
        case 0: Aw = epw; Bw = ewq;  outp = wqe + mp * 32 * D1; R = 32; aoff = (size_t)mp * E_DIMC * PREP; break;
        case 1: Aw = epw; Bw = nwk0; outp = wk0 + mp * 32 * D1; R = 32; aoff = (size_t)mp * E_DIMC * PREP; break;
        case 2: Aw = Wp1; Bw = ewk;  outp = wkn + mp * 64 * D1; R = 64; aoff = 0; break;
        default:Aw = Wp0; Bw = nwq0; outp = wq0 + mp * 64 * D1; R = 64; aoff = 0; break;
    }
    for (int r = rg; r < R; r += 4) {
        float acc = 0.f;
        for (int p = 0; p < PREP; ++p)
            acc += ldv<T>(Aw, aoff + (size_t)r * PREP + p) *
                   ldv<T>(Bw, boff + (size_t)p * O_DIM + o);
        outp[(size_t)r * D1 + h * O_DIM + o] = acc;
    }
}
__global__ void k_precomb(const void* epw, const void* ewq, const void* nwk0,
                          const void* Wp1, const void* ewk,
                          const void* Wp0, const void* nwq0,
                          float* wqe, float* wk0, float* wkn, float* wq0,
                          const int* flag) {
    if (*flag == 1) precomb_body<float>(epw, ewq, nwk0, Wp1, ewk, Wp0, nwq0, wqe, wk0, wkn, wq0);
    else            precomb_body<bf16 >(epw, ewq, nwk0, Wp1, ewk, Wp0, nwq0, wqe, wk0, wkn, wq0);
}

// ---------------------------------------------------------------------------
// Register-tiled GEMM: C[m, h*64+n] = sum_k A[aOff + row(m)*strideA + k] *
//                                            B[bOff + h*sH + k*sD + n]
// BM=64, BN=64 (h = blockIdx.y), BK=32, 256 thr, 4x4 acc.
template <typename TA, typename TB>
__device__ void gemm_body(const void* A, size_t aOff, const int* Aidx, int strideA,
                          const void* B, size_t bOff, int sH, int sD,
                          float* C, int ldC, int M, int K) {
    int bm = blockIdx.x * 64;
    int h  = blockIdx.y;
    int t  = threadIdx.x;
    int tx = t & 15, ty = t >> 4;

    __shared__ float As[32][68];
    __shared__ float Bs[32][68];

    float acc[4][4] = {{0.f}};
    int arow = t >> 3, kq = (t & 7) * 4;
    int brow = t >> 4, nq = (t & 15) * 4;

    for (int k0 = 0; k0 < K; k0 += 32) {
        #pragma unroll
        for (int c = 0; c < 2; ++c) {
            int rm = arow + 32 * c;
            int gr = bm + rm;
            gr = (gr < M) ? gr : 0;
            size_t row = Aidx ? (size_t)Aidx[gr] : (size_t)gr;
            float4 a = ld4<TA>(A, aOff + row * strideA + k0 + kq);
            As[kq + 0][rm] = a.x; As[kq + 1][rm] = a.y;
            As[kq + 2][rm] = a.z; As[kq + 3][rm] = a.w;
        }
        #pragma unroll
        for (int c = 0; c < 2; ++c) {
            int rk = brow + 16 * c;
            float4 b = ld4<TB>(B, bOff + (size_t)h * sH + (size_t)(k0 + rk) * sD + nq);
            *(float4*)&Bs[rk][nq] = b;
        }
        __syncthreads();
        #pragma unroll
        for (int kk = 0; kk < 32; ++kk) {
            float4 av = *(const float4*)&As[kk][ty * 4];
            float4 bv = *(const float4*)&Bs[kk][tx * 4];
            float am[4] = {av.x, av.y, av.z, av.w};
            #pragma unroll
            for (int i = 0; i < 4; ++i) {
                acc[i][0] += am[i] * bv.x; acc[i][1] += am[i] * bv.y;
                acc[i][2] += am[i] * bv.z; acc[i][3] += am[i] * bv.w;
            }
        }
        __syncthreads();
    }
    #pragma unroll
    for (int i = 0; i < 4; ++i) {
        int m = bm + ty * 4 + i;
        if (m < M) {
            float4 st; st.x = acc[i][0]; st.y = acc[i][1];
            st.z = acc[i][2]; st.w = acc[i][3];
            *(float4*)&C[(size_t)m * ldC + h * 64 + tx * 4] = st;
        }
    }
}
// A raw input dtype, B fp32 (precombined)
__global__ __launch_bounds__(256) void k_gemm_rf(
        const void* A, size_t aOff, const int* Aidx, int strideA,
        const float* B, int sH, int sD, float* C, int ldC, int M, int K,
        const int* flag) {
    if (*flag == 1) gemm_body<float, float>(A, aOff, Aidx, strideA, B, 0, sH, sD, C, ldC, M, K);
    else            gemm_body<bf16,  float>(A, aOff, Aidx, strideA, B, 0, sH, sD, C, ldC, M, K);
}
// A fp32 workspace, B raw input dtype
__global__ __launch_bounds__(256) void k_gemm_fr(
        const float* A, int strideA,
        const void* B, size_t bOff, int sH, int sD, float* C, int ldC, int M, int K,
        const int* flag) {
    if (*flag == 1) gemm_body<float, float>(A, 0, nullptr, strideA, B, bOff, sH, sD, C, ldC, M, K);
    else            gemm_body<float, bf16 >(A, 0, nullptr, strideA, B, bOff, sH, sD, C, ldC, M, K);
}

// ---------------------------------------------------------------------------
// slot tables (dtype-independent): full NSLOT per mp
__global__ void k_slot_setup(const int* __restrict__ n2e_mp,
                             const int* __restrict__ adj_mp,
                             const int* __restrict__ tid,
                             int* __restrict__ eid,
                             int* __restrict__ adjA,
                             int* __restrict__ adjB) {
    int i = blockIdx.x * blockDim.x + threadIdx.x;
    if (i >= NSLOT) return;
    int b = i >> 4, s = i & 15;
    int e = n2e_mp[(size_t)tid[b] * S_NE + s];
    eid[i] = e;
    adjA[i] = adj_mp[(size_t)e * 2 + 0];
    adjB[i] = adj_mp[(size_t)e * 2 + 1];
}

// Edge attention, in-place: A (=Qe) -> ned. Pure fp32, no flag.
__global__ void k_eattn(float* __restrict__ Ain,
                        const float* __restrict__ Kn,
                        const int* __restrict__ adjA,
                        const int* __restrict__ adjB) {
    int slot = blockIdx.x * 4 + (threadIdx.x >> 6);
    int o = threadIdx.x & 63;
    size_t ra = (size_t)adjA[slot] * D1, rb = (size_t)adjB[slot] * D1;
    size_t qs = (size_t)slot * D1;
    #pragma unroll
    for (int h = 0; h < H_HEADS; ++h) {
        int c = h * O_DIM + o;
        float q  = Ain[qs + c];
        float kA = Kn[ra + c];
        float kB = Kn[rb + c];
        float lA = wave_sum(q * kA) * 0.125f;
        float lB = wave_sum(q * kB) * 0.125f;
        float m = fmaxf(lA, lB);
        float eA = expf(lA - m), eB = expf(lB - m);
        float inv = 1.f / (eA + eB);
        Ain[qs + c] = eluf(q + (eA * kA + eB * kB) * inv);
    }
}

// Node attention (16 contiguous K rows per node). Pure fp32, no flag.
__global__ void k_nattn(const float* __restrict__ q,
                        const float* __restrict__ K,
                        float* __restrict__ outA,
                        float* __restrict__ xrow, int xoff) {
    int b = blockIdx.x;
    int t = threadIdx.x;
    int h = t >> 6, o = t & 63;
    int c = h * O_DIM + o;
    float qv = q[(size_t)b * D1 + c];
    float k[S_NE], lg[S_NE];
    #pragma unroll
    for (int s = 0; s < S_NE; ++s) {
        k[s] = K[((size_t)b * S_NE + s) * D1 + c];
        lg[s] = wave_sum(qv * k[s]) * 0.125f;
    }
    float mx = lg[0];
    #pragma unroll
    for (int s = 1; s < S_NE; ++s) mx = fmaxf(mx, lg[s]);
    float sum = 0.f;
    #pragma unroll
    for (int s = 0; s < S_NE; ++s) { lg[s] = expf(lg[s] - mx); sum += lg[s]; }
    float inv = 1.f / sum;
    float agg = 0.f;
    #pragma unroll
    for (int s = 0; s < S_NE; ++s) agg += lg[s] * k[s];
    float v = eluf(qv + agg * inv);
    if (outA) outA[(size_t)b * D1 + c] = v;
    xrow[(size_t)b * (2 * D1) + xoff + c] = v;
}

// gate finish: gate_pre[row] = sum_t tanh(gmat[row][t]) * vg[t]
template <typename T>
__device__ void gate_fin_body(const float* gmat, const void* vg, float* gate_pre) {
    int row = blockIdx.x;
    int t = threadIdx.x;   // 128
    float v = tanhf(gmat[(size_t)row * PREP + t]) * ldv<T>(vg, t);
    __shared__ float red[128];
    red[t] = v;
    __syncthreads();
    for (int s = 64; s > 0; s >>= 1) { if (t < s) red[t] += red[t + s]; __syncthreads(); }
    if (t == 0) gate_pre[row] = red[0];
}
__global__ void k_gate_fin(const float* gmat, const void* vg, float* gate_pre,
                           const int* flag) {
    if (*flag == 1) gate_fin_body<float>(gmat, vg, gate_pre);
    else            gate_fin_body<bf16 >(gmat, vg, gate_pre);
}

// fallback gate (direct from xcat)
template <typename T>
__device__ void gate_dir_body(const float* xcat, const void* Wg, const void* vg,
                              float* gate_pre) {
    int mb = blockIdx.x;
    int t = threadIdx.x;   // 128
    __shared__ float xr[2 * D1];
    for (int idx = t; idx < 2 * D1; idx += 128) xr[idx] = xcat[(size_t)mb * (2 * D1) + idx];
    __syncthreads();
    float acc = 0.f;
    for (int d = 0; d < 2 * D1; ++d) acc += xr[d] * ldv<T>(Wg, (size_t)d * PREP + t);
    float gp = tanhf(acc) * ldv<T>(vg, t);
    __shared__ float red[128];
    red[t] = gp;
    __syncthreads();
    for (int s = 64; s > 0; s >>= 1) { if (t < s) red[t] += red[t + s]; __syncthreads(); }
    if (t == 0) gate_pre[mb] = red[0];
}
__global__ void k_gate_direct(const float* xcat, const void* Wg, const void* vg,
                              float* gate_pre, const int* flag) {
    if (*flag == 1) gate_dir_body<float>(xcat, Wg, vg, gate_pre);
    else            gate_dir_body<bf16 >(xcat, Wg, vg, gate_pre);
}

// final: softmax over mp, pool, FC -> out
template <typename T>
__device__ void final_body(const float* xcat, const float* gate_pre,
                           const void* Wfc, const void* bfc, void* out) {
    int b = blockIdx.x;
    int t = threadIdx.x;  // 64
    float g0 = gate_pre[b], g1 = gate_pre[B_TR + b];
    float mx = fmaxf(g0, g1);
    float e0 = expf(g0 - mx), e1 = expf(g1 - mx);
    float inv = 1.f / (e0 + e1);
    float w0 = e0 * inv, w1 = e1 * inv;
    __shared__ float pooled[2 * D1];
    for (int d = t; d < 2 * D1; d += 64)
        pooled[d] = w0 * xcat[(size_t)b * (2 * D1) + d]
                  + w1 * xcat[(size_t)(B_TR + b) * (2 * D1) + d];
    __syncthreads();
    if (t < NCLS) {
        float acc = ldv<T>(bfc, t);
        for (int d = 0; d < 2 * D1; ++d) acc += pooled[d] * ldv<T>(Wfc, (size_t)d * NCLS + t);
        stv<T>(out, (size_t)b * NCLS + t, acc);
    }
    if (t == 8) stv<T>(out, (size_t)B_TR * NCLS + b, w0);
    if (t == 9) stv<T>(out, (size_t)B_TR * NCLS + B_TR + b, w1);
}
__global__ void k_final(const float* xcat, const float* gate_pre,
                        const void* Wfc, const void* bfc, void* out,
                        const int* flag) {
    if (*flag == 1) final_body<float>(xcat, gate_pre, Wfc, bfc, out);
    else            final_body<bf16 >(xcat, gate_pre, Wfc, bfc, out);
}

// ---------------------------------------------------------------------------
// Fallback kernels (R4-verified fused path)
template <typename T>
__global__ void k_prep_nodes(const void* __restrict__ feats,
                             const void* __restrict__ W,
                             float* __restrict__ out,
                             const int* __restrict__ flag) {
    if (!active<T>(flag)) return;
    int g = blockIdx.x * blockDim.x + threadIdx.x;
    if (g >= N_NODES * 32) return;
    int n = g >> 5, pg = g & 31;
    float4 acc; ZERO4(acc);
    #pragma unroll 8
    for (int d = 0; d < D_FEAT; ++d) {
        float f = ldv<T>(feats, (size_t)n * D_FEAT + d);
        float4 w4 = ld4<T>(W, (size_t)d * PREP + pg * 4);
        FMA4C(acc, f, w4);
    }
    *(float4*)(out + (size_t)n * PREP + pg * 4) = acc;
}

template <typename T>
__global__ __launch_bounds__(256) void k_fused(
        const void* __restrict__ feats,
        const void* __restrict__ edge_emb_mp,
        const void* __restrict__ W_prep0,
        const void* __restrict__ epw_mp,
        const void* __restrict__ ewq,
        const void* __restrict__ ewk,
        const void* __restrict__ nwq0,
        const void* __restrict__ nwk0,
        const void* __restrict__ nwq1,
        const void* __restrict__ nwk1,
        const int*  __restrict__ n2e_mp,
        const int*  __restrict__ adj_mp,
        const int*  __restrict__ tid,
        const float* __restrict__ all_feats0,
        float* __restrict__ xcat_mp,
        const int* __restrict__ flag) {
    if (!active<T>(flag)) return;
    int b = blockIdx.x;
    int t = threadIdx.x;
    int h = t >> 6;
    int lane = t & 63;
    int mg = lane & 3, og = lane >> 2;

    __shared__ int   s_eid[S_NE];
    __shared__ int   s_nrow[2 * S_NE];
    __shared__ __align__(16) float s_emb[S_NE * E_DIMC];
    __shared__ __align__(16) float s_f[D_FEAT];
    __shared__ __align__(16) float s_q0[PREP];
    __shared__ __align__(16) float s_eprep[S_NE * LDA0];
    __shared__ __align__(16) float s_xn_pool[2 * S_NE * LDA0];
    __shared__ __align__(16) float s_out0[D1];
    float* s_nedge = s_xn_pool;

    int tid_b = tid[b];
    if (t < S_NE)   s_eid[t] = n2e_mp[(size_t)tid_b * S_NE + t];
    if (t < D_FEAT) s_f[t] = ldv<T>(feats, (size_t)tid_b * D_FEAT + t);
    __syncthreads();

    if (t < 2 * S_NE) s_nrow[t] = adj_mp[(size_t)s_eid[t >> 1] * 2 + (t & 1)];
    {
        int j = t, s = j >> 5, d = j & 31;
        s_emb[j] = ldv<T>(edge_emb_mp, (size_t)s_eid[s] * E_DIMC + d);
        j = t + 256; s = j >> 5; d = j & 31;
        s_emb[j] = ldv<T>(edge_emb_mp, (size_t)s_eid[s] * E_DIMC + d);
    }
    if (t < PREP) {
        float a = 0.f;
        #pragma unroll
        for (int d = 0; d < D_FEAT; ++d) a += s_f[d] * ldv<T>(W_prep0, d * PREP + t);
        s_q0[t] = a;
    }
    __syncthreads();

    #pragma unroll
    for (int k = 0; k < 4; ++k) {
        int j = t + 256 * k;
        int r = j >> 5, dc = j & 31;
        float4 v = *(const float4*)(all_feats0 + (size_t)s_nrow[r] * PREP + dc * 4);
        *(float4*)&s_xn_pool[r * LDA0 + dc * 4] = v;
    }
    {
        int s = t >> 4, pg = t & 15;
        float4 a0, a1; ZERO4(a0); ZERO4(a1);
        #pragma unroll
        for (int d = 0; d < E_DIMC; ++d) {
            float e = s_emb[s * E_DIMC + d];
            float4 w0 = ld4<T>(epw_mp, (size_t)d * PREP + pg * 8);
            float4 w1 = ld4<T>(epw_mp, (size_t)d * PREP + pg * 8 + 4);
            FMA4C(a0, e, w0); FMA4C(a1, e, w1);
        }
        *(float4*)&s_eprep[s * LDA0 + pg * 8]     = a0;
        *(float4*)&s_eprep[s * LDA0 + pg * 8 + 4] = a1;
    }
    __syncthreads();

    float4 aq[4], ak[8];
    #pragma unroll
    for (int i = 0; i < 4; ++i) ZERO4(aq[i]);
    #pragma unroll
    for (int i = 0; i < 8; ++i) ZERO4(ak[i]);
    {
        size_t wb = (size_t)h * PREP * O_DIM + og * 4;
        for (int kk = 0; kk < PREP; kk += 4) {
            float4 bq[4], bk[4];
            #pragma unroll
            for (int j = 0; j < 4; ++j) {
                bq[j] = ld4<T>(ewq, wb + (size_t)(kk + j) * O_DIM);
                bk[j] = ld4<T>(ewk, wb + (size_t)(kk + j) * O_DIM);
            }
            #pragma unroll
            for (int i = 0; i < 4; ++i) {
                float4 a = *(const float4*)&s_eprep[(mg + 4 * i) * LDA0 + kk];
                FMA4C(aq[i], a.x, bq[0]); FMA4C(aq[i], a.y, bq[1]);
                FMA4C(aq[i], a.z, bq[2]); FMA4C(aq[i], a.w, bq[3]);
            }
            #pragma unroll
            for (int i = 0; i < 8; ++i) {
                int r = 2 * mg + (i & 1) + 8 * (i >> 1);
                float4 a = *(const float4*)&s_xn_pool[r * LDA0 + kk];
                FMA4C(ak[i], a.x, bk[0]); FMA4C(ak[i], a.y, bk[1]);
                FMA4C(ak[i], a.z, bk[2]); FMA4C(ak[i], a.w, bk[3]);
            }
        }
    }
    __syncthreads();

    #pragma unroll
    for (int j = 0; j < 4; ++j) {
        int s = mg + 4 * j;
        float4 q = aq[j], kA = ak[2 * j], kB = ak[2 * j + 1];
        float lA = og_sum(q.x * kA.x + q.y * kA.y + q.z * kA.z + q.w * kA.w) * 0.125f;
        float lB = og_sum(q.x * kB.x + q.y * kB.y + q.z * kB.z + q.w * kB.w) * 0.125f;
        float m = fmaxf(lA, lB);
        float eA = expf(lA - m), eB = expf(lB - m);
        float inv = 1.f / (eA + eB);
        float4 v;
        v.x = q.x + (eA * kA.x + eB * kB.x) * inv;
        v.y = q.y + (eA * kA.y + eB * kB.y) * inv;
        v.z = q.z + (eA * kA.z + eB * kB.z) * inv;
        v.w = q.w + (eA * kA.w + eB * kB.w) * inv;
        *(float4*)&s_nedge[s * LDA1 + h * O_DIM + og * 4] = elu4(v);
    }

    float4 zq; ZERO4(zq);
    float4 zk[4];
    #pragma unroll
    for (int i = 0; i < 4; ++i) ZERO4(zk[i]);
    {
        size_t wb = (size_t)h * PREP * O_DIM + og * 4;
        for (int kk = 0; kk < PREP; kk += 4) {
            float4 q4 = *(const float4*)&s_q0[kk];
            float4 bq[4], bk[4];
            #pragma unroll
            for (int j = 0; j < 4; ++j) {
                bq[j] = ld4<T>(nwq0, wb + (size_t)(kk + j) * O_DIM);
                bk[j] = ld4<T>(nwk0, wb + (size_t)(kk + j) * O_DIM);
            }
            FMA4C(zq, q4.x, bq[0]); FMA4C(zq, q4.y, bq[1]);
            FMA4C(zq, q4.z, bq[2]); FMA4C(zq, q4.w, bq[3]);
            #pragma unroll
            for (int i = 0; i < 4; ++i) {
                float4 a = *(const float4*)&s_eprep[(mg + 4 * i) * LDA0 + kk];
                FMA4C(zk[i], a.x, bk[0]); FMA4C(zk[i], a.y, bk[1]);
                FMA4C(zk[i], a.z, bk[2]); FMA4C(zk[i], a.w, bk[3]);
            }
        }
    }
    {
        float lg[4];
        #pragma unroll
        for (int j = 0; j < 4; ++j)
            lg[j] = og_sum(zq.x * zk[j].x + zq.y * zk[j].y +
                           zq.z * zk[j].z + zq.w * zk[j].w) * 0.125f;
        float mx = fmaxf(fmaxf(lg[0], lg[1]), fmaxf(lg[2], lg[3]));
        mx = mg_max(mx);
        float ea[4], ssum = 0.f;
        #pragma unroll
        for (int j = 0; j < 4; ++j) { ea[j] = expf(lg[j] - mx); ssum += ea[j]; }
        ssum = mg_sum(ssum);
        float inv = 1.f / ssum;
        float4 part; ZERO4(part);
        #pragma unroll
        for (int j = 0; j < 4; ++j) FMA4C(part, ea[j], zk[j]);
        part.x = mg_sum(part.x); part.y = mg_sum(part.y);
        part.z = mg_sum(part.z); part.w = mg_sum(part.w);
        float4 v;
        v.x = zq.x + part.x * inv; v.y = zq.y + part.y * inv;
        v.z = zq.z + part.z * inv; v.w = zq.w + part.w * inv;
        v = elu4(v);
        if (mg == 0) {
            *(float4*)&s_out0[h * O_DIM + og * 4] = v;
            *(float4*)(xcat_mp + (size_t)b * (2 * D1) + h * O_DIM + og * 4) = v;
        }
    }
    __syncthreads();

    ZERO4(zq);
    #pragma unroll
    for (int i = 0; i < 4; ++i) ZERO4(zk[i]);
    {
        size_t wb = (size_t)h * D1 * O_DIM + og * 4;
        for (int kk = 0; kk < D1; kk += 4) {
            float4 q4 = *(const float4*)&s_out0[kk];
            float4 bq[4], bk[4];
            #pragma unroll
            for (int j = 0; j < 4; ++j) {
                bq[j] = ld4<T>(nwq1, wb + (size_t)(kk + j) * O_DIM);
                bk[j] = ld4<T>(nwk1, wb + (size_t)(kk + j) * O_DIM);
            }
            FMA4C(zq, q4.x, bq[0]); FMA4C(zq, q4.y, bq[1]);
            FMA4C(zq, q4.z, bq[2]); FMA4C(zq, q4.w, bq[3]);
            #pragma unroll
            for (int i = 0; i < 4; ++i) {
                float4 a = *(const float4*)&s_nedge[(mg + 4 * i) * LDA1 + kk];
                FMA4C(zk[i], a.x, bk[0]); FMA4C(zk[i], a.y, bk[1]);
                FMA4C(zk[i], a.z, bk[2]); FMA4C(zk[i], a.w, bk[3]);
            }
        }
    }
    {
        float lg[4];
        #pragma unroll
        for (int j = 0; j < 4; ++j)
            lg[j] = og_sum(zq.x * zk[j].x + zq.y * zk[j].y +
                           zq.z * zk[j].z + zq.w * zk[j].w) * 0.125f;
        float mx = fmaxf(fmaxf(lg[0], lg[1]), fmaxf(lg[2], lg[3]));
        mx = mg_max(mx);
        float ea[4], ssum = 0.f;
        #pragma unroll
        for (int j = 0; j < 4; ++j) { ea[j] = expf(lg[j] - mx); ssum += ea[j]; }
        ssum = mg_sum(ssum);
        float inv = 1.f / ssum;
        float4 part; ZERO4(part);
        #pragma unroll
        for (int j = 0; j < 4; ++j) FMA4C(part, ea[j], zk[j]);
        part.x = mg_sum(part.x); part.y = mg_sum(part.y);
        part.z = mg_sum(part.z); part.w = mg_sum(part.w);
        float4 v;
        v.x = zq.x + part.x * inv; v.y = zq.y + part.y * inv;
        v.z = zq.z + part.z * inv; v.w = zq.w + part.w * inv;
        v = elu4(v);
        if (mg == 0)
            *(float4*)(xcat_mp + (size_t)b * (2 * D1) + D1 + h * O_DIM + og * 4) = v;
    }
}

// ---------------------------------------------------------------------------
extern "C" void kernel_launch(void* const* d_in, const int* in_sizes, int n_in,
                              void* d_out, int out_size, void* d_ws, size_t ws_size,
                              hipStream_t stream) {
    const void* feats       = d_in[0];
    const void* edge_emb    = d_in[1];
    const void* W_prep0     = d_in[2];
    const void* W_prep1     = d_in[3];
    const void* edge_prep_w = d_in[4];
    const void* e_wq0       = d_in[5];
    const void* e_wk0       = d_in[6];
    const void* n_wq0       = d_in[9];
    const void* n_wk0       = d_in[10];
    const void* n_wq1       = d_in[11];
    const void* n_wk1       = d_in[12];
    const void* Wg          = d_in[13];
    const void* vg          = d_in[14];
    const void* Wfc         = d_in[15];
    const void* bfc         = d_in[16];
    const int*  n2e         = (const int*)d_in[17];
    const int*  adj         = (const int*)d_in[18];
    const int*  tid         = (const int*)d_in[19];

    float* ws   = (float*)d_ws;
    int*   flag = (int*)ws;            // ws[0]
    float* base = ws + 4;
    size_t avail = (ws_size >= 16) ? (ws_size - 16) / 4 : 0;   // floats

    k_detect<<<1, 64, 0, stream>>>((const unsigned*)feats, flag);

    // ---- main-path fixed layout ----
    size_t off = 0;
    auto alloc = [&](size_t n) { size_t o = off; off += (n + 3) & ~(size_t)3; return o; };
    size_t o_xcat = alloc((size_t)NMP * B_TR * 2 * D1);   // 4.19M
    size_t o_gmat = alloc((size_t)NMP * B_TR * PREP);     // 1.05M
    size_t o_gpre = alloc(NMP * B_TR);
    size_t o_wqe  = alloc(NMP * 32 * D1);
    size_t o_wk0  = alloc(NMP * 32 * D1);
    size_t o_wkn  = alloc(NMP * 64 * D1);
    size_t o_wq0  = alloc(NMP * 64 * D1);
    size_t o_Kn   = alloc((size_t)N_NODES * D1);          // 5.12M
    size_t o_q0   = alloc((size_t)B_TR * D1);
    size_t o_out0 = alloc((size_t)B_TR * D1);
    size_t o_Q1   = alloc((size_t)B_TR * D1);
    size_t o_eid  = alloc(NSLOT);
    size_t o_adjA = alloc(NSLOT);
    size_t o_adjB = alloc(NSLOT);
    size_t fixed = off;

    int CH = 0;
    for (int c = B_TR; c >= 256; c >>= 1) {
        if (fixed + (size_t)2 * c * S_NE * D1 <= avail) { CH = c; break; }
    }

    if (CH > 0) {
        // ------------- de-fused GEMM path -------------
        size_t o_A = alloc((size_t)CH * S_NE * D1);
        size_t o_C = alloc((size_t)CH * S_NE * D1);
        float* xcat = base + o_xcat;
        float* gmat = base + o_gmat;
        float* gpre = base + o_gpre;
        float* wqe  = base + o_wqe;
        float* wk0  = base + o_wk0;
        float* wkn  = base + o_wkn;
        float* wq0  = base + o_wq0;
        float* Kn   = base + o_Kn;
        float* q0   = base + o_q0;
        float* out0 = base + o_out0;
        float* Q1   = base + o_Q1;
        int*   eid  = (int*)(base + o_eid);
        int*   adjA = (int*)(base + o_adjA);
        int*   adjB = (int*)(base + o_adjB);
        float* Abuf = base + o_A;
        float* Cbuf = base + o_C;
        int NC = B_TR / CH;

        k_precomb<<<32, 256, 0, stream>>>(edge_prep_w, e_wq0, n_wk0, W_prep1,
                                          e_wk0, W_prep0, n_wq0,
                                          wqe, wk0, wkn, wq0, flag);

        for (int mp = 0; mp < NMP; ++mp) {
            size_t wOff1 = (size_t)mp * H_HEADS * D1 * O_DIM;  // nwk1/nwq1 elem offset

            k_slot_setup<<<(NSLOT + 255) / 256, 256, 0, stream>>>(
                n2e + (size_t)mp * N_NODES * S_NE,
                adj + (size_t)mp * E_EDGES * 2,
                tid, eid, adjA, adjB);

            // Kn = feats @ Wkn[mp]   [N,256], K=64
            k_gemm_rf<<<dim3((N_NODES + 63) / 64, 4), 256, 0, stream>>>(
                feats, 0, nullptr, D_FEAT, wkn + (size_t)mp * 64 * D1,
                64, D1, Kn, D1, N_NODES, D_FEAT, flag);
            // q0 = feats[tid] @ Wq0c[mp]   [B,256], K=64
            k_gemm_rf<<<dim3(B_TR / 64, 4), 256, 0, stream>>>(
                feats, 0, tid, D_FEAT, wq0 + (size_t)mp * 64 * D1,
                64, D1, q0, D1, B_TR, D_FEAT, flag);

            for (int c = 0; c < NC; ++c) {
                int c0 = c * CH;
                int MS = CH * S_NE;
                // Qe -> Abuf : emb[eid] @ Wqe[mp]  K=32
                k_gemm_rf<<<dim3(MS / 64, 4), 256, 0, stream>>>(
                    edge_emb, (size_t)mp * E_EDGES * E_DIMC, eid + (size_t)c0 * S_NE,
                    E_DIMC, wqe + (size_t)mp * 32 * D1, 64, D1, Abuf, D1, MS, E_DIMC, flag);
                // edge attention in-place: Abuf = ned
                k_eattn<<<MS / 4, 256, 0, stream>>>(
                    Abuf, Kn, adjA + (size_t)c0 * S_NE, adjB + (size_t)c0 * S_NE);
                // K1 -> Cbuf : ned @ nwk1[mp]  K=256
                k_gemm_fr<<<dim3(MS / 64, 4), 256, 0, stream>>>(
                    Abuf, D1, n_wk1, wOff1, D1 * O_DIM, O_DIM, Cbuf, D1, MS, D1, flag);
                // K0 -> Abuf (overwrite) : emb[eid] @ Wk0c[mp]  K=32
                k_gemm_rf<<<dim3(MS / 64, 4), 256, 0, stream>>>(
                    edge_emb, (size_t)mp * E_EDGES * E_DIMC, eid + (size_t)c0 * S_NE,
                    E_DIMC, wk0 + (size_t)mp * 32 * D1, 64, D1, Abuf, D1, MS, E_DIMC, flag);
                // node attn L0 -> out0 + xcat[:,0:256]
                k_nattn<<<CH, 256, 0, stream>>>(
                    q0 + (size_t)c0 * D1, Abuf, out0 + (size_t)c0 * D1,
                    xcat + ((size_t)mp * B_TR + c0) * 2 * D1, 0);
                // Q1 = out0 @ nwq1[mp]  K=256
                k_gemm_fr<<<dim3(CH / 64, 4), 256, 0, stream>>>(
                    out0 + (size_t)c0 * D1, D1, n_wq1, wOff1, D1 * O_DIM, O_DIM,
                    Q1 + (size_t)c0 * D1, D1, CH, D1, flag);
                // node attn L1 -> xcat[:,256:512]
                k_nattn<<<CH, 256, 0, stream>>>(
                    Q1 + (size_t)c0 * D1, Cbuf, nullptr,
                    xcat + ((size_t)mp * B_TR + c0) * 2 * D1, D1);
            }
        }
        // gate: gmat = xcat @ Wg  [8192,128], K=512; then tanh·vg reduce
        k_gemm_fr<<<dim3(NMP * B_TR / 64, 2), 256, 0, stream>>>(
            xcat, 2 * D1, Wg, 0, 64, PREP, gmat, PREP, NMP * B_TR, 2 * D1, flag);
        k_gate_fin<<<NMP * B_TR, 128, 0, stream>>>(gmat, vg, gpre, flag);
        k_final<<<B_TR, 64, 0, stream>>>(xcat, gpre, Wfc, bfc, d_out, flag);
    } else {
        // ------------- fused fallback (R4) -------------
        size_t f_off = 0;
        auto falloc = [&](size_t n) { size_t o = f_off; f_off += (n + 3) & ~(size_t)3; return o; };
        float* af0  = base + falloc((size_t)N_NODES * PREP);
        float* xcat = base + falloc((size_t)NMP * B_TR * 2 * D1);
        float* gpre = base + falloc(NMP * B_TR);

        k_prep_nodes<float><<<(N_NODES * 32 + 255) / 256, 256, 0, stream>>>(
            feats, W_prep1, af0, flag);
        k_prep_nodes<bf16><<<(N_NODES * 32 + 255) / 256, 256, 0, stream>>>(
            feats, W_prep1, af0, flag);

        for (int mp = 0; mp < NMP; ++mp) {
            #define FUSED_ARGS(esz)                                                   \
                feats,                                                                \
                (const char*)edge_emb + (esz) * (size_t)mp * E_EDGES * E_DIMC,        \
                W_prep0,                                                              \
                (const char*)edge_prep_w + (esz) * (size_t)mp * E_DIMC * PREP,        \
                (const char*)e_wq0 + (esz) * (size_t)mp * H_HEADS * PREP * O_DIM,     \
                (const char*)e_wk0 + (esz) * (size_t)mp * H_HEADS * PREP * O_DIM,     \
                (const char*)n_wq0 + (esz) * (size_t)mp * H_HEADS * PREP * O_DIM,     \
                (const char*)n_wk0 + (esz) * (size_t)mp * H_HEADS * PREP * O_DIM,     \
                (const char*)n_wq1 + (esz) * (size_t)mp * H_HEADS * D1 * O_DIM,       \
                (const char*)n_wk1 + (esz) * (size_t)mp * H_HEADS * D1 * O_DIM,       \
                n2e + (size_t)mp * N_NODES * S_NE,                                    \
                adj + (size_t)mp * E_EDGES * 2,                                       \
                tid, af0, xcat + (size_t)mp * B_TR * 2 * D1, flag
            k_fused<float><<<B_TR, 256, 0, stream>>>(FUSED_ARGS(4));
            k_fused<bf16><<<B_TR, 256, 0, stream>>>(FUSED_ARGS(2));
            #undef FUSED_ARGS
        }
        k_gate_direct<<<NMP * B_TR, 128, 0, stream>>>(xcat, Wg, vg, gpre, flag);
        k_final<<<B_TR, 64, 0, stream>>>(xcat, gpre, Wfc, bfc, d_out, flag);
    }
}

// Round 7
// 829.539 us; speedup vs baseline: 3.0547x; 1.1055x over previous
//
#include <hip/hip_runtime.h>
#include <hip/hip_bf16.h>
#include <math.h>

// Problem dims
#define N_NODES 20000
#define S_NE    16
#define E_EDGES 160000
#define NMP     2
#define H_HEADS 4
#define O_DIM   64
#define D_FEAT  64
#define E_DIMC  32
#define PREP    128
#define NCLS    8
#define B_TR    4096
#define D1      256           // H*O
#define NSLOT   (B_TR * S_NE) // 65536

// LDS row pads for fused fallback
#define LDA0    132
#define LDA1    260

typedef __hip_bfloat16 bf16;
typedef unsigned short u16;
typedef __attribute__((ext_vector_type(8))) short s8v;   // 8 bf16 (4 VGPRs)
typedef __attribute__((ext_vector_type(4))) float f4v;   // MFMA acc

template <typename T>
__device__ __forceinline__ float ldv(const void* p, size_t i) {
    if constexpr (sizeof(T) == 4) return ((const float*)p)[i];
    else return __bfloat162float(((const bf16*)p)[i]);
}
template <typename T>
__device__ __forceinline__ float4 ld4(const void* p, size_t i) {
    if constexpr (sizeof(T) == 4) {
        return *(const float4*)((const float*)p + i);
    } else {
        float4 r;
        r.x = ldv<T>(p, i); r.y = ldv<T>(p, i + 1);
        r.z = ldv<T>(p, i + 2); r.w = ldv<T>(p, i + 3);
        return r;
    }
}
template <typename T>
__device__ __forceinline__ void stv(void* p, size_t i, float v) {
    if constexpr (sizeof(T) == 4) ((float*)p)[i] = v;
    else ((bf16*)p)[i] = __float2bfloat16(v);
}
template <typename T>
__device__ __forceinline__ bool active(const int* flag) {
    return *flag == (sizeof(T) == 4 ? 1 : 0);
}

__device__ __forceinline__ u16 f2bf(float x) {
    bf16 h = __float2bfloat16(x);
    return *reinterpret_cast<u16*>(&h);
}
__device__ __forceinline__ float bf2f(u16 u) {
    bf16 h; *reinterpret_cast<u16*>(&h) = u;
    return __bfloat162float(h);
}
// split-bf16: x ~= hi + lo, product error ~2^-17 relative
__device__ __forceinline__ void splitbf(float x, u16& h, u16& l) {
    h = f2bf(x);
    l = f2bf(x - bf2f(h));
}

__device__ __forceinline__ float wave_sum(float v) {
    #pragma unroll
    for (int off = 32; off > 0; off >>= 1) v += __shfl_xor(v, off, 64);
    return v;
}
__device__ __forceinline__ float og_sum(float v) {
    v += __shfl_xor(v, 4, 64);  v += __shfl_xor(v, 8, 64);
    v += __shfl_xor(v, 16, 64); v += __shfl_xor(v, 32, 64);
    return v;
}
__device__ __forceinline__ float mg_sum(float v) {
    v += __shfl_xor(v, 1, 64); v += __shfl_xor(v, 2, 64); return v;
}
__device__ __forceinline__ float mg_max(float v) {
    v = fmaxf(v, __shfl_xor(v, 1, 64)); v = fmaxf(v, __shfl_xor(v, 2, 64)); return v;
}
__device__ __forceinline__ float eluf(float x) { return x > 0.f ? x : expf(x) - 1.f; }
__device__ __forceinline__ float4 elu4(float4 v) {
    v.x = eluf(v.x); v.y = eluf(v.y); v.z = eluf(v.z); v.w = eluf(v.w); return v;
}

#define FMA4C(acc, s, b) do { (acc).x += (s)*(b).x; (acc).y += (s)*(b).y; \
                              (acc).z += (s)*(b).z; (acc).w += (s)*(b).w; } while (0)
#define ZERO4(v) do { (v).x = 0.f; (v).y = 0.f; (v).z = 0.f; (v).w = 0.f; } while (0)

// ---------------------------------------------------------------------------
// Dtype detector (R3-verified): flag=1 => fp32 buffers. flag at ws[0].
__global__ void k_detect(const unsigned* __restrict__ w, int* __restrict__ flag) {
    int t = threadIdx.x;
    int bad = 0;
    for (int i = t; i < 512; i += 64) {
        float v = __uint_as_float((w[i] & 0xffffu) << 16);
        if (!(fabsf(v) < 64.f)) bad++;
    }
    #pragma unroll
    for (int off = 32; off > 0; off >>= 1) bad += __shfl_xor(bad, off, 64);
    if (t == 0) *flag = (bad > 32) ? 1 : 0;
}

// ---------------------------------------------------------------------------
// Precombined fp32 weights (unchanged, R6-verified):
//  0: Wqe[mp][32][256] = epw@ewq   1: Wk0[mp][32][256] = epw@nwk0
//  2: Wkn[mp][64][256] = Wp1@ewk   3: Wq0[mp][64][256] = Wp0@nwq0
template <typename T>
__device__ void precomb_body(const void* epw, const void* ewq, const void* nwk0,
                             const void* Wp1, const void* ewk,
                             const void* Wp0, const void* nwq0,
                             float* wqe, float* wk0, float* wkn, float* wq0) {
    int bid = blockIdx.x;
    int combo = bid >> 3, mp = (bid >> 2) & 1, h = bid & 3;
    int t = threadIdx.x, o = t & 63, rg = t >> 6;
    const void* Aw; const void* Bw; float* outp; int R; size_t aoff;
    size_t boff = (size_t)mp * H_HEADS * PREP * O_DIM + (size_t)h * PREP * O_DIM;
    switch (combo) {
        case 0: Aw = epw; Bw = ewq;  outp = wqe + mp * 32 * D1; R = 32; aoff = (size_t)mp * E_DIMC * PREP; break;
        case 1: Aw = epw; Bw = nwk0; outp = wk0 + mp * 32 * D1; R = 32; aoff = (size_t)mp * E_DIMC * PREP; break;
        case 2: Aw = Wp1; Bw = ewk;  outp = wkn + mp * 64 * D1; R = 64; aoff = 0; break;
        default:Aw = Wp0; Bw = nwq0; outp = wq0 + mp * 64 * D1; R = 64; aoff = 0; break;
    }
    for (int r = rg; r < R; r += 4) {
        float acc = 0.f;
        for (int p = 0; p < PREP; ++p)
            acc += ldv<T>(Aw, aoff + (size_t)r * PREP + p) *
                   ldv<T>(Bw, boff + (size_t)p * O_DIM + o);
        outp[(size_t)r * D1 + h * O_DIM + o] = acc;
    }
}
__global__ void k_precomb(const void* epw, const void* ewq, const void* nwk0,
                          const void* Wp1, const void* ewk,
                          const void* Wp0, const void* nwq0,
                          float* wqe, float* wk0, float* wkn, float* wq0,
                          const int* flag) {
    if (*flag == 1) precomb_body<float>(epw, ewq, nwk0, Wp1, ewk, Wp0, nwq0, wqe, wk0, wkn, wq0);
    else            precomb_body<bf16 >(epw, ewq, nwk0, Wp1, ewk, Wp0, nwq0, wqe, wk0, wkn, wq0);
}

// Transposed hi/lo planes of nwk1/nwq1: Bt[mp][n=256][k=256] = w[mp][n>>6][k][n&63]
template <typename T>
__device__ void wt1_body(const void* wk1, const void* wq1,
                         u16* kth, u16* ktl, u16* qth, u16* qtl) {
    int idx = blockIdx.x * 256 + threadIdx.x;   // 0..262143
    int k = idx & 255, n = (idx >> 8) & 255;
    int wsel = (idx >> 16) & 1, mp = idx >> 17;
    size_t src = (size_t)mp * (H_HEADS * D1 * O_DIM) + (size_t)(n >> 6) * (D1 * O_DIM)
               + (size_t)k * O_DIM + (n & 63);
    float v = ldv<T>(wsel ? wq1 : wk1, src);
    u16 h, l; splitbf(v, h, l);
    size_t dst = (size_t)mp * 65536 + (size_t)n * 256 + k;
    if (wsel) { qth[dst] = h; qtl[dst] = l; }
    else      { kth[dst] = h; ktl[dst] = l; }
}
__global__ void k_wt1(const void* wk1, const void* wq1,
                      u16* kth, u16* ktl, u16* qth, u16* qtl, const int* flag) {
    if (*flag == 1) wt1_body<float>(wk1, wq1, kth, ktl, qth, qtl);
    else            wt1_body<bf16 >(wk1, wq1, kth, ktl, qth, qtl);
}

// Transposed hi/lo planes of Wg[512][128] -> Wgt[n=128][k=512]
template <typename T>
__device__ void wgt_body(const void* Wg, u16* gh, u16* gl) {
    int idx = blockIdx.x * 256 + threadIdx.x;   // 0..65535
    int n = idx >> 9, k = idx & 511;
    float v = ldv<T>(Wg, (size_t)k * PREP + n);
    u16 h, l; splitbf(v, h, l);
    gh[(size_t)n * 512 + k] = h;
    gl[(size_t)n * 512 + k] = l;
}
__global__ void k_wgt(const void* Wg, u16* gh, u16* gl, const int* flag) {
    if (*flag == 1) wgt_body<float>(Wg, gh, gl);
    else            wgt_body<bf16 >(Wg, gh, gl);
}

// ---------------------------------------------------------------------------
// fp32 register-tiled GEMM (R6-verified) for the K<=64 gather GEMMs.
template <typename TA, typename TB>
__device__ void gemm_body(const void* A, size_t aOff, const int* Aidx, int strideA,
                          const void* B, int sH, int sD,
                          float* C, int ldC, int M, int K) {
    int bm = blockIdx.x * 64;
    int h  = blockIdx.y;
    int t  = threadIdx.x;
    int tx = t & 15, ty = t >> 4;

    __shared__ float As[32][68];
    __shared__ float Bs[32][68];

    float acc[4][4] = {{0.f}};
    int arow = t >> 3, kq = (t & 7) * 4;
    int brow = t >> 4, nq = (t & 15) * 4;

    for (int k0 = 0; k0 < K; k0 += 32) {
        #pragma unroll
        for (int c = 0; c < 2; ++c) {
            int rm = arow + 32 * c;
            int gr = bm + rm;
            gr = (gr < M) ? gr : 0;
            size_t row = Aidx ? (size_t)Aidx[gr] : (size_t)gr;
            float4 a = ld4<TA>(A, aOff + row * strideA + k0 + kq);
            As[kq + 0][rm] = a.x; As[kq + 1][rm] = a.y;
            As[kq + 2][rm] = a.z; As[kq + 3][rm] = a.w;
        }
        #pragma unroll
        for (int c = 0; c < 2; ++c) {
            int rk = brow + 16 * c;
            float4 b = ld4<TB>(B, (size_t)h * sH + (size_t)(k0 + rk) * sD + nq);
            *(float4*)&Bs[rk][nq] = b;
        }
        __syncthreads();
        #pragma unroll
        for (int kk = 0; kk < 32; ++kk) {
            float4 av = *(const float4*)&As[kk][ty * 4];
            float4 bv = *(const float4*)&Bs[kk][tx * 4];
            float am[4] = {av.x, av.y, av.z, av.w};
            #pragma unroll
            for (int i = 0; i < 4; ++i) {
                acc[i][0] += am[i] * bv.x; acc[i][1] += am[i] * bv.y;
                acc[i][2] += am[i] * bv.z; acc[i][3] += am[i] * bv.w;
            }
        }
        __syncthreads();
    }
    #pragma unroll
    for (int i = 0; i < 4; ++i) {
        int m = bm + ty * 4 + i;
        if (m < M) {
            float4 st; st.x = acc[i][0]; st.y = acc[i][1];
            st.z = acc[i][2]; st.w = acc[i][3];
            *(float4*)&C[(size_t)m * ldC + h * 64 + tx * 4] = st;
        }
    }
}
__global__ __launch_bounds__(256) void k_gemm_rf(
        const void* A, size_t aOff, const int* Aidx, int strideA,
        const float* B, int sH, int sD, float* C, int ldC, int M, int K,
        const int* flag) {
    if (*flag == 1) gemm_body<float, float>(A, aOff, Aidx, strideA, B, sH, sD, C, ldC, M, K);
    else            gemm_body<bf16,  float>(A, aOff, Aidx, strideA, B, sH, sD, C, ldC, M, K);
}

// ---------------------------------------------------------------------------
// LDS-free split-bf16 MFMA GEMM: C[m,n] = sum_k A[m,k]*B[k,n]
// A as hi/lo bf16 planes [M,K] row-major; B as hi/lo planes TRANSPOSED [N,K].
// Block 256 thr = 4 waves, tile 128x128; wave tile 64x64 = 4x4 mfma tiles.
// Frag layouts per m89/m91-verified mapping:
//   A-frag: m = lane&15, k = (lane>>4)*8 + j   (contiguous 16B at row m)
//   B-frag: n = lane&15, k = (lane>>4)*8 + j   (contiguous 16B in B^T row n)
//   C/D:    col n = lane&15, row m = (lane>>4)*4 + reg
template <int K>
__global__ __launch_bounds__(256) void k_mfma(
        const u16* __restrict__ Ah, const u16* __restrict__ Al,
        const u16* __restrict__ Bh, const u16* __restrict__ Bl,
        float* __restrict__ C, int ldC) {
    int w = threadIdx.x >> 6, lane = threadIdx.x & 63;
    int bm = blockIdx.x * 128 + (w & 1) * 64;
    int bn = blockIdx.y * 128 + (w >> 1) * 64;
    int fr = lane & 15;
    int kq = (lane >> 4) * 8;

    f4v acc[4][4];
    #pragma unroll
    for (int i = 0; i < 4; ++i)
        #pragma unroll
        for (int j = 0; j < 4; ++j) acc[i][j] = f4v{0.f, 0.f, 0.f, 0.f};

    #pragma unroll 2
    for (int k0 = 0; k0 < K; k0 += 32) {
        s8v ah[4], al[4], bh[4], bl[4];
        #pragma unroll
        for (int i = 0; i < 4; ++i) {
            size_t ao = (size_t)(bm + i * 16 + fr) * K + k0 + kq;
            ah[i] = *(const s8v*)(Ah + ao);
            al[i] = *(const s8v*)(Al + ao);
            size_t bo = (size_t)(bn + i * 16 + fr) * K + k0 + kq;
            bh[i] = *(const s8v*)(Bh + bo);
            bl[i] = *(const s8v*)(Bl + bo);
        }
        #pragma unroll
        for (int i = 0; i < 4; ++i)
            #pragma unroll
            for (int j = 0; j < 4; ++j) {
                acc[i][j] = __builtin_amdgcn_mfma_f32_16x16x32_bf16(al[i], bh[j], acc[i][j], 0, 0, 0);
                acc[i][j] = __builtin_amdgcn_mfma_f32_16x16x32_bf16(ah[i], bl[j], acc[i][j], 0, 0, 0);
                acc[i][j] = __builtin_amdgcn_mfma_f32_16x16x32_bf16(ah[i], bh[j], acc[i][j], 0, 0, 0);
            }
    }
    int cn = lane & 15, cr = (lane >> 4) * 4;
    #pragma unroll
    for (int i = 0; i < 4; ++i) {
        int m0 = bm + i * 16 + cr;
        #pragma unroll
        for (int j = 0; j < 4; ++j) {
            int n = bn + j * 16 + cn;
            #pragma unroll
            for (int r = 0; r < 4; ++r)
                C[(size_t)(m0 + r) * ldC + n] = acc[i][j][r];
        }
    }
}

// ---------------------------------------------------------------------------
// slot tables
__global__ void k_slot_setup(const int* __restrict__ n2e_mp,
                             const int* __restrict__ adj_mp,
                             const int* __restrict__ tid,
                             int* __restrict__ eid,
                             int* __restrict__ adjA,
                             int* __restrict__ adjB) {
    int i = blockIdx.x * blockDim.x + threadIdx.x;
    if (i >= NSLOT) return;
    int b = i >> 4, s = i & 15;
    int e = n2e_mp[(size_t)tid[b] * S_NE + s];
    eid[i] = e;
    adjA[i] = adj_mp[(size_t)e * 2 + 0];
    adjB[i] = adj_mp[(size_t)e * 2 + 1];
}

// Edge attention: reads Qe (fp32 [MS,256]), writes ned as hi/lo bf16 planes.
__global__ void k_eattn(const float* __restrict__ Qe,
                        const float* __restrict__ Kn,
                        const int* __restrict__ adjA,
                        const int* __restrict__ adjB,
                        u16* __restrict__ nh, u16* __restrict__ nl) {
    int slot = blockIdx.x * 4 + (threadIdx.x >> 6);
    int o = threadIdx.x & 63;
    size_t ra = (size_t)adjA[slot] * D1, rb = (size_t)adjB[slot] * D1;
    size_t qs = (size_t)slot * D1;
    #pragma unroll
    for (int h = 0; h < H_HEADS; ++h) {
        int c = h * O_DIM + o;
        float q  = Qe[qs + c];
        float kA = Kn[ra + c];
        float kB = Kn[rb + c];
        float lA = wave_sum(q * kA) * 0.125f;
        float lB = wave_sum(q * kB) * 0.125f;
        float m = fmaxf(lA, lB);
        float eA = expf(lA - m), eB = expf(lB - m);
        float inv = 1.f / (eA + eB);
        float v = eluf(q + (eA * kA + eB * kB) * inv);
        u16 hh, ll; splitbf(v, hh, ll);
        nh[qs + c] = hh; nl[qs + c] = ll;
    }
}

// Node attention; writes xcat fp32 + hi/lo planes (+ optional 256-wide planes).
__global__ void k_nattn(const float* __restrict__ q,
                        const float* __restrict__ K,
                        u16* __restrict__ o0h, u16* __restrict__ o0l,  // may be null
                        float* __restrict__ xrow, int xoff,
                        u16* __restrict__ xh, u16* __restrict__ xl) {
    int b = blockIdx.x;
    int c = threadIdx.x;   // 256 = h*64+o
    float qv = q[(size_t)b * D1 + c];
    float k[S_NE], lg[S_NE];
    #pragma unroll
    for (int s = 0; s < S_NE; ++s) {
        k[s] = K[((size_t)b * S_NE + s) * D1 + c];
        lg[s] = wave_sum(qv * k[s]) * 0.125f;
    }
    float mx = lg[0];
    #pragma unroll
    for (int s = 1; s < S_NE; ++s) mx = fmaxf(mx, lg[s]);
    float sum = 0.f;
    #pragma unroll
    for (int s = 0; s < S_NE; ++s) { lg[s] = expf(lg[s] - mx); sum += lg[s]; }
    float inv = 1.f / sum;
    float agg = 0.f;
    #pragma unroll
    for (int s = 0; s < S_NE; ++s) agg += lg[s] * k[s];
    float v = eluf(qv + agg * inv);
    xrow[(size_t)b * (2 * D1) + xoff + c] = v;
    u16 hh, ll; splitbf(v, hh, ll);
    xh[(size_t)b * (2 * D1) + xoff + c] = hh;
    xl[(size_t)b * (2 * D1) + xoff + c] = ll;
    if (o0h) { o0h[(size_t)b * D1 + c] = hh; o0l[(size_t)b * D1 + c] = ll; }
}

// gate finish
template <typename T>
__device__ void gate_fin_body(const float* gmat, const void* vg, float* gate_pre) {
    int row = blockIdx.x;
    int t = threadIdx.x;   // 128
    float v = tanhf(gmat[(size_t)row * PREP + t]) * ldv<T>(vg, t);
    __shared__ float red[128];
    red[t] = v;
    __syncthreads();
    for (int s = 64; s > 0; s >>= 1) { if (t < s) red[t] += red[t + s]; __syncthreads(); }
    if (t == 0) gate_pre[row] = red[0];
}
__global__ void k_gate_fin(const float* gmat, const void* vg, float* gate_pre,
                           const int* flag) {
    if (*flag == 1) gate_fin_body<float>(gmat, vg, gate_pre);
    else            gate_fin_body<bf16 >(gmat, vg, gate_pre);
}

// fallback gate (direct from xcat)
template <typename T>
__device__ void gate_dir_body(const float* xcat, const void* Wg, const void* vg,
                              float* gate_pre) {
    int mb = blockIdx.x;
    int t = threadIdx.x;   // 128
    __shared__ float xr[2 * D1];
    for (int idx = t; idx < 2 * D1; idx += 128) xr[idx] = xcat[(size_t)mb * (2 * D1) + idx];
    __syncthreads();
    float acc = 0.f;
    for (int d = 0; d < 2 * D1; ++d) acc += xr[d] * ldv<T>(Wg, (size_t)d * PREP + t);
    float gp = tanhf(acc) * ldv<T>(vg, t);
    __shared__ float red[128];
    red[t] = gp;
    __syncthreads();
    for (int s = 64; s > 0; s >>= 1) { if (t < s) red[t] += red[t + s]; __syncthreads(); }
    if (t == 0) gate_pre[mb] = red[0];
}
__global__ void k_gate_direct(const float* xcat, const void* Wg, const void* vg,
                              float* gate_pre, const int* flag) {
    if (*flag == 1) gate_dir_body<float>(xcat, Wg, vg, gate_pre);
    else            gate_dir_body<bf16 >(xcat, Wg, vg, gate_pre);
}

// final
template <typename T>
__device__ void final_body(const float* xcat, const float* gate_pre,
                           const void* Wfc, const void* bfc, void* out) {
    int b = blockIdx.x;
    int t = threadIdx.x;  // 64
    float g0 = gate_pre[b], g1 = gate_pre[B_TR + b];
    float mx = fmaxf(g0, g1);
    float e0 = expf(g0 - mx), e1 = expf(g1 - mx);
    float inv = 1.f / (e0 + e1);
    float w0 = e0 * inv, w1 = e1 * inv;
    __shared__ float pooled[2 * D1];
    for (int d = t; d < 2 * D1; d += 64)
        pooled[d] = w0 * xcat[(size_t)b * (2 * D1) + d]
                  + w1 * xcat[(size_t)(B_TR + b) * (2 * D1) + d];
    __syncthreads();
    if (t < NCLS) {
        float acc = ldv<T>(bfc, t);
        for (int d = 0; d < 2 * D1; ++d) acc += pooled[d] * ldv<T>(Wfc, (size_t)d * NCLS + t);
        stv<T>(out, (size_t)b * NCLS + t, acc);
    }
    if (t == 8) stv<T>(out, (size_t)B_TR * NCLS + b, w0);
    if (t == 9) stv<T>(out, (size_t)B_TR * NCLS + B_TR + b, w1);
}
__global__ void k_final(const float* xcat, const float* gate_pre,
                        const void* Wfc, const void* bfc, void* out,
                        const int* flag) {
    if (*flag == 1) final_body<float>(xcat, gate_pre, Wfc, bfc, out);
    else            final_body<bf16 >(xcat, gate_pre, Wfc, bfc, out);
}

// ---------------------------------------------------------------------------
// Fallback kernels (R4-verified fused path)
template <typename T>
__global__ void k_prep_nodes(const void* __restrict__ feats,
                             const void* __restrict__ W,
                             float* __restrict__ out,
                             const int* __restrict__ flag) {
    if (!active<T>(flag)) return;
    int g = blockIdx.x * blockDim.x + threadIdx.x;
    if (g >= N_NODES * 32) return;
    int n = g >> 5, pg = g & 31;
    float4 acc; ZERO4(acc);
    #pragma unroll 8
    for (int d = 0; d < D_FEAT; ++d) {
        float f = ldv<T>(feats, (size_t)n * D_FEAT + d);
        float4 w4 = ld4<T>(W, (size_t)d * PREP + pg * 4);
        FMA4C(acc, f, w4);
    }
    *(float4*)(out + (size_t)n * PREP + pg * 4) = acc;
}

template <typename T>
__global__ __launch_bounds__(256) void k_fused(
        const void* __restrict__ feats,
        const void* __restrict__ edge_emb_mp,
        const void* __restrict__ W_prep0,
        const void* __restrict__ epw_mp,
        const void* __restrict__ ewq,
        const void* __restrict__ ewk,
        const void* __restrict__ nwq0,
        const void* __restrict__ nwk0,
        const void* __restrict__ nwq1,
        const void* __restrict__ nwk1,
        const int*  __restrict__ n2e_mp,
        const int*  __restrict__ adj_mp,
        const int*  __restrict__ tid,
        const float* __restrict__ all_feats0,
        float* __restrict__ xcat_mp,
        const int* __restrict__ flag) {
    if (!active<T>(flag)) return;
    int b = blockIdx.x;
    int t = threadIdx.x;
    int h = t >> 6;
    int lane = t & 63;
    int mg = lane & 3, og = lane >> 2;

    __shared__ int   s_eid[S_NE];
    __shared__ int   s_nrow[2 * S_NE];
    __shared__ __align__(16) float s_emb[S_NE * E_DIMC];
    __shared__ __align__(16) float s_f[D_FEAT];
    __shared__ __align__(16) float s_q0[PREP];
    __shared__ __align__(16) float s_eprep[S_NE * LDA0];
    __shared__ __align__(16) float s_xn_pool[2 * S_NE * LDA0];
    __shared__ __align__(16) float s_out0[D1];
    float* s_nedge = s_xn_pool;

    int tid_b = tid[b];
    if (t < S_NE)   s_eid[t] = n2e_mp[(size_t)tid_b * S_NE + t];
    if (t < D_FEAT) s_f[t] = ldv<T>(feats, (size_t)tid_b * D_FEAT + t);
    __syncthreads();

    if (t < 2 * S_NE) s_nrow[t] = adj_mp[(size_t)s_eid[t >> 1] * 2 + (t & 1)];
    {
        int j = t, s = j >> 5, d = j & 31;
        s_emb[j] = ldv<T>(edge_emb_mp, (size_t)s_eid[s] * E_DIMC + d);
        j = t + 256; s = j >> 5; d = j & 31;
        s_emb[j] = ldv<T>(edge_emb_mp, (size_t)s_eid[s] * E_DIMC + d);
    }
    if (t < PREP) {
        float a = 0.f;
        #pragma unroll
        for (int d = 0; d < D_FEAT; ++d) a += s_f[d] * ldv<T>(W_prep0, d * PREP + t);
        s_q0[t] = a;
    }
    __syncthreads();

    #pragma unroll
    for (int k = 0; k < 4; ++k) {
        int j = t + 256 * k;
        int r = j >> 5, dc = j & 31;
        float4 v = *(const float4*)(all_feats0 + (size_t)s_nrow[r] * PREP + dc * 4);
        *(float4*)&s_xn_pool[r * LDA0 + dc * 4] = v;
    }
    {
        int s = t >> 4, pg = t & 15;
        float4 a0, a1; ZERO4(a0); ZERO4(a1);
        #pragma unroll
        for (int d = 0; d < E_DIMC; ++d) {
            float e = s_emb[s * E_DIMC + d];
            float4 w0 = ld4<T>(epw_mp, (size_t)d * PREP + pg * 8);
            float4 w1 = ld4<T>(epw_mp, (size_t)d * PREP + pg * 8 + 4);
            FMA4C(a0, e, w0); FMA4C(a1, e, w1);
        }
        *(float4*)&s_eprep[s * LDA0 + pg * 8]     = a0;
        *(float4*)&s_eprep[s * LDA0 + pg * 8 + 4] = a1;
    }
    __syncthreads();

    float4 aq[4], ak[8];
    #pragma unroll
    for (int i = 0; i < 4; ++i) ZERO4(aq[i]);
    #pragma unroll
    for (int i = 0; i < 8; ++i) ZERO4(ak[i]);
    {
        size_t wb = (size_t)h * PREP * O_DIM + og * 4;
        for (int kk = 0; kk < PREP; kk += 4) {
            float4 bq[4], bk[4];
            #pragma unroll
            for (int j = 0; j < 4; ++j) {
                bq[j] = ld4<T>(ewq, wb + (size_t)(kk + j) * O_DIM);
                bk[j] = ld4<T>(ewk, wb + (size_t)(kk + j) * O_DIM);
            }
            #pragma unroll
            for (int i = 0; i < 4; ++i) {
                float4 a = *(const float4*)&s_eprep[(mg + 4 * i) * LDA0 + kk];
                FMA4C(aq[i], a.x, bq[0]); FMA4C(aq[i], a.y, bq[1]);
                FMA4C(aq[i], a.z, bq[2]); FMA4C(aq[i], a.w, bq[3]);
            }
            #pragma unroll
            for (int i = 0; i < 8; ++i) {
                int r = 2 * mg + (i & 1) + 8 * (i >> 1);
                float4 a = *(const float4*)&s_xn_pool[r * LDA0 + kk];
                FMA4C(ak[i], a.x, bk[0]); FMA4C(ak[i], a.y, bk[1]);
                FMA4C(ak[i], a.z, bk[2]); FMA4C(ak[i], a.w, bk[3]);
            }
        }
    }
    __syncthreads();

    #pragma unroll
    for (int j = 0; j < 4; ++j) {
        int s = mg + 4 * j;
        float4 q = aq[j], kA = ak[2 * j], kB = ak[2 * j + 1];
        float lA = og_sum(q.x * kA.x + q.y * kA.y + q.z * kA.z + q.w * kA.w) * 0.125f;
        float lB = og_sum(q.x * kB.x + q.y * kB.y + q.z * kB.z + q.w * kB.w) * 0.125f;
        float m = fmaxf(lA, lB);
        float eA = expf(lA - m), eB = expf(lB - m);
        float inv = 1.f / (eA + eB);
        float4 v;
        v.x = q.x + (eA * kA.x + eB * kB.x) * inv;
        v.y = q.y + (eA * kA.y + eB * kB.y) * inv;
        v.z = q.z + (eA * kA.z + eB * kB.z) * inv;
        v.w = q.w + (eA * kA.w + eB * kB.w) * inv;
        *(float4*)&s_nedge[s * LDA1 + h * O_DIM + og * 4] = elu4(v);
    }

    float4 zq; ZERO4(zq);
    float4 zk[4];
    #pragma unroll
    for (int i = 0; i < 4; ++i) ZERO4(zk[i]);
    {
        size_t wb = (size_t)h * PREP * O_DIM + og * 4;
        for (int kk = 0; kk < PREP; kk += 4) {
            float4 q4 = *(const float4*)&s_q0[kk];
            float4 bq[4], bk[4];
            #pragma unroll
            for (int j = 0; j < 4; ++j) {
                bq[j] = ld4<T>(nwq0, wb + (size_t)(kk + j) * O_DIM);
                bk[j] = ld4<T>(nwk0, wb + (size_t)(kk + j) * O_DIM);
            }
            FMA4C(zq, q4.x, bq[0]); FMA4C(zq, q4.y, bq[1]);
            FMA4C(zq, q4.z, bq[2]); FMA4C(zq, q4.w, bq[3]);
            #pragma unroll
            for (int i = 0; i < 4; ++i) {
                float4 a = *(const float4*)&s_eprep[(mg + 4 * i) * LDA0 + kk];
                FMA4C(zk[i], a.x, bk[0]); FMA4C(zk[i], a.y, bk[1]);
                FMA4C(zk[i], a.z, bk[2]); FMA4C(zk[i], a.w, bk[3]);
            }
        }
    }
    {
        float lg[4];
        #pragma unroll
        for (int j = 0; j < 4; ++j)
            lg[j] = og_sum(zq.x * zk[j].x + zq.y * zk[j].y +
                           zq.z * zk[j].z + zq.w * zk[j].w) * 0.125f;
        float mx = fmaxf(fmaxf(lg[0], lg[1]), fmaxf(lg[2], lg[3]));
        mx = mg_max(mx);
        float ea[4], ssum = 0.f;
        #pragma unroll
        for (int j = 0; j < 4; ++j) { ea[j] = expf(lg[j] - mx); ssum += ea[j]; }
        ssum = mg_sum(ssum);
        float inv = 1.f / ssum;
        float4 part; ZERO4(part);
        #pragma unroll
        for (int j = 0; j < 4; ++j) FMA4C(part, ea[j], zk[j]);
        part.x = mg_sum(part.x); part.y = mg_sum(part.y);
        part.z = mg_sum(part.z); part.w = mg_sum(part.w);
        float4 v;
        v.x = zq.x + part.x * inv; v.y = zq.y + part.y * inv;
        v.z = zq.z + part.z * inv; v.w = zq.w + part.w * inv;
        v = elu4(v);
        if (mg == 0) {
            *(float4*)&s_out0[h * O_DIM + og * 4] = v;
            *(float4*)(xcat_mp + (size_t)b * (2 * D1) + h * O_DIM + og * 4) = v;
        }
    }
    __syncthreads();

    ZERO4(zq);
    #pragma unroll
    for (int i = 0; i < 4; ++i) ZERO4(zk[i]);
    {
        size_t wb = (size_t)h * D1 * O_DIM + og * 4;
        for (int kk = 0; kk < D1; kk += 4) {
            float4 q4 = *(const float4*)&s_out0[kk];
            float4 bq[4], bk[4];
            #pragma unroll
            for (int j = 0; j < 4; ++j) {
                bq[j] = ld4<T>(nwq1, wb + (size_t)(kk + j) * O_DIM);
                bk[j] = ld4<T>(nwk1, wb + (size_t)(kk + j) * O_DIM);
            }
            FMA4C(zq, q4.x, bq[0]); FMA4C(zq, q4.y, bq[1]);
            FMA4C(zq, q4.z, bq[2]); FMA4C(zq, q4.w, bq[3]);
            #pragma unroll
            for (int i = 0; i < 4; ++i) {
                float4 a = *(const float4*)&s_nedge[(mg + 4 * i) * LDA1 + kk];
                FMA4C(zk[i], a.x, bk[0]); FMA4C(zk[i], a.y, bk[1]);
                FMA4C(zk[i], a.z, bk[2]); FMA4C(zk[i], a.w, bk[3]);
            }
        }
    }
    {
        float lg[4];
        #pragma unroll
        for (int j = 0; j < 4; ++j)
            lg[j] = og_sum(zq.x * zk[j].x + zq.y * zk[j].y +
                           zq.z * zk[j].z + zq.w * zk[j].w) * 0.125f;
        float mx = fmaxf(fmaxf(lg[0], lg[1]), fmaxf(lg[2], lg[3]));
        mx = mg_max(mx);
        float ea[4], ssum = 0.f;
        #pragma unroll
        for (int j = 0; j < 4; ++j) { ea[j] = expf(lg[j] - mx); ssum += ea[j]; }
        ssum = mg_sum(ssum);
        float inv = 1.f / ssum;
        float4 part; ZERO4(part);
        #pragma unroll
        for (int j = 0; j < 4; ++j) FMA4C(part, ea[j], zk[j]);
        part.x = mg_sum(part.x); part.y = mg_sum(part.y);
        part.z = mg_sum(part.z); part.w = mg_sum(part.w);
        float4 v;
        v.x = zq.x + part.x * inv; v.y = zq.y + part.y * inv;
        v.z = zq.z + part.z * inv; v.w = zq.w + part.w * inv;
        v = elu4(v);
        if (mg == 0)
            *(float4*)(xcat_mp + (size_t)b * (2 * D1) + D1 + h * O_DIM + og * 4) = v;
    }
}

// ---------------------------------------------------------------------------
extern "C" void kernel_launch(void* const* d_in, const int* in_sizes, int n_in,
                              void* d_out, int out_size, void* d_ws, size_t ws_size,
                              hipStream_t stream) {
    const void* feats       = d_in[0];
    const void* edge_emb    = d_in[1];
    const void* W_prep0     = d_in[2];
    const void* W_prep1     = d_in[3];
    const void* edge_prep_w = d_in[4];
    const void* e_wq0       = d_in[5];
    const void* e_wk0       = d_in[6];
    const void* n_wq0       = d_in[9];
    const void* n_wk0       = d_in[10];
    const void* n_wq1       = d_in[11];
    const void* n_wk1       = d_in[12];
    const void* Wg          = d_in[13];
    const void* vg          = d_in[14];
    const void* Wfc         = d_in[15];
    const void* bfc         = d_in[16];
    const int*  n2e         = (const int*)d_in[17];
    const int*  adj         = (const int*)d_in[18];
    const int*  tid         = (const int*)d_in[19];

    float* ws   = (float*)d_ws;
    int*   flag = (int*)ws;            // ws[0]
    float* base = ws + 4;
    size_t avail = (ws_size >= 16) ? (ws_size - 16) / 4 : 0;   // floats

    k_detect<<<1, 64, 0, stream>>>((const unsigned*)feats, flag);

    // ---- main-path fixed layout (float units; u16 buffers = n/2 floats) ----
    size_t off = 0;
    auto alloc = [&](size_t n) { size_t o = off; off += (n + 3) & ~(size_t)3; return o; };
    size_t o_xcat = alloc((size_t)NMP * B_TR * 2 * D1);       // 4.19M
    size_t o_gmat = alloc((size_t)NMP * B_TR * PREP);         // 1.05M
    size_t o_gpre = alloc(NMP * B_TR);
    size_t o_wqe  = alloc(NMP * 32 * D1);
    size_t o_wk0  = alloc(NMP * 32 * D1);
    size_t o_wkn  = alloc(NMP * 64 * D1);
    size_t o_wq0  = alloc(NMP * 64 * D1);
    size_t o_Kn   = alloc((size_t)N_NODES * D1);              // 5.12M
    size_t o_q0   = alloc((size_t)B_TR * D1);
    size_t o_Q1   = alloc((size_t)B_TR * D1);
    size_t o_eid  = alloc(NSLOT);
    size_t o_adjA = alloc(NSLOT);
    size_t o_adjB = alloc(NSLOT);
    size_t o_o0h  = alloc((size_t)B_TR * D1 / 2);
    size_t o_o0l  = alloc((size_t)B_TR * D1 / 2);
    size_t o_xh   = alloc((size_t)NMP * B_TR * D1);           // 512 u16/row
    size_t o_xl   = alloc((size_t)NMP * B_TR * D1);
    size_t o_wk1h = alloc((size_t)NMP * 32768);               // 256x256 u16
    size_t o_wk1l = alloc((size_t)NMP * 32768);
    size_t o_wq1h = alloc((size_t)NMP * 32768);
    size_t o_wq1l = alloc((size_t)NMP * 32768);
    size_t o_wgh  = alloc(32768);                             // 128x512 u16
    size_t o_wgl  = alloc(32768);
    size_t fixed = off;

    // chunk need: Abuf + Cbuf (fp32, CH*16*256 each) + nh/nl (u16, CH*16*256 ea)
    int CH = 0;
    for (int c = B_TR; c >= 256; c >>= 1)
        if (fixed + (size_t)c * S_NE * D1 * 3 <= avail) { CH = c; break; }

    if (CH > 0) {
        size_t o_A  = alloc((size_t)CH * S_NE * D1);
        size_t o_C  = alloc((size_t)CH * S_NE * D1);
        size_t o_nh = alloc((size_t)CH * S_NE * D1 / 2);
        size_t o_nl = alloc((size_t)CH * S_NE * D1 / 2);

        float* xcat = base + o_xcat;
        float* gmat = base + o_gmat;
        float* gpre = base + o_gpre;
        float* wqe  = base + o_wqe;
        float* wk0  = base + o_wk0;
        float* wkn  = base + o_wkn;
        float* wq0  = base + o_wq0;
        float* Kn   = base + o_Kn;
        float* q0   = base + o_q0;
        float* Q1   = base + o_Q1;
        int*   eid  = (int*)(base + o_eid);
        int*   adjA = (int*)(base + o_adjA);
        int*   adjB = (int*)(base + o_adjB);
        u16*   o0h  = (u16*)(base + o_o0h);
        u16*   o0l  = (u16*)(base + o_o0l);
        u16*   xh   = (u16*)(base + o_xh);
        u16*   xl   = (u16*)(base + o_xl);
        u16*   wk1h = (u16*)(base + o_wk1h);
        u16*   wk1l = (u16*)(base + o_wk1l);
        u16*   wq1h = (u16*)(base + o_wq1h);
        u16*   wq1l = (u16*)(base + o_wq1l);
        u16*   wgh  = (u16*)(base + o_wgh);
        u16*   wgl  = (u16*)(base + o_wgl);
        float* Abuf = base + o_A;
        float* Cbuf = base + o_C;
        u16*   nh   = (u16*)(base + o_nh);
        u16*   nl   = (u16*)(base + o_nl);
        int NC = B_TR / CH;

        k_precomb<<<32, 256, 0, stream>>>(edge_prep_w, e_wq0, n_wk0, W_prep1,
                                          e_wk0, W_prep0, n_wq0,
                                          wqe, wk0, wkn, wq0, flag);
        k_wt1<<<1024, 256, 0, stream>>>(n_wk1, n_wq1, wk1h, wk1l, wq1h, wq1l, flag);
        k_wgt<<<256, 256, 0, stream>>>(Wg, wgh, wgl, flag);

        for (int mp = 0; mp < NMP; ++mp) {
            k_slot_setup<<<(NSLOT + 255) / 256, 256, 0, stream>>>(
                n2e + (size_t)mp * N_NODES * S_NE,
                adj + (size_t)mp * E_EDGES * 2,
                tid, eid, adjA, adjB);

            // Kn = feats @ Wkn[mp]   [N,256], K=64 (fp32 path)
            k_gemm_rf<<<dim3((N_NODES + 63) / 64, 4), 256, 0, stream>>>(
                feats, 0, nullptr, D_FEAT, wkn + (size_t)mp * 64 * D1,
                64, D1, Kn, D1, N_NODES, D_FEAT, flag);
            // q0 = feats[tid] @ Wq0[mp]   [B,256], K=64
            k_gemm_rf<<<dim3(B_TR / 64, 4), 256, 0, stream>>>(
                feats, 0, tid, D_FEAT, wq0 + (size_t)mp * 64 * D1,
                64, D1, q0, D1, B_TR, D_FEAT, flag);

            for (int c = 0; c < NC; ++c) {
                int c0 = c * CH;
                int MS = CH * S_NE;
                // Qe -> Abuf : emb[eid] @ Wqe[mp]  K=32
                k_gemm_rf<<<dim3(MS / 64, 4), 256, 0, stream>>>(
                    edge_emb, (size_t)mp * E_EDGES * E_DIMC, eid + (size_t)c0 * S_NE,
                    E_DIMC, wqe + (size_t)mp * 32 * D1, 64, D1, Abuf, D1, MS, E_DIMC, flag);
                // edge attention -> ned hi/lo planes
                k_eattn<<<MS / 4, 256, 0, stream>>>(
                    Abuf, Kn, adjA + (size_t)c0 * S_NE, adjB + (size_t)c0 * S_NE, nh, nl);
                // K1 -> Cbuf : ned @ nwk1[mp]  (split-bf16 MFMA, K=256)
                k_mfma<256><<<dim3(MS / 128, 2), 256, 0, stream>>>(
                    nh, nl, wk1h + (size_t)mp * 65536, wk1l + (size_t)mp * 65536,
                    Cbuf, D1);
                // K0 -> Abuf (overwrite) : emb[eid] @ Wk0[mp]  K=32
                k_gemm_rf<<<dim3(MS / 64, 4), 256, 0, stream>>>(
                    edge_emb, (size_t)mp * E_EDGES * E_DIMC, eid + (size_t)c0 * S_NE,
                    E_DIMC, wk0 + (size_t)mp * 32 * D1, 64, D1, Abuf, D1, MS, E_DIMC, flag);
                // node attn L0 -> xcat[:,0:256] + o0 planes + x planes
                k_nattn<<<CH, 256, 0, stream>>>(
                    q0 + (size_t)c0 * D1, Abuf, o0h, o0l,
                    xcat + ((size_t)mp * B_TR + c0) * 2 * D1, 0,
                    xh + ((size_t)mp * B_TR + c0) * 2 * D1,
                    xl + ((size_t)mp * B_TR + c0) * 2 * D1);
                // Q1 = out0 @ nwq1[mp]  (MFMA, K=256) -> Q1 fp32 (chunk-local)
                k_mfma<256><<<dim3(CH / 128, 2), 256, 0, stream>>>(
                    o0h, o0l, wq1h + (size_t)mp * 65536, wq1l + (size_t)mp * 65536,
                    Q1, D1);
                // node attn L1 -> xcat[:,256:512] + x planes
                k_nattn<<<CH, 256, 0, stream>>>(
                    Q1, Cbuf, nullptr, nullptr,
                    xcat + ((size_t)mp * B_TR + c0) * 2 * D1, D1,
                    xh + ((size_t)mp * B_TR + c0) * 2 * D1,
                    xl + ((size_t)mp * B_TR + c0) * 2 * D1);
            }
        }
        // gate: gmat = xcat @ Wg  [8192,128], K=512 (MFMA from x planes)
        k_mfma<512><<<dim3(NMP * B_TR / 128, 1), 256, 0, stream>>>(
            xh, xl, wgh, wgl, gmat, PREP);
        k_gate_fin<<<NMP * B_TR, 128, 0, stream>>>(gmat, vg, gpre, flag);
        k_final<<<B_TR, 64, 0, stream>>>(xcat, gpre, Wfc, bfc, d_out, flag);
    } else {
        // ------------- fused fallback (R4) -------------
        size_t f_off = 0;
        auto falloc = [&](size_t n) { size_t o = f_off; f_off += (n + 3) & ~(size_t)3; return o; };
        float* af0  = base + falloc((size_t)N_NODES * PREP);
        float* xcat = base + falloc((size_t)NMP * B_TR * 2 * D1);
        float* gpre = base + falloc(NMP * B_TR);

        k_prep_nodes<float><<<(N_NODES * 32 + 255) / 256, 256, 0, stream>>>(
            feats, W_prep1, af0, flag);
        k_prep_nodes<bf16><<<(N_NODES * 32 + 255) / 256, 256, 0, stream>>>(
            feats, W_prep1, af0, flag);

        for (int mp = 0; mp < NMP; ++mp) {
            #define FUSED_ARGS(esz)                                                   \
                feats,                                                                \
                (const char*)edge_emb + (esz) * (size_t)mp * E_EDGES * E_DIMC,        \
                W_prep0,                                                              \
                (const char*)edge_prep_w + (esz) * (size_t)mp * E_DIMC * PREP,        \
                (const char*)e_wq0 + (esz) * (size_t)mp * H_HEADS * PREP * O_DIM,     \
                (const char*)e_wk0 + (esz) * (size_t)mp * H_HEADS * PREP * O_DIM,     \
                (const char*)n_wq0 + (esz) * (size_t)mp * H_HEADS * PREP * O_DIM,     \
                (const char*)n_wk0 + (esz) * (size_t)mp * H_HEADS * PREP * O_DIM,     \
                (const char*)n_wq1 + (esz) * (size_t)mp * H_HEADS * D1 * O_DIM,       \
                (const char*)n_wk1 + (esz) * (size_t)mp * H_HEADS * D1 * O_DIM,       \
                n2e + (size_t)mp * N_NODES * S_NE,                                    \
                adj + (size_t)mp * E_EDGES * 2,                                       \
                tid, af0, xcat + (size_t)mp * B_TR * 2 * D1, flag
            k_fused<float><<<B_TR, 256, 0, stream>>>(FUSED_ARGS(4));
            k_fused<bf16><<<B_TR, 256, 0, stream>>>(FUSED_ARGS(2));
            #undef FUSED_ARGS
        }
        k_gate_direct<<<NMP * B_TR, 128, 0, stream>>>(xcat, Wg, vg, gpre, flag);
        k_final<<<B_TR, 64, 0, stream>>>(xcat, gpre, Wfc, bfc, d_out, flag);
    }
}

// Round 8
// 784.214 us; speedup vs baseline: 3.2312x; 1.0578x over previous
//
#include <hip/hip_runtime.h>
#include <hip/hip_bf16.h>
#include <math.h>

// Problem dims
#define N_NODES 20000
#define S_NE    16
#define E_EDGES 160000
#define NMP     2
#define H_HEADS 4
#define O_DIM   64
#define D_FEAT  64
#define E_DIMC  32
#define PREP    128
#define NCLS    8
#define B_TR    4096
#define D1      256           // H*O
#define NSLOT   (B_TR * S_NE) // 65536

// LDS row pads for fused fallback
#define LDA0    132
#define LDA1    260

typedef __hip_bfloat16 bf16;
typedef unsigned short u16;
typedef __attribute__((ext_vector_type(8))) short s8v;   // 8 bf16 (4 VGPRs)
typedef __attribute__((ext_vector_type(4))) float f4v;   // MFMA acc

template <typename T>
__device__ __forceinline__ float ldv(const void* p, size_t i) {
    if constexpr (sizeof(T) == 4) return ((const float*)p)[i];
    else return __bfloat162float(((const bf16*)p)[i]);
}
template <typename T>
__device__ __forceinline__ float4 ld4(const void* p, size_t i) {
    if constexpr (sizeof(T) == 4) {
        return *(const float4*)((const float*)p + i);
    } else {
        float4 r;
        r.x = ldv<T>(p, i); r.y = ldv<T>(p, i + 1);
        r.z = ldv<T>(p, i + 2); r.w = ldv<T>(p, i + 3);
        return r;
    }
}
template <typename T>
__device__ __forceinline__ void stv(void* p, size_t i, float v) {
    if constexpr (sizeof(T) == 4) ((float*)p)[i] = v;
    else ((bf16*)p)[i] = __float2bfloat16(v);
}
template <typename T>
__device__ __forceinline__ bool active(const int* flag) {
    return *flag == (sizeof(T) == 4 ? 1 : 0);
}

__device__ __forceinline__ u16 f2bf(float x) {
    bf16 h = __float2bfloat16(x);
    return *reinterpret_cast<u16*>(&h);
}
__device__ __forceinline__ float bf2f(u16 u) {
    bf16 h; *reinterpret_cast<u16*>(&h) = u;
    return __bfloat162float(h);
}
// split-bf16: x ~= hi + lo, product error ~2^-17 relative
__device__ __forceinline__ void splitbf(float x, u16& h, u16& l) {
    h = f2bf(x);
    l = f2bf(x - bf2f(h));
}

__device__ __forceinline__ float wave_sum(float v) {
    #pragma unroll
    for (int off = 32; off > 0; off >>= 1) v += __shfl_xor(v, off, 64);
    return v;
}
__device__ __forceinline__ float og_sum(float v) {
    v += __shfl_xor(v, 4, 64);  v += __shfl_xor(v, 8, 64);
    v += __shfl_xor(v, 16, 64); v += __shfl_xor(v, 32, 64);
    return v;
}
__device__ __forceinline__ float mg_sum(float v) {
    v += __shfl_xor(v, 1, 64); v += __shfl_xor(v, 2, 64); return v;
}
__device__ __forceinline__ float mg_max(float v) {
    v = fmaxf(v, __shfl_xor(v, 1, 64)); v = fmaxf(v, __shfl_xor(v, 2, 64)); return v;
}
__device__ __forceinline__ float eluf(float x) { return x > 0.f ? x : expf(x) - 1.f; }
__device__ __forceinline__ float4 elu4(float4 v) {
    v.x = eluf(v.x); v.y = eluf(v.y); v.z = eluf(v.z); v.w = eluf(v.w); return v;
}

#define FMA4C(acc, s, b) do { (acc).x += (s)*(b).x; (acc).y += (s)*(b).y; \
                              (acc).z += (s)*(b).z; (acc).w += (s)*(b).w; } while (0)
#define ZERO4(v) do { (v).x = 0.f; (v).y = 0.f; (v).z = 0.f; (v).w = 0.f; } while (0)

// ---------------------------------------------------------------------------
// Dtype detector (R3-verified): flag=1 => fp32 buffers. flag at ws[0].
__global__ void k_detect(const unsigned* __restrict__ w, int* __restrict__ flag) {
    int t = threadIdx.x;
    int bad = 0;
    for (int i = t; i < 512; i += 64) {
        float v = __uint_as_float((w[i] & 0xffffu) << 16);
        if (!(fabsf(v) < 64.f)) bad++;
    }
    #pragma unroll
    for (int off = 32; off > 0; off >>= 1) bad += __shfl_xor(bad, off, 64);
    if (t == 0) *flag = (bad > 32) ? 1 : 0;
}

// ---------------------------------------------------------------------------
// Parallel precombined weights (one thread per output element, 98304 total):
//  c0: Wqe planes [mp][n=256][k=32] = (epw @ ewq)^T hi/lo     (MFMA B operand)
//  c1: Wk0 planes [mp][n=256][k=32] = (epw @ nwk0)^T hi/lo
//  c2: Wkn fp32 [mp][64][256] = Wp1 @ ewk                     (fp32 GEMM B)
//  c3: Wq0 fp32 [mp][64][256] = Wp0 @ nwq0
template <typename T>
__device__ void precomb2_body(const void* epw, const void* ewq, const void* nwk0,
                              const void* Wp1, const void* ewk,
                              const void* Wp0, const void* nwq0,
                              float* wkn, float* wq0,
                              u16* qeh, u16* qel, u16* k0h, u16* k0l) {
    int idx = blockIdx.x * 256 + threadIdx.x;
    if (idx >= 98304) return;
    int combo, rem;
    if (idx < 16384)      { combo = 0; rem = idx; }
    else if (idx < 32768) { combo = 1; rem = idx - 16384; }
    else if (idx < 65536) { combo = 2; rem = idx - 32768; }
    else                  { combo = 3; rem = idx - 65536; }
    int mp, r, n;
    if (combo < 2) { mp = rem >> 13; r = (rem >> 8) & 31; n = rem & 255; }
    else           { mp = rem >> 14; r = (rem >> 8) & 63; n = rem & 255; }
    int h = n >> 6, o = n & 63;
    const void* Aw; const void* Bw; size_t aoff;
    size_t boff = (size_t)mp * H_HEADS * PREP * O_DIM + (size_t)h * PREP * O_DIM + o;
    switch (combo) {
        case 0: Aw = epw; Bw = ewq;  aoff = (size_t)mp * E_DIMC * PREP + (size_t)r * PREP; break;
        case 1: Aw = epw; Bw = nwk0; aoff = (size_t)mp * E_DIMC * PREP + (size_t)r * PREP; break;
        case 2: Aw = Wp1; Bw = ewk;  aoff = (size_t)r * PREP; break;
        default:Aw = Wp0; Bw = nwq0; aoff = (size_t)r * PREP; break;
    }
    float acc = 0.f;
    #pragma unroll 4
    for (int p = 0; p < PREP; ++p)
        acc += ldv<T>(Aw, aoff + p) * ldv<T>(Bw, boff + (size_t)p * O_DIM);
    if (combo < 2) {
        u16 hh, ll; splitbf(acc, hh, ll);
        size_t dst = (size_t)mp * (256 * 32) + (size_t)n * 32 + r;
        if (combo == 0) { qeh[dst] = hh; qel[dst] = ll; }
        else            { k0h[dst] = hh; k0l[dst] = ll; }
    } else if (combo == 2) {
        wkn[(size_t)mp * 64 * D1 + (size_t)r * D1 + n] = acc;
    } else {
        wq0[(size_t)mp * 64 * D1 + (size_t)r * D1 + n] = acc;
    }
}
__global__ void k_precomb2(const void* epw, const void* ewq, const void* nwk0,
                           const void* Wp1, const void* ewk,
                           const void* Wp0, const void* nwq0,
                           float* wkn, float* wq0,
                           u16* qeh, u16* qel, u16* k0h, u16* k0l,
                           const int* flag) {
    if (*flag == 1) precomb2_body<float>(epw, ewq, nwk0, Wp1, ewk, Wp0, nwq0, wkn, wq0, qeh, qel, k0h, k0l);
    else            precomb2_body<bf16 >(epw, ewq, nwk0, Wp1, ewk, Wp0, nwq0, wkn, wq0, qeh, qel, k0h, k0l);
}

// edge_emb -> hi/lo bf16 planes [NMP][E][32] (coalesced)
template <typename T>
__device__ void embsplit_body(const void* emb, u16* eh, u16* el) {
    size_t idx = (size_t)blockIdx.x * 256 + threadIdx.x;
    if (idx >= (size_t)NMP * E_EDGES * E_DIMC) return;
    float v = ldv<T>(emb, idx);
    u16 hh, ll; splitbf(v, hh, ll);
    eh[idx] = hh; el[idx] = ll;
}
__global__ void k_embsplit(const void* emb, u16* eh, u16* el, const int* flag) {
    if (*flag == 1) embsplit_body<float>(emb, eh, el);
    else            embsplit_body<bf16 >(emb, eh, el);
}

// Transposed hi/lo planes of nwk1/nwq1: Bt[mp][n=256][k=256]
template <typename T>
__device__ void wt1_body(const void* wk1, const void* wq1,
                         u16* kth, u16* ktl, u16* qth, u16* qtl) {
    int idx = blockIdx.x * 256 + threadIdx.x;   // 0..262143
    int k = idx & 255, n = (idx >> 8) & 255;
    int wsel = (idx >> 16) & 1, mp = idx >> 17;
    size_t src = (size_t)mp * (H_HEADS * D1 * O_DIM) + (size_t)(n >> 6) * (D1 * O_DIM)
               + (size_t)k * O_DIM + (n & 63);
    float v = ldv<T>(wsel ? wq1 : wk1, src);
    u16 h, l; splitbf(v, h, l);
    size_t dst = (size_t)mp * 65536 + (size_t)n * 256 + k;
    if (wsel) { qth[dst] = h; qtl[dst] = l; }
    else      { kth[dst] = h; ktl[dst] = l; }
}
__global__ void k_wt1(const void* wk1, const void* wq1,
                      u16* kth, u16* ktl, u16* qth, u16* qtl, const int* flag) {
    if (*flag == 1) wt1_body<float>(wk1, wq1, kth, ktl, qth, qtl);
    else            wt1_body<bf16 >(wk1, wq1, kth, ktl, qth, qtl);
}

// Transposed hi/lo planes of Wg[512][128] -> Wgt[n=128][k=512]
template <typename T>
__device__ void wgt_body(const void* Wg, u16* gh, u16* gl) {
    int idx = blockIdx.x * 256 + threadIdx.x;   // 0..65535
    int n = idx >> 9, k = idx & 511;
    float v = ldv<T>(Wg, (size_t)k * PREP + n);
    u16 h, l; splitbf(v, h, l);
    gh[(size_t)n * 512 + k] = h;
    gl[(size_t)n * 512 + k] = l;
}
__global__ void k_wgt(const void* Wg, u16* gh, u16* gl, const int* flag) {
    if (*flag == 1) wgt_body<float>(Wg, gh, gl);
    else            wgt_body<bf16 >(Wg, gh, gl);
}

// ---------------------------------------------------------------------------
// fp32 register-tiled GEMM (R6-verified) for the K<=64 GEMMs (Kn, q0).
template <typename TA, typename TB>
__device__ void gemm_body(const void* A, size_t aOff, const int* Aidx, int strideA,
                          const void* B, int sH, int sD,
                          float* C, int ldC, int M, int K) {
    int bm = blockIdx.x * 64;
    int h  = blockIdx.y;
    int t  = threadIdx.x;
    int tx = t & 15, ty = t >> 4;

    __shared__ float As[32][68];
    __shared__ float Bs[32][68];

    float acc[4][4] = {{0.f}};
    int arow = t >> 3, kq = (t & 7) * 4;
    int brow = t >> 4, nq = (t & 15) * 4;

    for (int k0 = 0; k0 < K; k0 += 32) {
        #pragma unroll
        for (int c = 0; c < 2; ++c) {
            int rm = arow + 32 * c;
            int gr = bm + rm;
            gr = (gr < M) ? gr : 0;
            size_t row = Aidx ? (size_t)Aidx[gr] : (size_t)gr;
            float4 a = ld4<TA>(A, aOff + row * strideA + k0 + kq);
            As[kq + 0][rm] = a.x; As[kq + 1][rm] = a.y;
            As[kq + 2][rm] = a.z; As[kq + 3][rm] = a.w;
        }
        #pragma unroll
        for (int c = 0; c < 2; ++c) {
            int rk = brow + 16 * c;
            float4 b = ld4<TB>(B, (size_t)h * sH + (size_t)(k0 + rk) * sD + nq);
            *(float4*)&Bs[rk][nq] = b;
        }
        __syncthreads();
        #pragma unroll
        for (int kk = 0; kk < 32; ++kk) {
            float4 av = *(const float4*)&As[kk][ty * 4];
            float4 bv = *(const float4*)&Bs[kk][tx * 4];
            float am[4] = {av.x, av.y, av.z, av.w};
            #pragma unroll
            for (int i = 0; i < 4; ++i) {
                acc[i][0] += am[i] * bv.x; acc[i][1] += am[i] * bv.y;
                acc[i][2] += am[i] * bv.z; acc[i][3] += am[i] * bv.w;
            }
        }
        __syncthreads();
    }
    #pragma unroll
    for (int i = 0; i < 4; ++i) {
        int m = bm + ty * 4 + i;
        if (m < M) {
            float4 st; st.x = acc[i][0]; st.y = acc[i][1];
            st.z = acc[i][2]; st.w = acc[i][3];
            *(float4*)&C[(size_t)m * ldC + h * 64 + tx * 4] = st;
        }
    }
}
__global__ __launch_bounds__(256) void k_gemm_rf(
        const void* A, size_t aOff, const int* Aidx, int strideA,
        const float* B, int sH, int sD, float* C, int ldC, int M, int K,
        const int* flag) {
    if (*flag == 1) gemm_body<float, float>(A, aOff, Aidx, strideA, B, sH, sD, C, ldC, M, K);
    else            gemm_body<bf16,  float>(A, aOff, Aidx, strideA, B, sH, sD, C, ldC, M, K);
}

// ---------------------------------------------------------------------------
// LDS-free split-bf16 MFMA GEMM (R7-verified): C = A @ B^T-planes, K templated.
template <int K>
__global__ __launch_bounds__(256) void k_mfma(
        const u16* __restrict__ Ah, const u16* __restrict__ Al,
        const u16* __restrict__ Bh, const u16* __restrict__ Bl,
        float* __restrict__ C, int ldC) {
    int w = threadIdx.x >> 6, lane = threadIdx.x & 63;
    int bm = blockIdx.x * 128 + (w & 1) * 64;
    int bn = blockIdx.y * 128 + (w >> 1) * 64;
    int fr = lane & 15;
    int kq = (lane >> 4) * 8;

    f4v acc[4][4];
    #pragma unroll
    for (int i = 0; i < 4; ++i)
        #pragma unroll
        for (int j = 0; j < 4; ++j) acc[i][j] = f4v{0.f, 0.f, 0.f, 0.f};

    #pragma unroll 2
    for (int k0 = 0; k0 < K; k0 += 32) {
        s8v ah[4], al[4], bh[4], bl[4];
        #pragma unroll
        for (int i = 0; i < 4; ++i) {
            size_t ao = (size_t)(bm + i * 16 + fr) * K + k0 + kq;
            ah[i] = *(const s8v*)(Ah + ao);
            al[i] = *(const s8v*)(Al + ao);
            size_t bo = (size_t)(bn + i * 16 + fr) * K + k0 + kq;
            bh[i] = *(const s8v*)(Bh + bo);
            bl[i] = *(const s8v*)(Bl + bo);
        }
        #pragma unroll
        for (int i = 0; i < 4; ++i)
            #pragma unroll
            for (int j = 0; j < 4; ++j) {
                acc[i][j] = __builtin_amdgcn_mfma_f32_16x16x32_bf16(al[i], bh[j], acc[i][j], 0, 0, 0);
                acc[i][j] = __builtin_amdgcn_mfma_f32_16x16x32_bf16(ah[i], bl[j], acc[i][j], 0, 0, 0);
                acc[i][j] = __builtin_amdgcn_mfma_f32_16x16x32_bf16(ah[i], bh[j], acc[i][j], 0, 0, 0);
            }
    }
    int cn = lane & 15, cr = (lane >> 4) * 4;
    #pragma unroll
    for (int i = 0; i < 4; ++i) {
        int m0 = bm + i * 16 + cr;
        #pragma unroll
        for (int j = 0; j < 4; ++j) {
            int n = bn + j * 16 + cn;
            #pragma unroll
            for (int r = 0; r < 4; ++r)
                C[(size_t)(m0 + r) * ldC + n] = acc[i][j][r];
        }
    }
}

// Gather-A variant, K=32 fixed (one MFMA k-step): A rows indexed via rows[].
__global__ __launch_bounds__(256) void k_mfma_g32(
        const u16* __restrict__ Ah, const u16* __restrict__ Al,   // [E][32] planes
        const int* __restrict__ rows,                             // [MS] -> edge id
        const u16* __restrict__ Bh, const u16* __restrict__ Bl,   // [256][32] planes
        float* __restrict__ C, int ldC) {
    int w = threadIdx.x >> 6, lane = threadIdx.x & 63;
    int bm = blockIdx.x * 128 + (w & 1) * 64;
    int bn = blockIdx.y * 128 + (w >> 1) * 64;
    int fr = lane & 15;
    int kq = (lane >> 4) * 8;

    f4v acc[4][4];
    #pragma unroll
    for (int i = 0; i < 4; ++i)
        #pragma unroll
        for (int j = 0; j < 4; ++j) acc[i][j] = f4v{0.f, 0.f, 0.f, 0.f};

    s8v ah[4], al[4], bh[4], bl[4];
    #pragma unroll
    for (int i = 0; i < 4; ++i) {
        size_t ao = (size_t)rows[bm + i * 16 + fr] * E_DIMC + kq;
        ah[i] = *(const s8v*)(Ah + ao);
        al[i] = *(const s8v*)(Al + ao);
        size_t bo = (size_t)(bn + i * 16 + fr) * E_DIMC + kq;
        bh[i] = *(const s8v*)(Bh + bo);
        bl[i] = *(const s8v*)(Bl + bo);
    }
    #pragma unroll
    for (int i = 0; i < 4; ++i)
        #pragma unroll
        for (int j = 0; j < 4; ++j) {
            acc[i][j] = __builtin_amdgcn_mfma_f32_16x16x32_bf16(al[i], bh[j], acc[i][j], 0, 0, 0);
            acc[i][j] = __builtin_amdgcn_mfma_f32_16x16x32_bf16(ah[i], bl[j], acc[i][j], 0, 0, 0);
            acc[i][j] = __builtin_amdgcn_mfma_f32_16x16x32_bf16(ah[i], bh[j], acc[i][j], 0, 0, 0);
        }
    int cn = lane & 15, cr = (lane >> 4) * 4;
    #pragma unroll
    for (int i = 0; i < 4; ++i) {
        int m0 = bm + i * 16 + cr;
        #pragma unroll
        for (int j = 0; j < 4; ++j) {
            int n = bn + j * 16 + cn;
            #pragma unroll
            for (int r = 0; r < 4; ++r)
                C[(size_t)(m0 + r) * ldC + n] = acc[i][j][r];
        }
    }
}

// ---------------------------------------------------------------------------
// slot tables
__global__ void k_slot_setup(const int* __restrict__ n2e_mp,
                             const int* __restrict__ adj_mp,
                             const int* __restrict__ tid,
                             int* __restrict__ eid,
                             int* __restrict__ adjA,
                             int* __restrict__ adjB) {
    int i = blockIdx.x * blockDim.x + threadIdx.x;
    if (i >= NSLOT) return;
    int b = i >> 4, s = i & 15;
    int e = n2e_mp[(size_t)tid[b] * S_NE + s];
    eid[i] = e;
    adjA[i] = adj_mp[(size_t)e * 2 + 0];
    adjB[i] = adj_mp[(size_t)e * 2 + 1];
}

// Edge attention: reads Qe (fp32), writes ned hi/lo planes.
__global__ void k_eattn(const float* __restrict__ Qe,
                        const float* __restrict__ Kn,
                        const int* __restrict__ adjA,
                        const int* __restrict__ adjB,
                        u16* __restrict__ nh, u16* __restrict__ nl) {
    int slot = blockIdx.x * 4 + (threadIdx.x >> 6);
    int o = threadIdx.x & 63;
    size_t ra = (size_t)adjA[slot] * D1, rb = (size_t)adjB[slot] * D1;
    size_t qs = (size_t)slot * D1;
    #pragma unroll
    for (int h = 0; h < H_HEADS; ++h) {
        int c = h * O_DIM + o;
        float q  = Qe[qs + c];
        float kA = Kn[ra + c];
        float kB = Kn[rb + c];
        float lA = wave_sum(q * kA) * 0.125f;
        float lB = wave_sum(q * kB) * 0.125f;
        float m = fmaxf(lA, lB);
        float eA = expf(lA - m), eB = expf(lB - m);
        float inv = 1.f / (eA + eB);
        float v = eluf(q + (eA * kA + eB * kB) * inv);
        u16 hh, ll; splitbf(v, hh, ll);
        nh[qs + c] = hh; nl[qs + c] = ll;
    }
}

// Node attention; writes xcat fp32 + hi/lo planes (+ optional 256-wide planes).
__global__ void k_nattn(const float* __restrict__ q,
                        const float* __restrict__ K,
                        u16* __restrict__ o0h, u16* __restrict__ o0l,
                        float* __restrict__ xrow, int xoff,
                        u16* __restrict__ xh, u16* __restrict__ xl) {
    int b = blockIdx.x;
    int c = threadIdx.x;   // 256 = h*64+o
    float qv = q[(size_t)b * D1 + c];
    float k[S_NE], lg[S_NE];
    #pragma unroll
    for (int s = 0; s < S_NE; ++s) {
        k[s] = K[((size_t)b * S_NE + s) * D1 + c];
        lg[s] = wave_sum(qv * k[s]) * 0.125f;
    }
    float mx = lg[0];
    #pragma unroll
    for (int s = 1; s < S_NE; ++s) mx = fmaxf(mx, lg[s]);
    float sum = 0.f;
    #pragma unroll
    for (int s = 0; s < S_NE; ++s) { lg[s] = expf(lg[s] - mx); sum += lg[s]; }
    float inv = 1.f / sum;
    float agg = 0.f;
    #pragma unroll
    for (int s = 0; s < S_NE; ++s) agg += lg[s] * k[s];
    float v = eluf(qv + agg * inv);
    xrow[(size_t)b * (2 * D1) + xoff + c] = v;
    u16 hh, ll; splitbf(v, hh, ll);
    xh[(size_t)b * (2 * D1) + xoff + c] = hh;
    xl[(size_t)b * (2 * D1) + xoff + c] = ll;
    if (o0h) { o0h[(size_t)b * D1 + c] = hh; o0l[(size_t)b * D1 + c] = ll; }
}

// gate finish
template <typename T>
__device__ void gate_fin_body(const float* gmat, const void* vg, float* gate_pre) {
    int row = blockIdx.x;
    int t = threadIdx.x;   // 128
    float v = tanhf(gmat[(size_t)row * PREP + t]) * ldv<T>(vg, t);
    __shared__ float red[128];
    red[t] = v;
    __syncthreads();
    for (int s = 64; s > 0; s >>= 1) { if (t < s) red[t] += red[t + s]; __syncthreads(); }
    if (t == 0) gate_pre[row] = red[0];
}
__global__ void k_gate_fin(const float* gmat, const void* vg, float* gate_pre,
                           const int* flag) {
    if (*flag == 1) gate_fin_body<float>(gmat, vg, gate_pre);
    else            gate_fin_body<bf16 >(gmat, vg, gate_pre);
}

// fallback gate (direct from xcat)
template <typename T>
__device__ void gate_dir_body(const float* xcat, const void* Wg, const void* vg,
                              float* gate_pre) {
    int mb = blockIdx.x;
    int t = threadIdx.x;   // 128
    __shared__ float xr[2 * D1];
    for (int idx = t; idx < 2 * D1; idx += 128) xr[idx] = xcat[(size_t)mb * (2 * D1) + idx];
    __syncthreads();
    float acc = 0.f;
    for (int d = 0; d < 2 * D1; ++d) acc += xr[d] * ldv<T>(Wg, (size_t)d * PREP + t);
    float gp = tanhf(acc) * ldv<T>(vg, t);
    __shared__ float red[128];
    red[t] = gp;
    __syncthreads();
    for (int s = 64; s > 0; s >>= 1) { if (t < s) red[t] += red[t + s]; __syncthreads(); }
    if (t == 0) gate_pre[mb] = red[0];
}
__global__ void k_gate_direct(const float* xcat, const void* Wg, const void* vg,
                              float* gate_pre, const int* flag) {
    if (*flag == 1) gate_dir_body<float>(xcat, Wg, vg, gate_pre);
    else            gate_dir_body<bf16 >(xcat, Wg, vg, gate_pre);
}

// final
template <typename T>
__device__ void final_body(const float* xcat, const float* gate_pre,
                           const void* Wfc, const void* bfc, void* out) {
    int b = blockIdx.x;
    int t = threadIdx.x;  // 64
    float g0 = gate_pre[b], g1 = gate_pre[B_TR + b];
    float mx = fmaxf(g0, g1);
    float e0 = expf(g0 - mx), e1 = expf(g1 - mx);
    float inv = 1.f / (e0 + e1);
    float w0 = e0 * inv, w1 = e1 * inv;
    __shared__ float pooled[2 * D1];
    for (int d = t; d < 2 * D1; d += 64)
        pooled[d] = w0 * xcat[(size_t)b * (2 * D1) + d]
                  + w1 * xcat[(size_t)(B_TR + b) * (2 * D1) + d];
    __syncthreads();
    if (t < NCLS) {
        float acc = ldv<T>(bfc, t);
        for (int d = 0; d < 2 * D1; ++d) acc += pooled[d] * ldv<T>(Wfc, (size_t)d * NCLS + t);
        stv<T>(out, (size_t)b * NCLS + t, acc);
    }
    if (t == 8) stv<T>(out, (size_t)B_TR * NCLS + b, w0);
    if (t == 9) stv<T>(out, (size_t)B_TR * NCLS + B_TR + b, w1);
}
__global__ void k_final(const float* xcat, const float* gate_pre,
                        const void* Wfc, const void* bfc, void* out,
                        const int* flag) {
    if (*flag == 1) final_body<float>(xcat, gate_pre, Wfc, bfc, out);
    else            final_body<bf16 >(xcat, gate_pre, Wfc, bfc, out);
}

// ---------------------------------------------------------------------------
// Fallback kernels (R4-verified fused path)
template <typename T>
__global__ void k_prep_nodes(const void* __restrict__ feats,
                             const void* __restrict__ W,
                             float* __restrict__ out,
                             const int* __restrict__ flag) {
    if (!active<T>(flag)) return;
    int g = blockIdx.x * blockDim.x + threadIdx.x;
    if (g >= N_NODES * 32) return;
    int n = g >> 5, pg = g & 31;
    float4 acc; ZERO4(acc);
    #pragma unroll 8
    for (int d = 0; d < D_FEAT; ++d) {
        float f = ldv<T>(feats, (size_t)n * D_FEAT + d);
        float4 w4 = ld4<T>(W, (size_t)d * PREP + pg * 4);
        FMA4C(acc, f, w4);
    }
    *(float4*)(out + (size_t)n * PREP + pg * 4) = acc;
}

template <typename T>
__global__ __launch_bounds__(256) void k_fused(
        const void* __restrict__ feats,
        const void* __restrict__ edge_emb_mp,
        const void* __restrict__ W_prep0,
        const void* __restrict__ epw_mp,
        const void* __restrict__ ewq,
        const void* __restrict__ ewk,
        const void* __restrict__ nwq0,
        const void* __restrict__ nwk0,
        const void* __restrict__ nwq1,
        const void* __restrict__ nwk1,
        const int*  __restrict__ n2e_mp,
        const int*  __restrict__ adj_mp,
        const int*  __restrict__ tid,
        const float* __restrict__ all_feats0,
        float* __restrict__ xcat_mp,
        const int* __restrict__ flag) {
    if (!active<T>(flag)) return;
    int b = blockIdx.x;
    int t = threadIdx.x;
    int h = t >> 6;
    int lane = t & 63;
    int mg = lane & 3, og = lane >> 2;

    __shared__ int   s_eid[S_NE];
    __shared__ int   s_nrow[2 * S_NE];
    __shared__ __align__(16) float s_emb[S_NE * E_DIMC];
    __shared__ __align__(16) float s_f[D_FEAT];
    __shared__ __align__(16) float s_q0[PREP];
    __shared__ __align__(16) float s_eprep[S_NE * LDA0];
    __shared__ __align__(16) float s_xn_pool[2 * S_NE * LDA0];
    __shared__ __align__(16) float s_out0[D1];
    float* s_nedge = s_xn_pool;

    int tid_b = tid[b];
    if (t < S_NE)   s_eid[t] = n2e_mp[(size_t)tid_b * S_NE + t];
    if (t < D_FEAT) s_f[t] = ldv<T>(feats, (size_t)tid_b * D_FEAT + t);
    __syncthreads();

    if (t < 2 * S_NE) s_nrow[t] = adj_mp[(size_t)s_eid[t >> 1] * 2 + (t & 1)];
    {
        int j = t, s = j >> 5, d = j & 31;
        s_emb[j] = ldv<T>(edge_emb_mp, (size_t)s_eid[s] * E_DIMC + d);
        j = t + 256; s = j >> 5; d = j & 31;
        s_emb[j] = ldv<T>(edge_emb_mp, (size_t)s_eid[s] * E_DIMC + d);
    }
    if (t < PREP) {
        float a = 0.f;
        #pragma unroll
        for (int d = 0; d < D_FEAT; ++d) a += s_f[d] * ldv<T>(W_prep0, d * PREP + t);
        s_q0[t] = a;
    }
    __syncthreads();

    #pragma unroll
    for (int k = 0; k < 4; ++k) {
        int j = t + 256 * k;
        int r = j >> 5, dc = j & 31;
        float4 v = *(const float4*)(all_feats0 + (size_t)s_nrow[r] * PREP + dc * 4);
        *(float4*)&s_xn_pool[r * LDA0 + dc * 4] = v;
    }
    {
        int s = t >> 4, pg = t & 15;
        float4 a0, a1; ZERO4(a0); ZERO4(a1);
        #pragma unroll
        for (int d = 0; d < E_DIMC; ++d) {
            float e = s_emb[s * E_DIMC + d];
            float4 w0 = ld4<T>(epw_mp, (size_t)d * PREP + pg * 8);
            float4 w1 = ld4<T>(epw_mp, (size_t)d * PREP + pg * 8 + 4);
            FMA4C(a0, e, w0); FMA4C(a1, e, w1);
        }
        *(float4*)&s_eprep[s * LDA0 + pg * 8]     = a0;
        *(float4*)&s_eprep[s * LDA0 + pg * 8 + 4] = a1;
    }
    __syncthreads();

    float4 aq[4], ak[8];
    #pragma unroll
    for (int i = 0; i < 4; ++i) ZERO4(aq[i]);
    #pragma unroll
    for (int i = 0; i < 8; ++i) ZERO4(ak[i]);
    {
        size_t wb = (size_t)h * PREP * O_DIM + og * 4;
        for (int kk = 0; kk < PREP; kk += 4) {
            float4 bq[4], bk[4];
            #pragma unroll
            for (int j = 0; j < 4; ++j) {
                bq[j] = ld4<T>(ewq, wb + (size_t)(kk + j) * O_DIM);
                bk[j] = ld4<T>(ewk, wb + (size_t)(kk + j) * O_DIM);
            }
            #pragma unroll
            for (int i = 0; i < 4; ++i) {
                float4 a = *(const float4*)&s_eprep[(mg + 4 * i) * LDA0 + kk];
                FMA4C(aq[i], a.x, bq[0]); FMA4C(aq[i], a.y, bq[1]);
                FMA4C(aq[i], a.z, bq[2]); FMA4C(aq[i], a.w, bq[3]);
            }
            #pragma unroll
            for (int i = 0; i < 8; ++i) {
                int r = 2 * mg + (i & 1) + 8 * (i >> 1);
                float4 a = *(const float4*)&s_xn_pool[r * LDA0 + kk];
                FMA4C(ak[i], a.x, bk[0]); FMA4C(ak[i], a.y, bk[1]);
                FMA4C(ak[i], a.z, bk[2]); FMA4C(ak[i], a.w, bk[3]);
            }
        }
    }
    __syncthreads();

    #pragma unroll
    for (int j = 0; j < 4; ++j) {
        int s = mg + 4 * j;
        float4 q = aq[j], kA = ak[2 * j], kB = ak[2 * j + 1];
        float lA = og_sum(q.x * kA.x + q.y * kA.y + q.z * kA.z + q.w * kA.w) * 0.125f;
        float lB = og_sum(q.x * kB.x + q.y * kB.y + q.z * kB.z + q.w * kB.w) * 0.125f;
        float m = fmaxf(lA, lB);
        float eA = expf(lA - m), eB = expf(lB - m);
        float inv = 1.f / (eA + eB);
        float4 v;
        v.x = q.x + (eA * kA.x + eB * kB.x) * inv;
        v.y = q.y + (eA * kA.y + eB * kB.y) * inv;
        v.z = q.z + (eA * kA.z + eB * kB.z) * inv;
        v.w = q.w + (eA * kA.w + eB * kB.w) * inv;
        *(float4*)&s_nedge[s * LDA1 + h * O_DIM + og * 4] = elu4(v);
    }

    float4 zq; ZERO4(zq);
    float4 zk[4];
    #pragma unroll
    for (int i = 0; i < 4; ++i) ZERO4(zk[i]);
    {
        size_t wb = (size_t)h * PREP * O_DIM + og * 4;
        for (int kk = 0; kk < PREP; kk += 4) {
            float4 q4 = *(const float4*)&s_q0[kk];
            float4 bq[4], bk[4];
            #pragma unroll
            for (int j = 0; j < 4; ++j) {
                bq[j] = ld4<T>(nwq0, wb + (size_t)(kk + j) * O_DIM);
                bk[j] = ld4<T>(nwk0, wb + (size_t)(kk + j) * O_DIM);
            }
            FMA4C(zq, q4.x, bq[0]); FMA4C(zq, q4.y, bq[1]);
            FMA4C(zq, q4.z, bq[2]); FMA4C(zq, q4.w, bq[3]);
            #pragma unroll
            for (int i = 0; i < 4; ++i) {
                float4 a = *(const float4*)&s_eprep[(mg + 4 * i) * LDA0 + kk];
                FMA4C(zk[i], a.x, bk[0]); FMA4C(zk[i], a.y, bk[1]);
                FMA4C(zk[i], a.z, bk[2]); FMA4C(zk[i], a.w, bk[3]);
            }
        }
    }
    {
        float lg[4];
        #pragma unroll
        for (int j = 0; j < 4; ++j)
            lg[j] = og_sum(zq.x * zk[j].x + zq.y * zk[j].y +
                           zq.z * zk[j].z + zq.w * zk[j].w) * 0.125f;
        float mx = fmaxf(fmaxf(lg[0], lg[1]), fmaxf(lg[2], lg[3]));
        mx = mg_max(mx);
        float ea[4], ssum = 0.f;
        #pragma unroll
        for (int j = 0; j < 4; ++j) { ea[j] = expf(lg[j] - mx); ssum += ea[j]; }
        ssum = mg_sum(ssum);
        float inv = 1.f / ssum;
        float4 part; ZERO4(part);
        #pragma unroll
        for (int j = 0; j < 4; ++j) FMA4C(part, ea[j], zk[j]);
        part.x = mg_sum(part.x); part.y = mg_sum(part.y);
        part.z = mg_sum(part.z); part.w = mg_sum(part.w);
        float4 v;
        v.x = zq.x + part.x * inv; v.y = zq.y + part.y * inv;
        v.z = zq.z + part.z * inv; v.w = zq.w + part.w * inv;
        v = elu4(v);
        if (mg == 0) {
            *(float4*)&s_out0[h * O_DIM + og * 4] = v;
            *(float4*)(xcat_mp + (size_t)b * (2 * D1) + h * O_DIM + og * 4) = v;
        }
    }
    __syncthreads();

    ZERO4(zq);
    #pragma unroll
    for (int i = 0; i < 4; ++i) ZERO4(zk[i]);
    {
        size_t wb = (size_t)h * D1 * O_DIM + og * 4;
        for (int kk = 0; kk < D1; kk += 4) {
            float4 q4 = *(const float4*)&s_out0[kk];
            float4 bq[4], bk[4];
            #pragma unroll
            for (int j = 0; j < 4; ++j) {
                bq[j] = ld4<T>(nwq1, wb + (size_t)(kk + j) * O_DIM);
                bk[j] = ld4<T>(nwk1, wb + (size_t)(kk + j) * O_DIM);
            }
            FMA4C(zq, q4.x, bq[0]); FMA4C(zq, q4.y, bq[1]);
            FMA4C(zq, q4.z, bq[2]); FMA4C(zq, q4.w, bq[3]);
            #pragma unroll
            for (int i = 0; i < 4; ++i) {
                float4 a = *(const float4*)&s_nedge[(mg + 4 * i) * LDA1 + kk];
                FMA4C(zk[i], a.x, bk[0]); FMA4C(zk[i], a.y, bk[1]);
                FMA4C(zk[i], a.z, bk[2]); FMA4C(zk[i], a.w, bk[3]);
            }
        }
    }
    {
        float lg[4];
        #pragma unroll
        for (int j = 0; j < 4; ++j)
            lg[j] = og_sum(zq.x * zk[j].x + zq.y * zk[j].y +
                           zq.z * zk[j].z + zq.w * zk[j].w) * 0.125f;
        float mx = fmaxf(fmaxf(lg[0], lg[1]), fmaxf(lg[2], lg[3]));
        mx = mg_max(mx);
        float ea[4], ssum = 0.f;
        #pragma unroll
        for (int j = 0; j < 4; ++j) { ea[j] = expf(lg[j] - mx); ssum += ea[j]; }
        ssum = mg_sum(ssum);
        float inv = 1.f / ssum;
        float4 part; ZERO4(part);
        #pragma unroll
        for (int j = 0; j < 4; ++j) FMA4C(part, ea[j], zk[j]);
        part.x = mg_sum(part.x); part.y = mg_sum(part.y);
        part.z = mg_sum(part.z); part.w = mg_sum(part.w);
        float4 v;
        v.x = zq.x + part.x * inv; v.y = zq.y + part.y * inv;
        v.z = zq.z + part.z * inv; v.w = zq.w + part.w * inv;
        v = elu4(v);
        if (mg == 0)
            *(float4*)(xcat_mp + (size_t)b * (2 * D1) + D1 + h * O_DIM + og * 4) = v;
    }
}

// ---------------------------------------------------------------------------
extern "C" void kernel_launch(void* const* d_in, const int* in_sizes, int n_in,
                              void* d_out, int out_size, void* d_ws, size_t ws_size,
                              hipStream_t stream) {
    const void* feats       = d_in[0];
    const void* edge_emb    = d_in[1];
    const void* W_prep0     = d_in[2];
    const void* W_prep1     = d_in[3];
    const void* edge_prep_w = d_in[4];
    const void* e_wq0       = d_in[5];
    const void* e_wk0       = d_in[6];
    const void* n_wq0       = d_in[9];
    const void* n_wk0       = d_in[10];
    const void* n_wq1       = d_in[11];
    const void* n_wk1       = d_in[12];
    const void* Wg          = d_in[13];
    const void* vg          = d_in[14];
    const void* Wfc         = d_in[15];
    const void* bfc         = d_in[16];
    const int*  n2e         = (const int*)d_in[17];
    const int*  adj         = (const int*)d_in[18];
    const int*  tid         = (const int*)d_in[19];

    float* ws   = (float*)d_ws;
    int*   flag = (int*)ws;            // ws[0]
    float* base = ws + 4;
    size_t avail = (ws_size >= 16) ? (ws_size - 16) / 4 : 0;   // floats

    k_detect<<<1, 64, 0, stream>>>((const unsigned*)feats, flag);

    // ---- main-path fixed layout (float units; u16 buffers = n/2 floats) ----
    size_t off = 0;
    auto alloc = [&](size_t n) { size_t o = off; off += (n + 3) & ~(size_t)3; return o; };
    size_t o_xcat = alloc((size_t)NMP * B_TR * 2 * D1);       // 4.19M
    size_t o_gmat = alloc((size_t)NMP * B_TR * PREP);         // 1.05M
    size_t o_gpre = alloc(NMP * B_TR);
    size_t o_wkn  = alloc(NMP * 64 * D1);
    size_t o_wq0  = alloc(NMP * 64 * D1);
    size_t o_qeh  = alloc(NMP * 256 * 32 / 2);                // u16 planes
    size_t o_qel  = alloc(NMP * 256 * 32 / 2);
    size_t o_k0h  = alloc(NMP * 256 * 32 / 2);
    size_t o_k0l  = alloc(NMP * 256 * 32 / 2);
    size_t o_ebh  = alloc((size_t)NMP * E_EDGES * E_DIMC / 2); // 5.12M
    size_t o_ebl  = alloc((size_t)NMP * E_EDGES * E_DIMC / 2); // 5.12M
    size_t o_Kn   = alloc((size_t)N_NODES * D1);              // 5.12M
    size_t o_q0   = alloc((size_t)B_TR * D1);
    size_t o_Q1   = alloc((size_t)B_TR * D1);
    size_t o_eid  = alloc(NSLOT);
    size_t o_adjA = alloc(NSLOT);
    size_t o_adjB = alloc(NSLOT);
    size_t o_o0h  = alloc((size_t)B_TR * D1 / 2);
    size_t o_o0l  = alloc((size_t)B_TR * D1 / 2);
    size_t o_xh   = alloc((size_t)NMP * B_TR * D1);           // 512 u16/row
    size_t o_xl   = alloc((size_t)NMP * B_TR * D1);
    size_t o_wk1h = alloc((size_t)NMP * 32768);               // 256x256 u16
    size_t o_wk1l = alloc((size_t)NMP * 32768);
    size_t o_wq1h = alloc((size_t)NMP * 32768);
    size_t o_wq1l = alloc((size_t)NMP * 32768);
    size_t o_wgh  = alloc(32768);                             // 128x512 u16
    size_t o_wgl  = alloc(32768);
    size_t fixed = off;

    // chunk need: Abuf + Cbuf (fp32) + nh/nl (u16) = 3x CH*16*256 float-equivs
    int CH = 0;
    for (int c = B_TR; c >= 256; c >>= 1)
        if (fixed + (size_t)c * S_NE * D1 * 3 <= avail) { CH = c; break; }

    if (CH > 0) {
        size_t o_A  = alloc((size_t)CH * S_NE * D1);
        size_t o_C  = alloc((size_t)CH * S_NE * D1);
        size_t o_nh = alloc((size_t)CH * S_NE * D1 / 2);
        size_t o_nl = alloc((size_t)CH * S_NE * D1 / 2);

        float* xcat = base + o_xcat;
        float* gmat = base + o_gmat;
        float* gpre = base + o_gpre;
        float* wkn  = base + o_wkn;
        float* wq0  = base + o_wq0;
        u16*   qeh  = (u16*)(base + o_qeh);
        u16*   qel  = (u16*)(base + o_qel);
        u16*   k0h  = (u16*)(base + o_k0h);
        u16*   k0l  = (u16*)(base + o_k0l);
        u16*   ebh  = (u16*)(base + o_ebh);
        u16*   ebl  = (u16*)(base + o_ebl);
        float* Kn   = base + o_Kn;
        float* q0   = base + o_q0;
        float* Q1   = base + o_Q1;
        int*   eid  = (int*)(base + o_eid);
        int*   adjA = (int*)(base + o_adjA);
        int*   adjB = (int*)(base + o_adjB);
        u16*   o0h  = (u16*)(base + o_o0h);
        u16*   o0l  = (u16*)(base + o_o0l);
        u16*   xh   = (u16*)(base + o_xh);
        u16*   xl   = (u16*)(base + o_xl);
        u16*   wk1h = (u16*)(base + o_wk1h);
        u16*   wk1l = (u16*)(base + o_wk1l);
        u16*   wq1h = (u16*)(base + o_wq1h);
        u16*   wq1l = (u16*)(base + o_wq1l);
        u16*   wgh  = (u16*)(base + o_wgh);
        u16*   wgl  = (u16*)(base + o_wgl);
        float* Abuf = base + o_A;
        float* Cbuf = base + o_C;
        u16*   nh   = (u16*)(base + o_nh);
        u16*   nl   = (u16*)(base + o_nl);
        int NC = B_TR / CH;

        k_precomb2<<<384, 256, 0, stream>>>(edge_prep_w, e_wq0, n_wk0, W_prep1,
                                            e_wk0, W_prep0, n_wq0,
                                            wkn, wq0, qeh, qel, k0h, k0l, flag);
        k_embsplit<<<(NMP * E_EDGES * E_DIMC + 255) / 256, 256, 0, stream>>>(
            edge_emb, ebh, ebl, flag);
        k_wt1<<<1024, 256, 0, stream>>>(n_wk1, n_wq1, wk1h, wk1l, wq1h, wq1l, flag);
        k_wgt<<<256, 256, 0, stream>>>(Wg, wgh, wgl, flag);

        for (int mp = 0; mp < NMP; ++mp) {
            k_slot_setup<<<(NSLOT + 255) / 256, 256, 0, stream>>>(
                n2e + (size_t)mp * N_NODES * S_NE,
                adj + (size_t)mp * E_EDGES * 2,
                tid, eid, adjA, adjB);

            // Kn = feats @ Wkn[mp]   [N,256], K=64 (fp32 path)
            k_gemm_rf<<<dim3((N_NODES + 63) / 64, 4), 256, 0, stream>>>(
                feats, 0, nullptr, D_FEAT, wkn + (size_t)mp * 64 * D1,
                64, D1, Kn, D1, N_NODES, D_FEAT, flag);
            // q0 = feats[tid] @ Wq0[mp]   [B,256], K=64
            k_gemm_rf<<<dim3(B_TR / 64, 4), 256, 0, stream>>>(
                feats, 0, tid, D_FEAT, wq0 + (size_t)mp * 64 * D1,
                64, D1, q0, D1, B_TR, D_FEAT, flag);

            const u16* ebh_mp = ebh + (size_t)mp * E_EDGES * E_DIMC;
            const u16* ebl_mp = ebl + (size_t)mp * E_EDGES * E_DIMC;

            for (int c = 0; c < NC; ++c) {
                int c0 = c * CH;
                int MS = CH * S_NE;
                // Qe -> Abuf : emb[eid] @ Wqe[mp]  (gather MFMA, K=32)
                k_mfma_g32<<<dim3(MS / 128, 2), 256, 0, stream>>>(
                    ebh_mp, ebl_mp, eid + (size_t)c0 * S_NE,
                    qeh + (size_t)mp * 8192, qel + (size_t)mp * 8192, Abuf, D1);
                // edge attention -> ned hi/lo planes
                k_eattn<<<MS / 4, 256, 0, stream>>>(
                    Abuf, Kn, adjA + (size_t)c0 * S_NE, adjB + (size_t)c0 * S_NE, nh, nl);
                // K1 -> Cbuf : ned @ nwk1[mp]  (MFMA, K=256)
                k_mfma<256><<<dim3(MS / 128, 2), 256, 0, stream>>>(
                    nh, nl, wk1h + (size_t)mp * 65536, wk1l + (size_t)mp * 65536,
                    Cbuf, D1);
                // K0 -> Abuf (overwrite) : emb[eid] @ Wk0[mp]  (gather MFMA, K=32)
                k_mfma_g32<<<dim3(MS / 128, 2), 256, 0, stream>>>(
                    ebh_mp, ebl_mp, eid + (size_t)c0 * S_NE,
                    k0h + (size_t)mp * 8192, k0l + (size_t)mp * 8192, Abuf, D1);
                // node attn L0 -> xcat[:,0:256] + o0 planes + x planes
                k_nattn<<<CH, 256, 0, stream>>>(
                    q0 + (size_t)c0 * D1, Abuf, o0h, o0l,
                    xcat + ((size_t)mp * B_TR + c0) * 2 * D1, 0,
                    xh + ((size_t)mp * B_TR + c0) * 2 * D1,
                    xl + ((size_t)mp * B_TR + c0) * 2 * D1);
                // Q1 = out0 @ nwq1[mp]  (MFMA, K=256), chunk-local rows
                k_mfma<256><<<dim3(CH / 128, 2), 256, 0, stream>>>(
                    o0h, o0l, wq1h + (size_t)mp * 65536, wq1l + (size_t)mp * 65536,
                    Q1, D1);
                // node attn L1 -> xcat[:,256:512] + x planes
                k_nattn<<<CH, 256, 0, stream>>>(
                    Q1, Cbuf, nullptr, nullptr,
                    xcat + ((size_t)mp * B_TR + c0) * 2 * D1, D1,
                    xh + ((size_t)mp * B_TR + c0) * 2 * D1,
                    xl + ((size_t)mp * B_TR + c0) * 2 * D1);
            }
        }
        // gate: gmat = xcat @ Wg  [8192,128], K=512 (MFMA from x planes)
        k_mfma<512><<<dim3(NMP * B_TR / 128, 1), 256, 0, stream>>>(
            xh, xl, wgh, wgl, gmat, PREP);
        k_gate_fin<<<NMP * B_TR, 128, 0, stream>>>(gmat, vg, gpre, flag);
        k_final<<<B_TR, 64, 0, stream>>>(xcat, gpre, Wfc, bfc, d_out, flag);
    } else {
        // ------------- fused fallback (R4) -------------
        size_t f_off = 0;
        auto falloc = [&](size_t n) { size_t o = f_off; f_off += (n + 3) & ~(size_t)3; return o; };
        float* af0  = base + falloc((size_t)N_NODES * PREP);
        float* xcat = base + falloc((size_t)NMP * B_TR * 2 * D1);
        float* gpre = base + falloc(NMP * B_TR);

        k_prep_nodes<float><<<(N_NODES * 32 + 255) / 256, 256, 0, stream>>>(
            feats, W_prep1, af0, flag);
        k_prep_nodes<bf16><<<(N_NODES * 32 + 255) / 256, 256, 0, stream>>>(
            feats, W_prep1, af0, flag);

        for (int mp = 0; mp < NMP; ++mp) {
            #define FUSED_ARGS(esz)                                                   \
                feats,                                                                \
                (const char*)edge_emb + (esz) * (size_t)mp * E_EDGES * E_DIMC,        \
                W_prep0,                                                              \
                (const char*)edge_prep_w + (esz) * (size_t)mp * E_DIMC * PREP,        \
                (const char*)e_wq0 + (esz) * (size_t)mp * H_HEADS * PREP * O_DIM,     \
                (const char*)e_wk0 + (esz) * (size_t)mp * H_HEADS * PREP * O_DIM,     \
                (const char*)n_wq0 + (esz) * (size_t)mp * H_HEADS * PREP * O_DIM,     \
                (const char*)n_wk0 + (esz) * (size_t)mp * H_HEADS * PREP * O_DIM,     \
                (const char*)n_wq1 + (esz) * (size_t)mp * H_HEADS * D1 * O_DIM,       \
                (const char*)n_wk1 + (esz) * (size_t)mp * H_HEADS * D1 * O_DIM,       \
                n2e + (size_t)mp * N_NODES * S_NE,                                    \
                adj + (size_t)mp * E_EDGES * 2,                                       \
                tid, af0, xcat + (size_t)mp * B_TR * 2 * D1, flag
            k_fused<float><<<B_TR, 256, 0, stream>>>(FUSED_ARGS(4));
            k_fused<bf16><<<B_TR, 256, 0, stream>>>(FUSED_ARGS(2));
            #undef FUSED_ARGS
        }
        k_gate_direct<<<NMP * B_TR, 128, 0, stream>>>(xcat, Wg, vg, gpre, flag);
        k_final<<<B_TR, 64, 0, stream>>>(xcat, gpre, Wfc, bfc, d_out, flag);
    }
}